// Round 3
// baseline (1786.385 us; speedup 1.0000x reference)
//
#include <hip/hip_runtime.h>
#include <hip/hip_bf16.h>
#include <math.h>

#define THREADS 256

__global__ void zero_i32(int* __restrict__ p, int n) {
    int i = blockIdx.x * blockDim.x + threadIdx.x;
    if (i < n) p[i] = 0;
}

__global__ void count_kernel(const int* __restrict__ dst, int* __restrict__ cnt, int E) {
    int e = blockIdx.x * blockDim.x + threadIdx.x;
    if (e < E) atomicAdd(&cnt[dst[e]], 1);
}

__global__ void dinv_kernel(const int* __restrict__ cnt, float* __restrict__ dinv, int n) {
    int i = blockIdx.x * blockDim.x + threadIdx.x;
    if (i < n) dinv[i] = rsqrtf((float)cnt[i] + 1.0f);
}

// ---- multi-block exclusive scan: p1 partial sums, p2 scan partials, p3 local scan ----
__global__ __launch_bounds__(256) void scan_p1(const int* __restrict__ cnt, int* __restrict__ partial, int n) {
    __shared__ int red[256];
    int base = blockIdx.x * 1024 + threadIdx.x * 4;
    int s = 0;
    if (base + 3 < n) {
        int4 v = *(const int4*)(cnt + base);
        s = v.x + v.y + v.z + v.w;
    } else {
        for (int k = 0; k < 4; k++) { int i = base + k; if (i < n) s += cnt[i]; }
    }
    red[threadIdx.x] = s;
    __syncthreads();
    for (int off = 128; off > 0; off >>= 1) {
        if (threadIdx.x < off) red[threadIdx.x] += red[threadIdx.x + off];
        __syncthreads();
    }
    if (threadIdx.x == 0) partial[blockIdx.x] = red[0];
}

__global__ __launch_bounds__(256) void scan_p2(int* __restrict__ partial, int* __restrict__ rowptr, int nb, int n) {
    __shared__ int sm[256];
    int tid = threadIdx.x;
    int v = (tid < nb) ? partial[tid] : 0;
    sm[tid] = v;
    __syncthreads();
    int acc = v;
    for (int off = 1; off < 256; off <<= 1) {
        int t = (tid >= off) ? sm[tid - off] : 0;
        __syncthreads();
        acc += t;
        sm[tid] = acc;
        __syncthreads();
    }
    if (tid < nb) partial[tid] = acc - v;      // exclusive offsets
    if (tid == 255) rowptr[n] = sm[255];       // grand total
}

__global__ __launch_bounds__(256) void scan_p3(const int* __restrict__ cnt, const int* __restrict__ partial,
                                               int* __restrict__ rowptr, int* __restrict__ cursor, int n) {
    __shared__ int tsum[256];
    int tid = threadIdx.x;
    int base = blockIdx.x * 1024 + tid * 4;
    int v0 = 0, v1 = 0, v2 = 0, v3 = 0;
    if (base + 3 < n) {
        int4 t = *(const int4*)(cnt + base);
        v0 = t.x; v1 = t.y; v2 = t.z; v3 = t.w;
    } else {
        if (base + 0 < n) v0 = cnt[base + 0];
        if (base + 1 < n) v1 = cnt[base + 1];
        if (base + 2 < n) v2 = cnt[base + 2];
        if (base + 3 < n) v3 = cnt[base + 3];
    }
    int s = v0 + v1 + v2 + v3;
    tsum[tid] = s;
    __syncthreads();
    int acc = s;
    for (int off = 1; off < 256; off <<= 1) {
        int t = (tid >= off) ? tsum[tid - off] : 0;
        __syncthreads();
        acc += t;
        tsum[tid] = acc;
        __syncthreads();
    }
    int run = partial[blockIdx.x] + acc - s;   // exclusive start for this thread's 4
    int vv[4] = {v0, v1, v2, v3};
    for (int k = 0; k < 4; k++) {
        int i = base + k;
        if (i < n) { rowptr[i] = run; cursor[i] = run; run += vv[k]; }
    }
}

__global__ void scatter_kernel(const int* __restrict__ src, const int* __restrict__ dst,
                               int* __restrict__ cursor, int* __restrict__ col, int E) {
    int e = blockIdx.x * blockDim.x + threadIdx.x;
    if (e < E) {
        int d = dst[e];
        int p = atomicAdd(&cursor[d], 1);
        col[p] = src[e];
    }
}

// ---------------------------------------------------------------------------
// Register-tiled GEMM: Y = (X @ W) * dinv[i]  (pre-scaled for aggregation)
// ---------------------------------------------------------------------------
template<int FIN, int FOUT>
__global__ __launch_bounds__(256) void gemm_kernel(
    const float* __restrict__ X, const float* __restrict__ W,
    const float* __restrict__ dinv, float* __restrict__ Y, int n)
{
    constexpr int KC = (FIN % 32 == 0) ? 32 : FIN;
    constexpr int NCHUNK = FIN / KC;
    constexpr int TN = (FOUT + 15) / 16;
    constexpr int FOUTP = TN * 16;
    constexpr int BM = 64;
    constexpr int KP = KC + 4;
    constexpr int K4 = KC / 4;

    __shared__ __align__(16) float sX[BM * KP];
    __shared__ __align__(16) float sW[FOUTP * KP];

    const int tid = threadIdx.x;
    const int tj = tid & 15;
    const int ti = tid >> 4;
    const int i0 = blockIdx.x * BM;

    float acc[4][TN] = {};

    for (int c = 0; c < NCHUNK; ++c) {
        const int k0 = c * KC;
        __syncthreads();
        for (int v = tid; v < BM * K4; v += 256) {
            int r = v / K4;
            int kk4 = v - r * K4;
            int gi = i0 + r;
            float4 val = (gi < n) ? *(const float4*)(X + (size_t)gi * FIN + k0 + kk4 * 4)
                                  : make_float4(0.f, 0.f, 0.f, 0.f);
            float* p = &sX[r * KP + kk4 * 4];
            p[0] = val.x; p[1] = val.y; p[2] = val.z; p[3] = val.w;
        }
        for (int v = tid; v < KC * FOUT; v += 256) {
            int kk = v / FOUT;
            int j = v - kk * FOUT;
            sW[j * KP + kk] = W[(size_t)(k0 + kk) * FOUT + j];
        }
        __syncthreads();
#pragma unroll
        for (int kk = 0; kk < KC; kk += 4) {
            float4 xv[4];
#pragma unroll
            for (int m = 0; m < 4; ++m)
                xv[m] = *(const float4*)&sX[(ti + 16 * m) * KP + kk];
#pragma unroll
            for (int u = 0; u < TN; ++u) {
                float4 wv = *(const float4*)&sW[(tj + 16 * u) * KP + kk];
#pragma unroll
                for (int m = 0; m < 4; ++m) {
                    acc[m][u] = fmaf(xv[m].x, wv.x, acc[m][u]);
                    acc[m][u] = fmaf(xv[m].y, wv.y, acc[m][u]);
                    acc[m][u] = fmaf(xv[m].z, wv.z, acc[m][u]);
                    acc[m][u] = fmaf(xv[m].w, wv.w, acc[m][u]);
                }
            }
        }
    }

#pragma unroll
    for (int m = 0; m < 4; ++m) {
        int gi = i0 + ti + 16 * m;
        if (gi >= n) continue;
        float dv = dinv[gi];
#pragma unroll
        for (int u = 0; u < TN; ++u) {
            int j = tj + 16 * u;
            if (j < FOUT) Y[(size_t)gi * FOUT + j] = acc[m][u] * dv;
        }
    }
}

// ---------------------------------------------------------------------------
// Fused aggregate + next-layer GEMM:
//   h[i,:] = dinv_i*(A[i,:] + sum A[col,:]) + bias   (into LDS)
//   Y[i,:] = (h @ W) * dinv_i                        (pre-scaled for next agg)
// ---------------------------------------------------------------------------
template<int F, int FOUT>
__global__ __launch_bounds__(256) void agg_mm_kernel(
    const float* __restrict__ A, const int* __restrict__ rowptr,
    const int* __restrict__ col, const float* __restrict__ dinv,
    const float* __restrict__ bias, const float* __restrict__ W,
    float* __restrict__ Y, int n)
{
    constexpr int F4 = F / 4;
    constexpr int KP = F + 4;                       // sX stride
    constexpr int KC = (F % 32 == 0) ? 32 : F;      // W-chunk along k
    constexpr int NCHUNK = F / KC;
    constexpr int KP2 = KC + 4;                     // sW stride
    constexpr int TN = (FOUT + 15) / 16;
    constexpr int FOUTP = TN * 16;
    constexpr int BM = 64;

    __shared__ __align__(16) float sX[BM * KP];
    __shared__ __align__(16) float sW[FOUTP * KP2];

    const int tid = threadIdx.x;
    const int i0 = blockIdx.x * BM;

    // phase 1: gather-aggregate into LDS
    const float4* A4 = (const float4*)A;
    const float4* b4 = (const float4*)bias;
    for (int v = tid; v < BM * F4; v += 256) {
        int r = v / F4, f4 = v - r * F4;
        int gi = i0 + r;
        float rx = 0.f, ry = 0.f, rz = 0.f, rw = 0.f;
        if (gi < n) {
            float4 a = A4[(size_t)gi * F4 + f4];
            float ax = a.x, ay = a.y, az = a.z, aw = a.w;
            int s = rowptr[gi], e = rowptr[gi + 1];
            for (int k = s; k < e; ++k) {
                int c = col[k];
                float4 vv = A4[(size_t)c * F4 + f4];
                ax += vv.x; ay += vv.y; az += vv.z; aw += vv.w;
            }
            float dv = dinv[gi];
            float4 b = b4[f4];
            rx = ax * dv + b.x; ry = ay * dv + b.y;
            rz = az * dv + b.z; rw = aw * dv + b.w;
        }
        float* p = &sX[r * KP + f4 * 4];
        p[0] = rx; p[1] = ry; p[2] = rz; p[3] = rw;
    }

    // phase 2: GEMM from LDS
    float acc[4][TN] = {};
    const int tj = tid & 15;
    const int ti = tid >> 4;
    for (int c = 0; c < NCHUNK; ++c) {
        const int k0 = c * KC;
        __syncthreads();   // phase1 done / previous chunk compute done
        for (int v = tid; v < KC * FOUT; v += 256) {
            int kk = v / FOUT;
            int j = v - kk * FOUT;
            sW[j * KP2 + kk] = W[(size_t)(k0 + kk) * FOUT + j];
        }
        __syncthreads();
#pragma unroll
        for (int kk = 0; kk < KC; kk += 4) {
            float4 xv[4];
#pragma unroll
            for (int m = 0; m < 4; ++m)
                xv[m] = *(const float4*)&sX[(ti + 16 * m) * KP + k0 + kk];
#pragma unroll
            for (int u = 0; u < TN; ++u) {
                float4 wv = *(const float4*)&sW[(tj + 16 * u) * KP2 + kk];
#pragma unroll
                for (int m = 0; m < 4; ++m) {
                    acc[m][u] = fmaf(xv[m].x, wv.x, acc[m][u]);
                    acc[m][u] = fmaf(xv[m].y, wv.y, acc[m][u]);
                    acc[m][u] = fmaf(xv[m].z, wv.z, acc[m][u]);
                    acc[m][u] = fmaf(xv[m].w, wv.w, acc[m][u]);
                }
            }
        }
    }

#pragma unroll
    for (int m = 0; m < 4; ++m) {
        int gi = i0 + ti + 16 * m;
        if (gi >= n) continue;
        float dv = dinv[gi];
#pragma unroll
        for (int u = 0; u < TN; ++u) {
            int j = tj + 16 * u;
            if (j < FOUT) Y[(size_t)gi * FOUT + j] = acc[m][u] * dv;
        }
    }
}

// out[i,f] = dinv[i] * (hs[i,f] + sum hs[col,f]) + bias[f]
template<int F>
__global__ void agg_kernel(const float* __restrict__ hs, const int* __restrict__ rowptr,
                           const int* __restrict__ col, const float* __restrict__ dinv,
                           const float* __restrict__ bias, float* __restrict__ out, int n) {
    constexpr int F4 = F / 4;
    int tid = blockIdx.x * blockDim.x + threadIdx.x;
    if (tid >= n * F4) return;
    int i = tid / F4;
    int f = tid - i * F4;
    int s = rowptr[i], e = rowptr[i + 1];
    const float4* hs4 = (const float4*)hs;
    float4 a = hs4[(size_t)i * F4 + f];
    float ax = a.x, ay = a.y, az = a.z, aw = a.w;
    for (int k = s; k < e; k++) {
        int c = col[k];
        float4 v = hs4[(size_t)c * F4 + f];
        ax += v.x; ay += v.y; az += v.z; aw += v.w;
    }
    float dv = dinv[i];
    float4 b = ((const float4*)bias)[f];
    float4 r;
    r.x = ax * dv + b.x;
    r.y = ay * dv + b.y;
    r.z = az * dv + b.z;
    r.w = aw * dv + b.w;
    ((float4*)out)[(size_t)i * F4 + f] = r;
}

// ---- fused final layer: out = sigmoid([h2|xl|dw] @ Wf + bf) ----
template<int KC>
__device__ __forceinline__ void fuse_chunk(
    const float* __restrict__ src, int FIN, int k0, int wrow0,
    const float* __restrict__ Wf, float* sX, float* sW,
    float acc[4][3], int i0, int n, int tid)
{
    constexpr int K4 = KC / 4;
    constexpr int KP = 44;
    __syncthreads();   // guard previous chunk's compute
    for (int v = tid; v < 64 * K4; v += 256) {
        int r = v / K4, q = v - r * K4;
        int gi = i0 + r;
        float4 val = (gi < n) ? *(const float4*)(src + (size_t)gi * FIN + k0 + q * 4)
                              : make_float4(0.f, 0.f, 0.f, 0.f);
        float* p = &sX[r * KP + q * 4];
        p[0] = val.x; p[1] = val.y; p[2] = val.z; p[3] = val.w;
    }
    for (int v = tid; v < KC * 40; v += 256) {
        int kk = v / 40, j = v - kk * 40;
        sW[j * KP + kk] = Wf[(size_t)(wrow0 + kk) * 40 + j];
    }
    __syncthreads();
    int tj = tid & 15, ti = tid >> 4;
#pragma unroll
    for (int kk = 0; kk < KC; kk += 4) {
        float4 xv[4];
#pragma unroll
        for (int m = 0; m < 4; ++m)
            xv[m] = *(const float4*)&sX[(ti + 16 * m) * KP + kk];
#pragma unroll
        for (int u = 0; u < 3; ++u) {
            float4 wv = *(const float4*)&sW[(tj + 16 * u) * KP + kk];
#pragma unroll
            for (int m = 0; m < 4; ++m) {
                acc[m][u] = fmaf(xv[m].x, wv.x, acc[m][u]);
                acc[m][u] = fmaf(xv[m].y, wv.y, acc[m][u]);
                acc[m][u] = fmaf(xv[m].z, wv.z, acc[m][u]);
                acc[m][u] = fmaf(xv[m].w, wv.w, acc[m][u]);
            }
        }
    }
}

__global__ __launch_bounds__(256) void fuse_gemm_kernel(
    const float* __restrict__ h2, const float* __restrict__ xl,
    const float* __restrict__ dw, const float* __restrict__ Wf,
    const float* __restrict__ bf, float* __restrict__ out, int n)
{
    __shared__ __align__(16) float sX[64 * 44];
    __shared__ __align__(16) float sW[48 * 44];
    float acc[4][3] = {};
    const int tid = threadIdx.x;
    const int i0 = blockIdx.x * 64;
    fuse_chunk<32>(h2, 96, 0,  0,   Wf, sX, sW, acc, i0, n, tid);
    fuse_chunk<32>(h2, 96, 32, 32,  Wf, sX, sW, acc, i0, n, tid);
    fuse_chunk<32>(h2, 96, 64, 64,  Wf, sX, sW, acc, i0, n, tid);
    fuse_chunk<40>(xl, 40, 0,  96,  Wf, sX, sW, acc, i0, n, tid);
    fuse_chunk<32>(dw, 64, 0,  136, Wf, sX, sW, acc, i0, n, tid);
    fuse_chunk<32>(dw, 64, 32, 168, Wf, sX, sW, acc, i0, n, tid);
    const int tj = tid & 15, ti = tid >> 4;
#pragma unroll
    for (int m = 0; m < 4; ++m) {
        int gi = i0 + ti + 16 * m;
        if (gi >= n) continue;
#pragma unroll
        for (int u = 0; u < 3; ++u) {
            int j = tj + 16 * u;
            if (j < 40) {
                float t = acc[m][u] + bf[j];
                out[(size_t)gi * 40 + j] = 1.f / (1.f + expf(-t));
            }
        }
    }
}

extern "C" void kernel_launch(void* const* d_in, const int* in_sizes, int n_in,
                              void* d_out, int out_size, void* d_ws, size_t ws_size,
                              hipStream_t stream) {
    const float* x   = (const float*)d_in[0];
    const float* y   = (const float*)d_in[1];
    const int*   ei  = (const int*)d_in[2];
    const float* dwe = (const float*)d_in[3];
    const float* W1  = (const float*)d_in[4];
    const float* b1  = (const float*)d_in[5];
    const float* W2  = (const float*)d_in[6];
    const float* b2  = (const float*)d_in[7];
    const float* Wl  = (const float*)d_in[8];
    const float* bl  = (const float*)d_in[9];
    const float* Wf  = (const float*)d_in[10];
    const float* bf  = (const float*)d_in[11];
    float* out = (float*)d_out;

    const int n = in_sizes[0] / 128;
    const int E = in_sizes[2] / 2;
    const int* srcp = ei;
    const int* dstp = ei + E;

    char* ws = (char*)d_ws;
    size_t off = 0;
    auto alloc = [&](size_t bytes) -> void* {
        void* p = ws + off;
        off += bytes;
        off = (off + 255) & ~(size_t)255;
        return p;
    };

    int*   cnt     = (int*)alloc((size_t)n * 4);
    float* dinv    = (float*)alloc((size_t)n * 4);
    int*   rowptr  = (int*)alloc((size_t)(n + 1) * 4);
    int*   cursor  = (int*)alloc((size_t)n * 4);
    int*   partial = (int*)alloc(256 * 4);
    int*   col     = (int*)alloc((size_t)E * 4);
    float* A96     = (float*)alloc((size_t)n * 96 * 4);
    float* C96     = (float*)alloc((size_t)n * 96 * 4);
    float* LA      = (float*)alloc((size_t)n * 40 * 4);
    float* LB      = (float*)alloc((size_t)n * 40 * 4);
    (void)ws_size;

    const int gb_n   = (n + THREADS - 1) / THREADS;
    const int gb_e   = (E + THREADS - 1) / THREADS;
    const int NB     = (n + 1023) / 1024;                      // scan blocks
    const int gb_gm  = (n + 63) / 64;                          // 64-row tiles
    const int gb_a96 = (n * 24 + THREADS - 1) / THREADS;       // agg F=96 (float4)
    const int gb_a40 = (n * 10 + THREADS - 1) / THREADS;       // agg F=40 (float4)

    // ---- build CSR (by dst) + dinv ----
    zero_i32<<<gb_n, THREADS, 0, stream>>>(cnt, n);
    count_kernel<<<gb_e, THREADS, 0, stream>>>(dstp, cnt, E);
    dinv_kernel<<<gb_n, THREADS, 0, stream>>>(cnt, dinv, n);
    scan_p1<<<NB, THREADS, 0, stream>>>(cnt, partial, n);
    scan_p2<<<1, THREADS, 0, stream>>>(partial, rowptr, NB, n);
    scan_p3<<<NB, THREADS, 0, stream>>>(cnt, partial, rowptr, cursor, n);
    scatter_kernel<<<gb_e, THREADS, 0, stream>>>(srcp, dstp, cursor, col, E);

    // ---- label propagation first (smaller buffers): 10 GCN layers ----
    gemm_kernel<40, 40><<<gb_gm, THREADS, 0, stream>>>(y, Wl, dinv, LA, n);
    const float* cur = LA;
    for (int l = 0; l < 9; l++) {
        float* nxt = (l & 1) ? LA : LB;
        agg_mm_kernel<40, 40><<<gb_gm, THREADS, 0, stream>>>(
            cur, rowptr, col, dinv, bl + (size_t)l * 40, Wl + (size_t)(l + 1) * 1600, nxt, n);
        cur = nxt;
    }
    // cur == LB after 9 steps; final aggregation -> x_label in LA
    agg_kernel<40><<<gb_a40, THREADS, 0, stream>>>(cur, rowptr, col, dinv, bl + 9 * 40, LA, n);

    // ---- feature propagation: 2 GCN layers ----
    gemm_kernel<128, 96><<<gb_gm, THREADS, 0, stream>>>(x, W1, dinv, A96, n);
    agg_mm_kernel<96, 96><<<gb_gm, THREADS, 0, stream>>>(A96, rowptr, col, dinv, b1, W2, C96, n);
    agg_kernel<96><<<gb_a96, THREADS, 0, stream>>>(C96, rowptr, col, dinv, b2, A96, n);

    // ---- fuse + sigmoid ----
    fuse_gemm_kernel<<<gb_gm, THREADS, 0, stream>>>(A96, LA, dwe, Wf, bf, out, n);
}

// Round 4
// 688.468 us; speedup vs baseline: 2.5947x; 2.5947x over previous
//
#include <hip/hip_runtime.h>
#include <hip/hip_bf16.h>
#include <math.h>

#define THREADS 256
typedef _Float16 h16;

__device__ __forceinline__ void ld8h(const h16* p, float* f) {
    union { uint4 u; h16 h[8]; } c;
    c.u = *(const uint4*)p;
#pragma unroll
    for (int j = 0; j < 8; ++j) f[j] = (float)c.h[j];
}

__global__ void zero_i32(int* __restrict__ p, int n) {
    int i = blockIdx.x * blockDim.x + threadIdx.x;
    if (i < n) p[i] = 0;
}

__global__ void count_kernel(const int* __restrict__ dst, int* __restrict__ cnt, int E) {
    int e = blockIdx.x * blockDim.x + threadIdx.x;
    if (e < E) atomicAdd(&cnt[dst[e]], 1);
}

__global__ void dinv_kernel(const int* __restrict__ cnt, float* __restrict__ dinv, int n) {
    int i = blockIdx.x * blockDim.x + threadIdx.x;
    if (i < n) dinv[i] = rsqrtf((float)cnt[i] + 1.0f);
}

// ---- multi-block exclusive scan ----
__global__ __launch_bounds__(256) void scan_p1(const int* __restrict__ cnt, int* __restrict__ partial, int n) {
    __shared__ int red[256];
    int base = blockIdx.x * 1024 + threadIdx.x * 4;
    int s = 0;
    if (base + 3 < n) {
        int4 v = *(const int4*)(cnt + base);
        s = v.x + v.y + v.z + v.w;
    } else {
        for (int k = 0; k < 4; k++) { int i = base + k; if (i < n) s += cnt[i]; }
    }
    red[threadIdx.x] = s;
    __syncthreads();
    for (int off = 128; off > 0; off >>= 1) {
        if (threadIdx.x < off) red[threadIdx.x] += red[threadIdx.x + off];
        __syncthreads();
    }
    if (threadIdx.x == 0) partial[blockIdx.x] = red[0];
}

__global__ __launch_bounds__(256) void scan_p2(int* __restrict__ partial, int* __restrict__ rowptr, int nb, int n) {
    __shared__ int sm[256];
    int tid = threadIdx.x;
    int v = (tid < nb) ? partial[tid] : 0;
    sm[tid] = v;
    __syncthreads();
    int acc = v;
    for (int off = 1; off < 256; off <<= 1) {
        int t = (tid >= off) ? sm[tid - off] : 0;
        __syncthreads();
        acc += t;
        sm[tid] = acc;
        __syncthreads();
    }
    if (tid < nb) partial[tid] = acc - v;
    if (tid == 255) rowptr[n] = sm[255];
}

__global__ __launch_bounds__(256) void scan_p3(const int* __restrict__ cnt, const int* __restrict__ partial,
                                               int* __restrict__ rowptr, int* __restrict__ cursor, int n) {
    __shared__ int tsum[256];
    int tid = threadIdx.x;
    int base = blockIdx.x * 1024 + tid * 4;
    int v0 = 0, v1 = 0, v2 = 0, v3 = 0;
    if (base + 3 < n) {
        int4 t = *(const int4*)(cnt + base);
        v0 = t.x; v1 = t.y; v2 = t.z; v3 = t.w;
    } else {
        if (base + 0 < n) v0 = cnt[base + 0];
        if (base + 1 < n) v1 = cnt[base + 1];
        if (base + 2 < n) v2 = cnt[base + 2];
        if (base + 3 < n) v3 = cnt[base + 3];
    }
    int s = v0 + v1 + v2 + v3;
    tsum[tid] = s;
    __syncthreads();
    int acc = s;
    for (int off = 1; off < 256; off <<= 1) {
        int t = (tid >= off) ? tsum[tid - off] : 0;
        __syncthreads();
        acc += t;
        tsum[tid] = acc;
        __syncthreads();
    }
    int run = partial[blockIdx.x] + acc - s;
    int vv[4] = {v0, v1, v2, v3};
    for (int k = 0; k < 4; k++) {
        int i = base + k;
        if (i < n) { rowptr[i] = run; cursor[i] = run; run += vv[k]; }
    }
}

__global__ void scatter_kernel(const int* __restrict__ src, const int* __restrict__ dst,
                               int* __restrict__ cursor, int* __restrict__ col, int E) {
    int e = blockIdx.x * blockDim.x + threadIdx.x;
    if (e < E) {
        int d = dst[e];
        int p = atomicAdd(&cursor[d], 1);
        col[p] = src[e];
    }
}

// ---------------------------------------------------------------------------
// Register-tiled GEMM: Y = (X @ W) * dinv[i]   (pre-scaled for aggregation)
// TX in {float, h16}; Y stored as h16. fp32 accumulate.
// ---------------------------------------------------------------------------
template<int FIN, int FOUT, typename TX>
__global__ __launch_bounds__(256) void gemm_kernel(
    const TX* __restrict__ X, const float* __restrict__ W,
    const float* __restrict__ dinv, h16* __restrict__ Y, int n)
{
    constexpr int KC = (FIN % 32 == 0) ? 32 : FIN;
    constexpr int NCHUNK = FIN / KC;
    constexpr int TN = (FOUT + 15) / 16;
    constexpr int FOUTP = TN * 16;
    constexpr int BM = 64;
    constexpr int KP = KC + 4;

    __shared__ __align__(16) float sX[BM * KP];
    __shared__ __align__(16) float sW[FOUTP * KP];

    const int tid = threadIdx.x;
    const int tj = tid & 15;
    const int ti = tid >> 4;
    const int i0 = blockIdx.x * BM;

    float acc[4][TN] = {};

    for (int c = 0; c < NCHUNK; ++c) {
        const int k0 = c * KC;
        __syncthreads();
        if constexpr (sizeof(TX) == 2) {
            constexpr int K8 = KC / 8;
            for (int v = tid; v < BM * K8; v += 256) {
                int r = v / K8, q = v - r * K8;
                int gi = i0 + r;
                float f[8] = {0.f, 0.f, 0.f, 0.f, 0.f, 0.f, 0.f, 0.f};
                if (gi < n) ld8h((const h16*)X + (size_t)gi * FIN + k0 + q * 8, f);
                float* p = &sX[r * KP + q * 8];
#pragma unroll
                for (int j = 0; j < 8; ++j) p[j] = f[j];
            }
        } else {
            constexpr int K4 = KC / 4;
            for (int v = tid; v < BM * K4; v += 256) {
                int r = v / K4, q = v - r * K4;
                int gi = i0 + r;
                float4 val = (gi < n) ? *(const float4*)((const float*)X + (size_t)gi * FIN + k0 + q * 4)
                                      : make_float4(0.f, 0.f, 0.f, 0.f);
                float* p = &sX[r * KP + q * 4];
                p[0] = val.x; p[1] = val.y; p[2] = val.z; p[3] = val.w;
            }
        }
        for (int v = tid; v < KC * FOUT; v += 256) {
            int kk = v / FOUT;
            int j = v - kk * FOUT;
            sW[j * KP + kk] = W[(size_t)(k0 + kk) * FOUT + j];
        }
        __syncthreads();
#pragma unroll
        for (int kk = 0; kk < KC; kk += 4) {
            float4 xv[4];
#pragma unroll
            for (int m = 0; m < 4; ++m)
                xv[m] = *(const float4*)&sX[(ti + 16 * m) * KP + kk];
#pragma unroll
            for (int u = 0; u < TN; ++u) {
                float4 wv = *(const float4*)&sW[(tj + 16 * u) * KP + kk];
#pragma unroll
                for (int m = 0; m < 4; ++m) {
                    acc[m][u] = fmaf(xv[m].x, wv.x, acc[m][u]);
                    acc[m][u] = fmaf(xv[m].y, wv.y, acc[m][u]);
                    acc[m][u] = fmaf(xv[m].z, wv.z, acc[m][u]);
                    acc[m][u] = fmaf(xv[m].w, wv.w, acc[m][u]);
                }
            }
        }
    }

#pragma unroll
    for (int m = 0; m < 4; ++m) {
        int gi = i0 + ti + 16 * m;
        if (gi >= n) continue;
        float dv = dinv[gi];
#pragma unroll
        for (int u = 0; u < TN; ++u) {
            int j = tj + 16 * u;
            if (j < FOUT) Y[(size_t)gi * FOUT + j] = (h16)(acc[m][u] * dv);
        }
    }
}

// out[i,f] = dinv[i] * (hs[i,f] + sum hs[col,f]) + bias[f]   (fp16 storage)
// thread = (node, 8-feature group); fp32 accumulate
template<int F>
__global__ void agg_h(const h16* __restrict__ hs, const int* __restrict__ rowptr,
                      const int* __restrict__ col, const float* __restrict__ dinv,
                      const float* __restrict__ bias, h16* __restrict__ out, int n) {
    constexpr int F8 = F / 8;
    int tid = blockIdx.x * blockDim.x + threadIdx.x;
    if (tid >= n * F8) return;
    int i = tid / F8;
    int f = tid - i * F8;
    int s = rowptr[i], e = rowptr[i + 1];
    float acc[8];
    ld8h(hs + (size_t)i * F + f * 8, acc);
    for (int k = s; k < e; k++) {
        int c = col[k];
        float v[8];
        ld8h(hs + (size_t)c * F + f * 8, v);
#pragma unroll
        for (int j = 0; j < 8; ++j) acc[j] += v[j];
    }
    float dv = dinv[i];
    union { uint4 u; h16 h[8]; } o;
#pragma unroll
    for (int j = 0; j < 8; ++j) o.h[j] = (h16)(acc[j] * dv + bias[f * 8 + j]);
    *(uint4*)(out + (size_t)i * F + f * 8) = o.u;
}

// ---- fused final layer: out = sigmoid([h2|xl|dw] @ Wf + bf) ----
template<int KC, typename T>
__device__ __forceinline__ void fuse_chunk(
    const T* __restrict__ src, int FIN, int k0, int wrow0,
    const float* __restrict__ Wf, float* sX, float* sW,
    float acc[4][3], int i0, int n, int tid)
{
    constexpr int KP = 44;
    __syncthreads();
    if constexpr (sizeof(T) == 2) {
        constexpr int K8 = KC / 8;
        for (int v = tid; v < 64 * K8; v += 256) {
            int r = v / K8, q = v - r * K8;
            int gi = i0 + r;
            float f[8] = {0.f, 0.f, 0.f, 0.f, 0.f, 0.f, 0.f, 0.f};
            if (gi < n) ld8h((const h16*)src + (size_t)gi * FIN + k0 + q * 8, f);
            float* p = &sX[r * KP + q * 8];
#pragma unroll
            for (int j = 0; j < 8; ++j) p[j] = f[j];
        }
    } else {
        constexpr int K4 = KC / 4;
        for (int v = tid; v < 64 * K4; v += 256) {
            int r = v / K4, q = v - r * K4;
            int gi = i0 + r;
            float4 val = (gi < n) ? *(const float4*)((const float*)src + (size_t)gi * FIN + k0 + q * 4)
                                  : make_float4(0.f, 0.f, 0.f, 0.f);
            float* p = &sX[r * KP + q * 4];
            p[0] = val.x; p[1] = val.y; p[2] = val.z; p[3] = val.w;
        }
    }
    for (int v = tid; v < KC * 40; v += 256) {
        int kk = v / 40, j = v - kk * 40;
        sW[j * KP + kk] = Wf[(size_t)(wrow0 + kk) * 40 + j];
    }
    __syncthreads();
    int tj = tid & 15, ti = tid >> 4;
#pragma unroll
    for (int kk = 0; kk < KC; kk += 4) {
        float4 xv[4];
#pragma unroll
        for (int m = 0; m < 4; ++m)
            xv[m] = *(const float4*)&sX[(ti + 16 * m) * KP + kk];
#pragma unroll
        for (int u = 0; u < 3; ++u) {
            float4 wv = *(const float4*)&sW[(tj + 16 * u) * KP + kk];
#pragma unroll
            for (int m = 0; m < 4; ++m) {
                acc[m][u] = fmaf(xv[m].x, wv.x, acc[m][u]);
                acc[m][u] = fmaf(xv[m].y, wv.y, acc[m][u]);
                acc[m][u] = fmaf(xv[m].z, wv.z, acc[m][u]);
                acc[m][u] = fmaf(xv[m].w, wv.w, acc[m][u]);
            }
        }
    }
}

__global__ __launch_bounds__(256) void fuse_gemm_kernel(
    const h16* __restrict__ h2, const h16* __restrict__ xl,
    const float* __restrict__ dw, const float* __restrict__ Wf,
    const float* __restrict__ bf, float* __restrict__ out, int n)
{
    __shared__ __align__(16) float sX[64 * 44];
    __shared__ __align__(16) float sW[48 * 44];
    float acc[4][3] = {};
    const int tid = threadIdx.x;
    const int i0 = blockIdx.x * 64;
    fuse_chunk<32>(h2, 96, 0,  0,   Wf, sX, sW, acc, i0, n, tid);
    fuse_chunk<32>(h2, 96, 32, 32,  Wf, sX, sW, acc, i0, n, tid);
    fuse_chunk<32>(h2, 96, 64, 64,  Wf, sX, sW, acc, i0, n, tid);
    fuse_chunk<40>(xl, 40, 0,  96,  Wf, sX, sW, acc, i0, n, tid);
    fuse_chunk<32>(dw, 64, 0,  136, Wf, sX, sW, acc, i0, n, tid);
    fuse_chunk<32>(dw, 64, 32, 168, Wf, sX, sW, acc, i0, n, tid);
    const int tj = tid & 15, ti = tid >> 4;
#pragma unroll
    for (int m = 0; m < 4; ++m) {
        int gi = i0 + ti + 16 * m;
        if (gi >= n) continue;
#pragma unroll
        for (int u = 0; u < 3; ++u) {
            int j = tj + 16 * u;
            if (j < 40) {
                float t = acc[m][u] + bf[j];
                out[(size_t)gi * 40 + j] = 1.f / (1.f + expf(-t));
            }
        }
    }
}

extern "C" void kernel_launch(void* const* d_in, const int* in_sizes, int n_in,
                              void* d_out, int out_size, void* d_ws, size_t ws_size,
                              hipStream_t stream) {
    const float* x   = (const float*)d_in[0];
    const float* y   = (const float*)d_in[1];
    const int*   ei  = (const int*)d_in[2];
    const float* dwe = (const float*)d_in[3];
    const float* W1  = (const float*)d_in[4];
    const float* b1  = (const float*)d_in[5];
    const float* W2  = (const float*)d_in[6];
    const float* b2  = (const float*)d_in[7];
    const float* Wl  = (const float*)d_in[8];
    const float* bl  = (const float*)d_in[9];
    const float* Wf  = (const float*)d_in[10];
    const float* bf  = (const float*)d_in[11];
    float* out = (float*)d_out;

    const int n = in_sizes[0] / 128;
    const int E = in_sizes[2] / 2;
    const int* srcp = ei;
    const int* dstp = ei + E;

    char* ws = (char*)d_ws;
    size_t off = 0;
    auto alloc = [&](size_t bytes) -> void* {
        void* p = ws + off;
        off += bytes;
        off = (off + 255) & ~(size_t)255;
        return p;
    };

    int*   cnt     = (int*)alloc((size_t)n * 4);
    float* dinv    = (float*)alloc((size_t)n * 4);
    int*   rowptr  = (int*)alloc((size_t)(n + 1) * 4);
    int*   cursor  = (int*)alloc((size_t)n * 4);
    int*   partial = (int*)alloc(256 * 4);
    int*   col     = (int*)alloc((size_t)E * 4);
    h16*   A96     = (h16*)alloc((size_t)n * 96 * 2);
    h16*   B96     = (h16*)alloc((size_t)n * 96 * 2);
    h16*   T40     = (h16*)alloc((size_t)n * 40 * 2);
    h16*   LA      = (h16*)alloc((size_t)n * 40 * 2);
    h16*   LB      = (h16*)alloc((size_t)n * 40 * 2);
    (void)ws_size;

    const int gb_n    = (n + THREADS - 1) / THREADS;
    const int gb_e    = (E + THREADS - 1) / THREADS;
    const int NB      = (n + 1023) / 1024;
    const int gb_gm   = (n + 63) / 64;
    const int gb_a96  = (n * 12 + THREADS - 1) / THREADS;   // F=96, 8 halves/thread
    const int gb_a40  = (n * 5 + THREADS - 1) / THREADS;    // F=40, 8 halves/thread

    // ---- build CSR (by dst) + dinv ----
    zero_i32<<<gb_n, THREADS, 0, stream>>>(cnt, n);
    count_kernel<<<gb_e, THREADS, 0, stream>>>(dstp, cnt, E);
    dinv_kernel<<<gb_n, THREADS, 0, stream>>>(cnt, dinv, n);
    scan_p1<<<NB, THREADS, 0, stream>>>(cnt, partial, n);
    scan_p2<<<1, THREADS, 0, stream>>>(partial, rowptr, NB, n);
    scan_p3<<<NB, THREADS, 0, stream>>>(cnt, partial, rowptr, cursor, n);
    scatter_kernel<<<gb_e, THREADS, 0, stream>>>(srcp, dstp, cursor, col, E);

    // ---- label propagation: 10 GCN layers (standalone gemm + agg) ----
    gemm_kernel<40, 40, float><<<gb_gm, THREADS, 0, stream>>>(y, Wl, dinv, T40, n);
    const h16* xl = nullptr;
    for (int l = 0; l < 10; l++) {
        h16* aggout = (l & 1) ? LB : LA;
        agg_h<40><<<gb_a40, THREADS, 0, stream>>>(T40, rowptr, col, dinv, bl + (size_t)l * 40, aggout, n);
        if (l < 9)
            gemm_kernel<40, 40, h16><<<gb_gm, THREADS, 0, stream>>>(aggout, Wl + (size_t)(l + 1) * 1600, dinv, T40, n);
        xl = aggout;
    }

    // ---- feature propagation: 2 GCN layers ----
    gemm_kernel<128, 96, float><<<gb_gm, THREADS, 0, stream>>>(x, W1, dinv, A96, n);
    agg_h<96><<<gb_a96, THREADS, 0, stream>>>(A96, rowptr, col, dinv, b1, B96, n);
    gemm_kernel<96, 96, h16><<<gb_gm, THREADS, 0, stream>>>(B96, W2, dinv, A96, n);
    agg_h<96><<<gb_a96, THREADS, 0, stream>>>(A96, rowptr, col, dinv, b2, B96, n);

    // ---- fuse + sigmoid ----
    fuse_gemm_kernel<<<gb_gm, THREADS, 0, stream>>>(B96, xl, dwe, Wf, bf, out, n);
}

// Round 5
// 549.187 us; speedup vs baseline: 3.2528x; 1.2536x over previous
//
#include <hip/hip_runtime.h>
#include <hip/hip_bf16.h>
#include <math.h>

#define THREADS 256
typedef _Float16 h16;

__device__ __forceinline__ void ld8h(const h16* p, float* f) {
    union { uint4 u; h16 h[8]; } c;
    c.u = *(const uint4*)p;
#pragma unroll
    for (int j = 0; j < 8; ++j) f[j] = (float)c.h[j];
}

__global__ void zero_i32(int* __restrict__ p, int n) {
    int i = blockIdx.x * blockDim.x + threadIdx.x;
    if (i < n) p[i] = 0;
}

__global__ void count_kernel(const int* __restrict__ dst, int* __restrict__ cnt, int E) {
    int e = blockIdx.x * blockDim.x + threadIdx.x;
    if (e < E) atomicAdd(&cnt[dst[e]], 1);
}

__global__ void dinv_kernel(const int* __restrict__ cnt, float* __restrict__ dinv, int n) {
    int i = blockIdx.x * blockDim.x + threadIdx.x;
    if (i < n) dinv[i] = rsqrtf((float)cnt[i] + 1.0f);
}

// ---- multi-block exclusive scan ----
__global__ __launch_bounds__(256) void scan_p1(const int* __restrict__ cnt, int* __restrict__ partial, int n) {
    __shared__ int red[256];
    int base = blockIdx.x * 1024 + threadIdx.x * 4;
    int s = 0;
    if (base + 3 < n) {
        int4 v = *(const int4*)(cnt + base);
        s = v.x + v.y + v.z + v.w;
    } else {
        for (int k = 0; k < 4; k++) { int i = base + k; if (i < n) s += cnt[i]; }
    }
    red[threadIdx.x] = s;
    __syncthreads();
    for (int off = 128; off > 0; off >>= 1) {
        if (threadIdx.x < off) red[threadIdx.x] += red[threadIdx.x + off];
        __syncthreads();
    }
    if (threadIdx.x == 0) partial[blockIdx.x] = red[0];
}

__global__ __launch_bounds__(256) void scan_p2(int* __restrict__ partial, int* __restrict__ rowptr, int nb, int n) {
    __shared__ int sm[256];
    int tid = threadIdx.x;
    int v = (tid < nb) ? partial[tid] : 0;
    sm[tid] = v;
    __syncthreads();
    int acc = v;
    for (int off = 1; off < 256; off <<= 1) {
        int t = (tid >= off) ? sm[tid - off] : 0;
        __syncthreads();
        acc += t;
        sm[tid] = acc;
        __syncthreads();
    }
    if (tid < nb) partial[tid] = acc - v;
    if (tid == 255) rowptr[n] = sm[255];
}

__global__ __launch_bounds__(256) void scan_p3(const int* __restrict__ cnt, const int* __restrict__ partial,
                                               int* __restrict__ rowptr, int* __restrict__ cursor, int n) {
    __shared__ int tsum[256];
    int tid = threadIdx.x;
    int base = blockIdx.x * 1024 + tid * 4;
    int v0 = 0, v1 = 0, v2 = 0, v3 = 0;
    if (base + 3 < n) {
        int4 t = *(const int4*)(cnt + base);
        v0 = t.x; v1 = t.y; v2 = t.z; v3 = t.w;
    } else {
        if (base + 0 < n) v0 = cnt[base + 0];
        if (base + 1 < n) v1 = cnt[base + 1];
        if (base + 2 < n) v2 = cnt[base + 2];
        if (base + 3 < n) v3 = cnt[base + 3];
    }
    int s = v0 + v1 + v2 + v3;
    tsum[tid] = s;
    __syncthreads();
    int acc = s;
    for (int off = 1; off < 256; off <<= 1) {
        int t = (tid >= off) ? tsum[tid - off] : 0;
        __syncthreads();
        acc += t;
        tsum[tid] = acc;
        __syncthreads();
    }
    int run = partial[blockIdx.x] + acc - s;
    int vv[4] = {v0, v1, v2, v3};
    for (int k = 0; k < 4; k++) {
        int i = base + k;
        if (i < n) { rowptr[i] = run; cursor[i] = run; run += vv[k]; }
    }
}

__global__ void scatter_kernel(const int* __restrict__ src, const int* __restrict__ dst,
                               int* __restrict__ cursor, int* __restrict__ col, int E) {
    int e = blockIdx.x * blockDim.x + threadIdx.x;
    if (e < E) {
        int d = dst[e];
        int p = atomicAdd(&cursor[d], 1);
        col[p] = src[e];
    }
}

// ---------------------------------------------------------------------------
// Precompute collapsed weights:
//  block 0:      C_10 = I; C_m = W_{m+1} @ C_{m+1}; beta_m = b_m @ C_m (m=10..1)
//                outputs C0 (40x40) and betas[10][40]
//  blocks 1..48: W12 = W1(128x96) @ W2(96x96); block 1 also betaf1 = b1 @ W2
// ---------------------------------------------------------------------------
__global__ __launch_bounds__(256) void precompute_kernel(
    const float* __restrict__ Wl, const float* __restrict__ bl,
    const float* __restrict__ W1, const float* __restrict__ W2,
    const float* __restrict__ b1,
    float* __restrict__ C0, float* __restrict__ betas,
    float* __restrict__ W12, float* __restrict__ betaf1)
{
    const int tid = threadIdx.x;
    if (blockIdx.x == 0) {
        __shared__ float Ca[1600], Cb[1600];
        for (int idx = tid; idx < 1600; idx += 256)
            Ca[idx] = ((idx / 40) == (idx % 40)) ? 1.f : 0.f;
        if (tid < 40) betas[9 * 40 + tid] = bl[9 * 40 + tid];   // beta_10 = b_10
        __syncthreads();
        float* cur = Ca;
        float* nxt = Cb;
        for (int m = 9; m >= 0; --m) {
            for (int idx = tid; idx < 1600; idx += 256) {
                int i = idx / 40, j = idx - (idx / 40) * 40;
                float s = 0.f;
                const float* wr = Wl + (size_t)m * 1600 + i * 40;
#pragma unroll 8
                for (int k = 0; k < 40; ++k) s = fmaf(wr[k], cur[k * 40 + j], s);
                nxt[idx] = s;
            }
            __syncthreads();
            if (m >= 1 && tid < 40) {        // beta_m = b_m @ C_m
                float s = 0.f;
                const float* br = bl + (size_t)(m - 1) * 40;
                for (int k = 0; k < 40; ++k) s = fmaf(br[k], nxt[k * 40 + tid], s);
                betas[(size_t)(m - 1) * 40 + tid] = s;
            }
            float* t = cur; cur = nxt; nxt = t;
            __syncthreads();
        }
        for (int idx = tid; idx < 1600; idx += 256) C0[idx] = cur[idx];
    } else {
        int idx = (blockIdx.x - 1) * 256 + tid;   // 0..12287
        if (idx < 128 * 96) {
            int i = idx / 96, j = idx - (idx / 96) * 96;
            float s = 0.f;
            const float* wr = W1 + (size_t)i * 96;
#pragma unroll 8
            for (int k = 0; k < 96; ++k) s = fmaf(wr[k], W2[(size_t)k * 96 + j], s);
            W12[idx] = s;
        }
        if (blockIdx.x == 1 && tid < 96) {
            float s = 0.f;
            for (int k = 0; k < 96; ++k) s = fmaf(b1[k], W2[(size_t)k * 96 + tid], s);
            betaf1[tid] = s;
        }
    }
}

// ---------------------------------------------------------------------------
// Register-tiled GEMM: Y = (X @ W) * dinv[i]   (pre-scaled for aggregation)
// ---------------------------------------------------------------------------
template<int FIN, int FOUT, typename TX>
__global__ __launch_bounds__(256) void gemm_kernel(
    const TX* __restrict__ X, const float* __restrict__ W,
    const float* __restrict__ dinv, h16* __restrict__ Y, int n)
{
    constexpr int KC = (FIN % 32 == 0) ? 32 : FIN;
    constexpr int NCHUNK = FIN / KC;
    constexpr int TN = (FOUT + 15) / 16;
    constexpr int FOUTP = TN * 16;
    constexpr int BM = 64;
    constexpr int KP = KC + 4;

    __shared__ __align__(16) float sX[BM * KP];
    __shared__ __align__(16) float sW[FOUTP * KP];

    const int tid = threadIdx.x;
    const int tj = tid & 15;
    const int ti = tid >> 4;
    const int i0 = blockIdx.x * BM;

    float acc[4][TN] = {};

    for (int c = 0; c < NCHUNK; ++c) {
        const int k0 = c * KC;
        __syncthreads();
        if constexpr (sizeof(TX) == 2) {
            constexpr int K8 = KC / 8;
            for (int v = tid; v < BM * K8; v += 256) {
                int r = v / K8, q = v - r * K8;
                int gi = i0 + r;
                float f[8] = {0.f, 0.f, 0.f, 0.f, 0.f, 0.f, 0.f, 0.f};
                if (gi < n) ld8h((const h16*)X + (size_t)gi * FIN + k0 + q * 8, f);
                float* p = &sX[r * KP + q * 8];
#pragma unroll
                for (int j = 0; j < 8; ++j) p[j] = f[j];
            }
        } else {
            constexpr int K4 = KC / 4;
            for (int v = tid; v < BM * K4; v += 256) {
                int r = v / K4, q = v - r * K4;
                int gi = i0 + r;
                float4 val = (gi < n) ? *(const float4*)((const float*)X + (size_t)gi * FIN + k0 + q * 4)
                                      : make_float4(0.f, 0.f, 0.f, 0.f);
                float* p = &sX[r * KP + q * 4];
                p[0] = val.x; p[1] = val.y; p[2] = val.z; p[3] = val.w;
            }
        }
        for (int v = tid; v < KC * FOUT; v += 256) {
            int kk = v / FOUT;
            int j = v - kk * FOUT;
            sW[j * KP + kk] = W[(size_t)(k0 + kk) * FOUT + j];
        }
        __syncthreads();
#pragma unroll
        for (int kk = 0; kk < KC; kk += 4) {
            float4 xv[4];
#pragma unroll
            for (int m = 0; m < 4; ++m)
                xv[m] = *(const float4*)&sX[(ti + 16 * m) * KP + kk];
#pragma unroll
            for (int u = 0; u < TN; ++u) {
                float4 wv = *(const float4*)&sW[(tj + 16 * u) * KP + kk];
#pragma unroll
                for (int m = 0; m < 4; ++m) {
                    acc[m][u] = fmaf(xv[m].x, wv.x, acc[m][u]);
                    acc[m][u] = fmaf(xv[m].y, wv.y, acc[m][u]);
                    acc[m][u] = fmaf(xv[m].z, wv.z, acc[m][u]);
                    acc[m][u] = fmaf(xv[m].w, wv.w, acc[m][u]);
                }
            }
        }
    }

#pragma unroll
    for (int m = 0; m < 4; ++m) {
        int gi = i0 + ti + 16 * m;
        if (gi >= n) continue;
        float dv = dinv[gi];
#pragma unroll
        for (int u = 0; u < TN; ++u) {
            int j = tj + 16 * u;
            if (j < FOUT) Y[(size_t)gi * FOUT + j] = (h16)(acc[m][u] * dv);
        }
    }
}

// out[i,f] = dinv[i]*(hs[i,f] + sum hs[col,f]) + bias[f]; if PRE, out *= dinv[i]
template<int F, int PRE>
__global__ __launch_bounds__(256) void agg_h(
    const h16* __restrict__ hs, const int* __restrict__ rowptr,
    const int* __restrict__ col, const float* __restrict__ dinv,
    const float* __restrict__ bias, h16* __restrict__ out, int n) {
    constexpr int F8 = F / 8;
    int tid = blockIdx.x * blockDim.x + threadIdx.x;
    if (tid >= n * F8) return;
    int i = tid / F8;
    int f = tid - i * F8;
    int s = rowptr[i], e = rowptr[i + 1];
    float acc[8];
    ld8h(hs + (size_t)i * F + f * 8, acc);
    for (int k = s; k < e; k++) {
        int c = col[k];
        float v[8];
        ld8h(hs + (size_t)c * F + f * 8, v);
#pragma unroll
        for (int j = 0; j < 8; ++j) acc[j] += v[j];
    }
    float dv = dinv[i];
    float sc = PRE ? dv : 1.f;
    union { uint4 u; h16 h[8]; } o;
#pragma unroll
    for (int j = 0; j < 8; ++j) o.h[j] = (h16)((acc[j] * dv + bias[f * 8 + j]) * sc);
    *(uint4*)(out + (size_t)i * F + f * 8) = o.u;
}

// ---- fused final layer: out = sigmoid([h2|xl|dw] @ Wf + bf) ----
template<int KC, typename T>
__device__ __forceinline__ void fuse_chunk(
    const T* __restrict__ src, int FIN, int k0, int wrow0,
    const float* __restrict__ Wf, float* sX, float* sW,
    float acc[4][3], int i0, int n, int tid)
{
    constexpr int KP = 44;
    __syncthreads();
    if constexpr (sizeof(T) == 2) {
        constexpr int K8 = KC / 8;
        for (int v = tid; v < 64 * K8; v += 256) {
            int r = v / K8, q = v - r * K8;
            int gi = i0 + r;
            float f[8] = {0.f, 0.f, 0.f, 0.f, 0.f, 0.f, 0.f, 0.f};
            if (gi < n) ld8h((const h16*)src + (size_t)gi * FIN + k0 + q * 8, f);
            float* p = &sX[r * KP + q * 8];
#pragma unroll
            for (int j = 0; j < 8; ++j) p[j] = f[j];
        }
    } else {
        constexpr int K4 = KC / 4;
        for (int v = tid; v < 64 * K4; v += 256) {
            int r = v / K4, q = v - r * K4;
            int gi = i0 + r;
            float4 val = (gi < n) ? *(const float4*)((const float*)src + (size_t)gi * FIN + k0 + q * 4)
                                  : make_float4(0.f, 0.f, 0.f, 0.f);
            float* p = &sX[r * KP + q * 4];
            p[0] = val.x; p[1] = val.y; p[2] = val.z; p[3] = val.w;
        }
    }
    for (int v = tid; v < KC * 40; v += 256) {
        int kk = v / 40, j = v - kk * 40;
        sW[j * KP + kk] = Wf[(size_t)(wrow0 + kk) * 40 + j];
    }
    __syncthreads();
    int tj = tid & 15, ti = tid >> 4;
#pragma unroll
    for (int kk = 0; kk < KC; kk += 4) {
        float4 xv[4];
#pragma unroll
        for (int m = 0; m < 4; ++m)
            xv[m] = *(const float4*)&sX[(ti + 16 * m) * KP + kk];
#pragma unroll
        for (int u = 0; u < 3; ++u) {
            float4 wv = *(const float4*)&sW[(tj + 16 * u) * KP + kk];
#pragma unroll
            for (int m = 0; m < 4; ++m) {
                acc[m][u] = fmaf(xv[m].x, wv.x, acc[m][u]);
                acc[m][u] = fmaf(xv[m].y, wv.y, acc[m][u]);
                acc[m][u] = fmaf(xv[m].z, wv.z, acc[m][u]);
                acc[m][u] = fmaf(xv[m].w, wv.w, acc[m][u]);
            }
        }
    }
}

__global__ __launch_bounds__(256) void fuse_gemm_kernel(
    const h16* __restrict__ h2, const h16* __restrict__ xl,
    const float* __restrict__ dw, const float* __restrict__ Wf,
    const float* __restrict__ bf, float* __restrict__ out, int n)
{
    __shared__ __align__(16) float sX[64 * 44];
    __shared__ __align__(16) float sW[48 * 44];
    float acc[4][3] = {};
    const int tid = threadIdx.x;
    const int i0 = blockIdx.x * 64;
    fuse_chunk<32>(h2, 96, 0,  0,   Wf, sX, sW, acc, i0, n, tid);
    fuse_chunk<32>(h2, 96, 32, 32,  Wf, sX, sW, acc, i0, n, tid);
    fuse_chunk<32>(h2, 96, 64, 64,  Wf, sX, sW, acc, i0, n, tid);
    fuse_chunk<40>(xl, 40, 0,  96,  Wf, sX, sW, acc, i0, n, tid);
    fuse_chunk<32>(dw, 64, 0,  136, Wf, sX, sW, acc, i0, n, tid);
    fuse_chunk<32>(dw, 64, 32, 168, Wf, sX, sW, acc, i0, n, tid);
    const int tj = tid & 15, ti = tid >> 4;
#pragma unroll
    for (int m = 0; m < 4; ++m) {
        int gi = i0 + ti + 16 * m;
        if (gi >= n) continue;
#pragma unroll
        for (int u = 0; u < 3; ++u) {
            int j = tj + 16 * u;
            if (j < 40) {
                float t = acc[m][u] + bf[j];
                out[(size_t)gi * 40 + j] = 1.f / (1.f + expf(-t));
            }
        }
    }
}

extern "C" void kernel_launch(void* const* d_in, const int* in_sizes, int n_in,
                              void* d_out, int out_size, void* d_ws, size_t ws_size,
                              hipStream_t stream) {
    const float* x   = (const float*)d_in[0];
    const float* y   = (const float*)d_in[1];
    const int*   ei  = (const int*)d_in[2];
    const float* dwe = (const float*)d_in[3];
    const float* W1  = (const float*)d_in[4];
    const float* b1  = (const float*)d_in[5];
    const float* W2  = (const float*)d_in[6];
    const float* b2  = (const float*)d_in[7];
    const float* Wl  = (const float*)d_in[8];
    const float* bl  = (const float*)d_in[9];
    const float* Wf  = (const float*)d_in[10];
    const float* bf  = (const float*)d_in[11];
    float* out = (float*)d_out;

    const int n = in_sizes[0] / 128;
    const int E = in_sizes[2] / 2;
    const int* srcp = ei;
    const int* dstp = ei + E;

    char* ws = (char*)d_ws;
    size_t off = 0;
    auto alloc = [&](size_t bytes) -> void* {
        void* p = ws + off;
        off += bytes;
        off = (off + 255) & ~(size_t)255;
        return p;
    };

    int*   cnt     = (int*)alloc((size_t)n * 4);
    float* dinv    = (float*)alloc((size_t)n * 4);
    int*   rowptr  = (int*)alloc((size_t)(n + 1) * 4);
    int*   cursor  = (int*)alloc((size_t)n * 4);
    int*   partial = (int*)alloc(256 * 4);
    int*   col     = (int*)alloc((size_t)E * 4);
    h16*   A96     = (h16*)alloc((size_t)n * 96 * 2);
    h16*   B96     = (h16*)alloc((size_t)n * 96 * 2);
    h16*   Z0      = (h16*)alloc((size_t)n * 40 * 2);
    h16*   LA      = (h16*)alloc((size_t)n * 40 * 2);
    h16*   LB      = (h16*)alloc((size_t)n * 40 * 2);
    float* C0      = (float*)alloc(1600 * 4);
    float* betas   = (float*)alloc(10 * 40 * 4);
    float* W12     = (float*)alloc(128 * 96 * 4);
    float* betaf1  = (float*)alloc(96 * 4);
    (void)ws_size;

    const int gb_n    = (n + THREADS - 1) / THREADS;
    const int gb_e    = (E + THREADS - 1) / THREADS;
    const int NB      = (n + 1023) / 1024;
    const int gb_gm   = (n + 63) / 64;
    const int gb_a96  = (n * 12 + THREADS - 1) / THREADS;
    const int gb_a40  = (n * 5 + THREADS - 1) / THREADS;

    // ---- build CSR (by dst) + dinv ----
    zero_i32<<<gb_n, THREADS, 0, stream>>>(cnt, n);
    count_kernel<<<gb_e, THREADS, 0, stream>>>(dstp, cnt, E);
    dinv_kernel<<<gb_n, THREADS, 0, stream>>>(cnt, dinv, n);
    scan_p1<<<NB, THREADS, 0, stream>>>(cnt, partial, n);
    scan_p2<<<1, THREADS, 0, stream>>>(partial, rowptr, NB, n);
    scan_p3<<<NB, THREADS, 0, stream>>>(cnt, partial, rowptr, cursor, n);
    scatter_kernel<<<gb_e, THREADS, 0, stream>>>(srcp, dstp, cursor, col, E);

    // ---- collapse weights ----
    precompute_kernel<<<49, THREADS, 0, stream>>>(Wl, bl, W1, W2, b1, C0, betas, W12, betaf1);

    // ---- label propagation: z0 = y@C0, then 10 pure aggregations ----
    gemm_kernel<40, 40, float><<<gb_gm, THREADS, 0, stream>>>(y, C0, dinv, Z0, n);
    const h16* cur = Z0;
    const h16* xl = nullptr;
    for (int m = 1; m <= 10; m++) {
        h16* nxt = (m & 1) ? LA : LB;
        if (m < 10)
            agg_h<40, 1><<<gb_a40, THREADS, 0, stream>>>(cur, rowptr, col, dinv, betas + (size_t)(m - 1) * 40, nxt, n);
        else
            agg_h<40, 0><<<gb_a40, THREADS, 0, stream>>>(cur, rowptr, col, dinv, betas + (size_t)(m - 1) * 40, nxt, n);
        cur = nxt;
        xl = nxt;
    }

    // ---- feature propagation: x@W12, then 2 aggregations ----
    gemm_kernel<128, 96, float><<<gb_gm, THREADS, 0, stream>>>(x, W12, dinv, A96, n);
    agg_h<96, 1><<<gb_a96, THREADS, 0, stream>>>(A96, rowptr, col, dinv, betaf1, B96, n);
    agg_h<96, 0><<<gb_a96, THREADS, 0, stream>>>(B96, rowptr, col, dinv, b2, A96, n);

    // ---- fuse + sigmoid ----
    fuse_gemm_kernel<<<gb_gm, THREADS, 0, stream>>>(A96, xl, dwe, Wf, bf, out, n);
}

// Round 6
// 510.681 us; speedup vs baseline: 3.4980x; 1.0754x over previous
//
#include <hip/hip_runtime.h>
#include <hip/hip_bf16.h>
#include <math.h>

#define THREADS 256
typedef _Float16 h16;

__device__ __forceinline__ void ld8h(const h16* p, float* f) {
    union { uint4 u; h16 h[8]; } c;
    c.u = *(const uint4*)p;
#pragma unroll
    for (int j = 0; j < 8; ++j) f[j] = (float)c.h[j];
}

__global__ void count_kernel(const int* __restrict__ dst, int* __restrict__ cnt, int E) {
    int e = blockIdx.x * blockDim.x + threadIdx.x;
    if (e < E) atomicAdd(&cnt[dst[e]], 1);
}

// ---- multi-block exclusive scan ----
__global__ __launch_bounds__(256) void scan_p1(const int* __restrict__ cnt, int* __restrict__ partial, int n) {
    __shared__ int red[256];
    int base = blockIdx.x * 1024 + threadIdx.x * 4;
    int s = 0;
    if (base + 3 < n) {
        int4 v = *(const int4*)(cnt + base);
        s = v.x + v.y + v.z + v.w;
    } else {
        for (int k = 0; k < 4; k++) { int i = base + k; if (i < n) s += cnt[i]; }
    }
    red[threadIdx.x] = s;
    __syncthreads();
    for (int off = 128; off > 0; off >>= 1) {
        if (threadIdx.x < off) red[threadIdx.x] += red[threadIdx.x + off];
        __syncthreads();
    }
    if (threadIdx.x == 0) partial[blockIdx.x] = red[0];
}

__global__ __launch_bounds__(256) void scan_p2(int* __restrict__ partial, int* __restrict__ rowptr, int nb, int n) {
    __shared__ int sm[256];
    int tid = threadIdx.x;
    int v = (tid < nb) ? partial[tid] : 0;
    sm[tid] = v;
    __syncthreads();
    int acc = v;
    for (int off = 1; off < 256; off <<= 1) {
        int t = (tid >= off) ? sm[tid - off] : 0;
        __syncthreads();
        acc += t;
        sm[tid] = acc;
        __syncthreads();
    }
    if (tid < nb) partial[tid] = acc - v;
    if (tid == 255) rowptr[n] = sm[255];
}

// local scan + write rowptr/cursor + dinv (folded in)
__global__ __launch_bounds__(256) void scan_p3(const int* __restrict__ cnt, const int* __restrict__ partial,
                                               int* __restrict__ rowptr, int* __restrict__ cursor,
                                               float* __restrict__ dinv, int n) {
    __shared__ int tsum[256];
    int tid = threadIdx.x;
    int base = blockIdx.x * 1024 + tid * 4;
    int v0 = 0, v1 = 0, v2 = 0, v3 = 0;
    if (base + 3 < n) {
        int4 t = *(const int4*)(cnt + base);
        v0 = t.x; v1 = t.y; v2 = t.z; v3 = t.w;
    } else {
        if (base + 0 < n) v0 = cnt[base + 0];
        if (base + 1 < n) v1 = cnt[base + 1];
        if (base + 2 < n) v2 = cnt[base + 2];
        if (base + 3 < n) v3 = cnt[base + 3];
    }
    int s = v0 + v1 + v2 + v3;
    tsum[tid] = s;
    __syncthreads();
    int acc = s;
    for (int off = 1; off < 256; off <<= 1) {
        int t = (tid >= off) ? tsum[tid - off] : 0;
        __syncthreads();
        acc += t;
        tsum[tid] = acc;
        __syncthreads();
    }
    int run = partial[blockIdx.x] + acc - s;
    int vv[4] = {v0, v1, v2, v3};
    for (int k = 0; k < 4; k++) {
        int i = base + k;
        if (i < n) {
            rowptr[i] = run; cursor[i] = run; run += vv[k];
            dinv[i] = rsqrtf((float)vv[k] + 1.0f);
        }
    }
}

__global__ void scatter_kernel(const int* __restrict__ src, const int* __restrict__ dst,
                               int* __restrict__ cursor, int* __restrict__ col, int E) {
    int e = blockIdx.x * blockDim.x + threadIdx.x;
    if (e < E) {
        int d = dst[e];
        int p = atomicAdd(&cursor[d], 1);
        col[p] = src[e];
    }
}

// ---------------------------------------------------------------------------
// Precompute collapsed weights (LDS-staged operands):
//  block 0:      C_10 = I; C_m = W_{m+1} @ C_{m+1}; beta_m = b_m @ C_m
//  blocks 1..48: W12 = W1 @ W2 (W2 staged in LDS); block 1: betaf1 = b1 @ W2
// ---------------------------------------------------------------------------
__global__ __launch_bounds__(256) void precompute_kernel(
    const float* __restrict__ Wl, const float* __restrict__ bl,
    const float* __restrict__ W1, const float* __restrict__ W2,
    const float* __restrict__ b1,
    float* __restrict__ C0, float* __restrict__ betas,
    float* __restrict__ W12, float* __restrict__ betaf1)
{
    const int tid = threadIdx.x;
    if (blockIdx.x == 0) {
        __shared__ float Ca[1600], Cb[1600], sW[1600];
        for (int idx = tid; idx < 1600; idx += 256)
            Ca[idx] = ((idx / 40) == (idx % 40)) ? 1.f : 0.f;
        if (tid < 40) betas[9 * 40 + tid] = bl[9 * 40 + tid];   // beta_10 = b_10
        __syncthreads();
        float* cur = Ca;
        float* nxt = Cb;
        for (int m = 9; m >= 0; --m) {
            // stage Wl[m] (coalesced float4)
            for (int idx = tid; idx < 400; idx += 256)
                *(float4*)&sW[idx * 4] = *(const float4*)&Wl[(size_t)m * 1600 + idx * 4];
            __syncthreads();
            for (int idx = tid; idx < 1600; idx += 256) {
                int i = idx / 40, j = idx - (idx / 40) * 40;
                float s = 0.f;
                const float* wr = &sW[i * 40];
#pragma unroll
                for (int k = 0; k < 40; ++k) s = fmaf(wr[k], cur[k * 40 + j], s);
                nxt[idx] = s;
            }
            __syncthreads();
            if (m >= 1 && tid < 40) {        // beta_m = b_m @ C_m
                float s = 0.f;
                const float* br = bl + (size_t)(m - 1) * 40;
                for (int k = 0; k < 40; ++k) s = fmaf(br[k], nxt[k * 40 + tid], s);
                betas[(size_t)(m - 1) * 40 + tid] = s;
            }
            float* t = cur; cur = nxt; nxt = t;
            __syncthreads();
        }
        for (int idx = tid; idx < 1600; idx += 256) C0[idx] = cur[idx];
    } else {
        __shared__ float sW2[9216];          // 96x96
        for (int idx = tid; idx < 2304; idx += 256)
            *(float4*)&sW2[idx * 4] = *(const float4*)&W2[idx * 4];
        __syncthreads();
        int idx = (blockIdx.x - 1) * 256 + tid;   // 0..12287 == 128*96
        if (idx < 128 * 96) {
            int i = idx / 96, j = idx - (idx / 96) * 96;
            float s = 0.f;
            const float* wr = W1 + (size_t)i * 96;
#pragma unroll 8
            for (int k = 0; k < 96; ++k) s = fmaf(wr[k], sW2[k * 96 + j], s);
            W12[idx] = s;
        }
        if (blockIdx.x == 1 && tid < 96) {
            float s = 0.f;
            for (int k = 0; k < 96; ++k) s = fmaf(b1[k], sW2[k * 96 + tid], s);
            betaf1[tid] = s;
        }
    }
}

// ---------------------------------------------------------------------------
// Register-tiled GEMM: Y = (X @ W) * dinv[i]   (pre-scaled for aggregation)
// ---------------------------------------------------------------------------
template<int FIN, int FOUT, typename TX>
__global__ __launch_bounds__(256) void gemm_kernel(
    const TX* __restrict__ X, const float* __restrict__ W,
    const float* __restrict__ dinv, h16* __restrict__ Y, int n)
{
    constexpr int KC = (FIN % 32 == 0) ? 32 : FIN;
    constexpr int NCHUNK = FIN / KC;
    constexpr int TN = (FOUT + 15) / 16;
    constexpr int FOUTP = TN * 16;
    constexpr int BM = 64;
    constexpr int KP = KC + 4;

    __shared__ __align__(16) float sX[BM * KP];
    __shared__ __align__(16) float sW[FOUTP * KP];

    const int tid = threadIdx.x;
    const int tj = tid & 15;
    const int ti = tid >> 4;
    const int i0 = blockIdx.x * BM;

    float acc[4][TN] = {};

    for (int c = 0; c < NCHUNK; ++c) {
        const int k0 = c * KC;
        __syncthreads();
        if constexpr (sizeof(TX) == 2) {
            constexpr int K8 = KC / 8;
            for (int v = tid; v < BM * K8; v += 256) {
                int r = v / K8, q = v - r * K8;
                int gi = i0 + r;
                float f[8] = {0.f, 0.f, 0.f, 0.f, 0.f, 0.f, 0.f, 0.f};
                if (gi < n) ld8h((const h16*)X + (size_t)gi * FIN + k0 + q * 8, f);
                float* p = &sX[r * KP + q * 8];
#pragma unroll
                for (int j = 0; j < 8; ++j) p[j] = f[j];
            }
        } else {
            constexpr int K4 = KC / 4;
            for (int v = tid; v < BM * K4; v += 256) {
                int r = v / K4, q = v - r * K4;
                int gi = i0 + r;
                float4 val = (gi < n) ? *(const float4*)((const float*)X + (size_t)gi * FIN + k0 + q * 4)
                                      : make_float4(0.f, 0.f, 0.f, 0.f);
                float* p = &sX[r * KP + q * 4];
                p[0] = val.x; p[1] = val.y; p[2] = val.z; p[3] = val.w;
            }
        }
        for (int v = tid; v < KC * FOUT; v += 256) {
            int kk = v / FOUT;
            int j = v - kk * FOUT;
            sW[j * KP + kk] = W[(size_t)(k0 + kk) * FOUT + j];
        }
        __syncthreads();
#pragma unroll
        for (int kk = 0; kk < KC; kk += 4) {
            float4 xv[4];
#pragma unroll
            for (int m = 0; m < 4; ++m)
                xv[m] = *(const float4*)&sX[(ti + 16 * m) * KP + kk];
#pragma unroll
            for (int u = 0; u < TN; ++u) {
                float4 wv = *(const float4*)&sW[(tj + 16 * u) * KP + kk];
#pragma unroll
                for (int m = 0; m < 4; ++m) {
                    acc[m][u] = fmaf(xv[m].x, wv.x, acc[m][u]);
                    acc[m][u] = fmaf(xv[m].y, wv.y, acc[m][u]);
                    acc[m][u] = fmaf(xv[m].z, wv.z, acc[m][u]);
                    acc[m][u] = fmaf(xv[m].w, wv.w, acc[m][u]);
                }
            }
        }
    }

#pragma unroll
    for (int m = 0; m < 4; ++m) {
        int gi = i0 + ti + 16 * m;
        if (gi >= n) continue;
        float dv = dinv[gi];
#pragma unroll
        for (int u = 0; u < TN; ++u) {
            int j = tj + 16 * u;
            if (j < FOUT) Y[(size_t)gi * FOUT + j] = (h16)(acc[m][u] * dv);
        }
    }
}

// out[i,f] = dinv[i]*(hs[i,f] + sum hs[col,f]) + bias[f]; if PRE, out *= dinv[i]
template<int F, int PRE>
__global__ __launch_bounds__(256) void agg_h(
    const h16* __restrict__ hs, const int* __restrict__ rowptr,
    const int* __restrict__ col, const float* __restrict__ dinv,
    const float* __restrict__ bias, h16* __restrict__ out, int n) {
    constexpr int F8 = F / 8;
    int tid = blockIdx.x * blockDim.x + threadIdx.x;
    if (tid >= n * F8) return;
    int i = tid / F8;
    int f = tid - i * F8;
    int s = rowptr[i], e = rowptr[i + 1];
    float acc[8];
    ld8h(hs + (size_t)i * F + f * 8, acc);
    for (int k = s; k < e; k++) {
        int c = col[k];
        float v[8];
        ld8h(hs + (size_t)c * F + f * 8, v);
#pragma unroll
        for (int j = 0; j < 8; ++j) acc[j] += v[j];
    }
    float dv = dinv[i];
    float sc = PRE ? dv : 1.f;
    union { uint4 u; h16 h[8]; } o;
#pragma unroll
    for (int j = 0; j < 8; ++j) o.h[j] = (h16)((acc[j] * dv + bias[f * 8 + j]) * sc);
    *(uint4*)(out + (size_t)i * F + f * 8) = o.u;
}

// ---- fused final layer: out = sigmoid([h2|xl|dw] @ Wf + bf) ----
template<int KC, typename T>
__device__ __forceinline__ void fuse_chunk(
    const T* __restrict__ src, int FIN, int k0, int wrow0,
    const float* __restrict__ Wf, float* sX, float* sW,
    float acc[4][3], int i0, int n, int tid)
{
    constexpr int KP = 44;
    __syncthreads();
    if constexpr (sizeof(T) == 2) {
        constexpr int K8 = KC / 8;
        for (int v = tid; v < 64 * K8; v += 256) {
            int r = v / K8, q = v - r * K8;
            int gi = i0 + r;
            float f[8] = {0.f, 0.f, 0.f, 0.f, 0.f, 0.f, 0.f, 0.f};
            if (gi < n) ld8h((const h16*)src + (size_t)gi * FIN + k0 + q * 8, f);
            float* p = &sX[r * KP + q * 8];
#pragma unroll
            for (int j = 0; j < 8; ++j) p[j] = f[j];
        }
    } else {
        constexpr int K4 = KC / 4;
        for (int v = tid; v < 64 * K4; v += 256) {
            int r = v / K4, q = v - r * K4;
            int gi = i0 + r;
            float4 val = (gi < n) ? *(const float4*)((const float*)src + (size_t)gi * FIN + k0 + q * 4)
                                  : make_float4(0.f, 0.f, 0.f, 0.f);
            float* p = &sX[r * KP + q * 4];
            p[0] = val.x; p[1] = val.y; p[2] = val.z; p[3] = val.w;
        }
    }
    for (int v = tid; v < KC * 40; v += 256) {
        int kk = v / 40, j = v - kk * 40;
        sW[j * KP + kk] = Wf[(size_t)(wrow0 + kk) * 40 + j];
    }
    __syncthreads();
    int tj = tid & 15, ti = tid >> 4;
#pragma unroll
    for (int kk = 0; kk < KC; kk += 4) {
        float4 xv[4];
#pragma unroll
        for (int m = 0; m < 4; ++m)
            xv[m] = *(const float4*)&sX[(ti + 16 * m) * KP + kk];
#pragma unroll
        for (int u = 0; u < 3; ++u) {
            float4 wv = *(const float4*)&sW[(tj + 16 * u) * KP + kk];
#pragma unroll
            for (int m = 0; m < 4; ++m) {
                acc[m][u] = fmaf(xv[m].x, wv.x, acc[m][u]);
                acc[m][u] = fmaf(xv[m].y, wv.y, acc[m][u]);
                acc[m][u] = fmaf(xv[m].z, wv.z, acc[m][u]);
                acc[m][u] = fmaf(xv[m].w, wv.w, acc[m][u]);
            }
        }
    }
}

__global__ __launch_bounds__(256) void fuse_gemm_kernel(
    const h16* __restrict__ h2, const h16* __restrict__ xl,
    const float* __restrict__ dw, const float* __restrict__ Wf,
    const float* __restrict__ bf, float* __restrict__ out, int n)
{
    __shared__ __align__(16) float sX[64 * 44];
    __shared__ __align__(16) float sW[48 * 44];
    float acc[4][3] = {};
    const int tid = threadIdx.x;
    const int i0 = blockIdx.x * 64;
    fuse_chunk<32>(h2, 96, 0,  0,   Wf, sX, sW, acc, i0, n, tid);
    fuse_chunk<32>(h2, 96, 32, 32,  Wf, sX, sW, acc, i0, n, tid);
    fuse_chunk<32>(h2, 96, 64, 64,  Wf, sX, sW, acc, i0, n, tid);
    fuse_chunk<40>(xl, 40, 0,  96,  Wf, sX, sW, acc, i0, n, tid);
    fuse_chunk<32>(dw, 64, 0,  136, Wf, sX, sW, acc, i0, n, tid);
    fuse_chunk<32>(dw, 64, 32, 168, Wf, sX, sW, acc, i0, n, tid);
    const int tj = tid & 15, ti = tid >> 4;
#pragma unroll
    for (int m = 0; m < 4; ++m) {
        int gi = i0 + ti + 16 * m;
        if (gi >= n) continue;
#pragma unroll
        for (int u = 0; u < 3; ++u) {
            int j = tj + 16 * u;
            if (j < 40) {
                float t = acc[m][u] + bf[j];
                out[(size_t)gi * 40 + j] = 1.f / (1.f + expf(-t));
            }
        }
    }
}

extern "C" void kernel_launch(void* const* d_in, const int* in_sizes, int n_in,
                              void* d_out, int out_size, void* d_ws, size_t ws_size,
                              hipStream_t stream) {
    const float* x   = (const float*)d_in[0];
    const float* y   = (const float*)d_in[1];
    const int*   ei  = (const int*)d_in[2];
    const float* dwe = (const float*)d_in[3];
    const float* W1  = (const float*)d_in[4];
    const float* b1  = (const float*)d_in[5];
    const float* W2  = (const float*)d_in[6];
    const float* b2  = (const float*)d_in[7];
    const float* Wl  = (const float*)d_in[8];
    const float* bl  = (const float*)d_in[9];
    const float* Wf  = (const float*)d_in[10];
    const float* bf  = (const float*)d_in[11];
    float* out = (float*)d_out;

    const int n = in_sizes[0] / 128;
    const int E = in_sizes[2] / 2;
    const int* srcp = ei;
    const int* dstp = ei + E;

    char* ws = (char*)d_ws;
    size_t off = 0;
    auto alloc = [&](size_t bytes) -> void* {
        void* p = ws + off;
        off += bytes;
        off = (off + 255) & ~(size_t)255;
        return p;
    };

    int*   cnt     = (int*)alloc((size_t)n * 4);
    float* dinv    = (float*)alloc((size_t)n * 4);
    int*   rowptr  = (int*)alloc((size_t)(n + 1) * 4);
    int*   cursor  = (int*)alloc((size_t)n * 4);
    int*   partial = (int*)alloc(256 * 4);
    int*   col     = (int*)alloc((size_t)E * 4);
    h16*   A96     = (h16*)alloc((size_t)n * 96 * 2);
    h16*   B96     = (h16*)alloc((size_t)n * 96 * 2);
    h16*   Z0      = (h16*)alloc((size_t)n * 40 * 2);
    h16*   LA      = (h16*)alloc((size_t)n * 40 * 2);
    h16*   LB      = (h16*)alloc((size_t)n * 40 * 2);
    float* C0      = (float*)alloc(1600 * 4);
    float* betas   = (float*)alloc(10 * 40 * 4);
    float* W12     = (float*)alloc(128 * 96 * 4);
    float* betaf1  = (float*)alloc(96 * 4);
    (void)ws_size;

    const int gb_e    = (E + THREADS - 1) / THREADS;
    const int NB      = (n + 1023) / 1024;
    const int gb_gm   = (n + 63) / 64;
    const int gb_a96  = (n * 12 + THREADS - 1) / THREADS;
    const int gb_a40  = (n * 5 + THREADS - 1) / THREADS;

    // ---- collapse weights (independent of CSR; tiny) ----
    precompute_kernel<<<49, THREADS, 0, stream>>>(Wl, bl, W1, W2, b1, C0, betas, W12, betaf1);

    // ---- build CSR (by dst) + dinv ----
    hipMemsetAsync(cnt, 0, (size_t)n * 4, stream);
    count_kernel<<<gb_e, THREADS, 0, stream>>>(dstp, cnt, E);
    scan_p1<<<NB, THREADS, 0, stream>>>(cnt, partial, n);
    scan_p2<<<1, THREADS, 0, stream>>>(partial, rowptr, NB, n);
    scan_p3<<<NB, THREADS, 0, stream>>>(cnt, partial, rowptr, cursor, dinv, n);
    scatter_kernel<<<gb_e, THREADS, 0, stream>>>(srcp, dstp, cursor, col, E);

    // ---- label propagation: z0 = y@C0, then 10 pure aggregations ----
    gemm_kernel<40, 40, float><<<gb_gm, THREADS, 0, stream>>>(y, C0, dinv, Z0, n);
    const h16* cur = Z0;
    const h16* xl = nullptr;
    for (int m = 1; m <= 10; m++) {
        h16* nxt = (m & 1) ? LA : LB;
        if (m < 10)
            agg_h<40, 1><<<gb_a40, THREADS, 0, stream>>>(cur, rowptr, col, dinv, betas + (size_t)(m - 1) * 40, nxt, n);
        else
            agg_h<40, 0><<<gb_a40, THREADS, 0, stream>>>(cur, rowptr, col, dinv, betas + (size_t)(m - 1) * 40, nxt, n);
        cur = nxt;
        xl = nxt;
    }

    // ---- feature propagation: x@W12, then 2 aggregations ----
    gemm_kernel<128, 96, float><<<gb_gm, THREADS, 0, stream>>>(x, W12, dinv, A96, n);
    agg_h<96, 1><<<gb_a96, THREADS, 0, stream>>>(A96, rowptr, col, dinv, betaf1, B96, n);
    agg_h<96, 0><<<gb_a96, THREADS, 0, stream>>>(B96, rowptr, col, dinv, b2, A96, n);

    // ---- fuse + sigmoid ----
    fuse_gemm_kernel<<<gb_gm, THREADS, 0, stream>>>(A96, xl, dwe, Wf, bf, out, n);
}

// Round 7
// 482.364 us; speedup vs baseline: 3.7034x; 1.0587x over previous
//
#include <hip/hip_runtime.h>
#include <hip/hip_bf16.h>
#include <math.h>

#define THREADS 256
typedef _Float16 h16;

__device__ __forceinline__ void ld8h(const h16* p, float* f) {
    union { uint4 u; h16 h[8]; } c;
    c.u = *(const uint4*)p;
#pragma unroll
    for (int j = 0; j < 8; ++j) f[j] = (float)c.h[j];
}

// ---------------------------------------------------------------------------
// Merged: blocks [0, gbE) histogram dst; block gbE runs the 40x40 weight chain;
// blocks gbE+1 .. gbE+48 compute W12 = W1 @ W2 (and betaf1 in the first).
// ---------------------------------------------------------------------------
__global__ __launch_bounds__(256) void count_pre_kernel(
    const int* __restrict__ dst, int* __restrict__ cnt, int E, int gbE,
    const float* __restrict__ Wl, const float* __restrict__ bl,
    const float* __restrict__ W1, const float* __restrict__ W2,
    const float* __restrict__ b1,
    float* __restrict__ C0, float* __restrict__ betas,
    float* __restrict__ W12, float* __restrict__ betaf1)
{
    __shared__ __align__(16) float smem[9216];
    const int tid = threadIdx.x;
    const int bid = blockIdx.x;

    if (bid < gbE) {
        int e = bid * 256 + tid;
        if (e < E) atomicAdd(&cnt[dst[e]], 1);
        return;
    }

    if (bid == gbE) {
        // ---- label-prop weight chain: C_m = W_{m+1} @ C_{m+1}, beta_m = b_m @ C_m
        float* Ca  = smem;            // 1600
        float* Cb  = smem + 1600;     // 1600
        float* sWm = smem + 3200;     // 1600
        float* bls = smem + 4800;     // 400
        for (int idx = tid; idx < 100; idx += 256)
            ((float4*)bls)[idx] = ((const float4*)bl)[idx];
        for (int idx = tid; idx < 1600; idx += 256)
            Ca[idx] = ((idx / 40) == (idx % 40)) ? 1.f : 0.f;
        if (tid < 40) betas[9 * 40 + tid] = bl[9 * 40 + tid];   // beta_10 = b_10
        __syncthreads();
        float* cur = Ca;
        float* nxt = Cb;
        for (int m = 9; m >= 0; --m) {
            for (int idx = tid; idx < 400; idx += 256)
                ((float4*)sWm)[idx] = ((const float4*)(Wl + (size_t)m * 1600))[idx];
            __syncthreads();
            // strips: thread -> (row i, 4-col group jq)
            for (int sid = tid; sid < 400; sid += 256) {
                int i = sid / 10, jq = sid - (sid / 10) * 10;
                const float* wr = &sWm[i * 40];
                const float4* c4 = (const float4*)cur;
                float4 a = make_float4(0.f, 0.f, 0.f, 0.f);
#pragma unroll
                for (int k = 0; k < 40; ++k) {
                    float w = wr[k];
                    float4 c = c4[k * 10 + jq];
                    a.x = fmaf(w, c.x, a.x); a.y = fmaf(w, c.y, a.y);
                    a.z = fmaf(w, c.z, a.z); a.w = fmaf(w, c.w, a.w);
                }
                ((float4*)nxt)[sid] = a;
            }
            __syncthreads();
            if (m >= 1 && tid < 40) {
                float s = 0.f;
                const float* br = &bls[(m - 1) * 40];
#pragma unroll
                for (int k = 0; k < 40; ++k) s = fmaf(br[k], nxt[k * 40 + tid], s);
                betas[(size_t)(m - 1) * 40 + tid] = s;
            }
            float* t = cur; cur = nxt; nxt = t;
            __syncthreads();
        }
        for (int idx = tid; idx < 1600; idx += 256) C0[idx] = cur[idx];
        return;
    }

    // ---- W12 = W1 @ W2 (W2 staged in LDS) ----
    float* sW2 = smem;                // 9216 = 96x96
    for (int idx = tid; idx < 2304; idx += 256)
        ((float4*)sW2)[idx] = ((const float4*)W2)[idx];
    __syncthreads();
    int idx = (bid - gbE - 1) * 256 + tid;   // 0..12287 == 128*96
    {
        int i = idx / 96, j = idx - (idx / 96) * 96;
        float s = 0.f;
        const float* wr = W1 + (size_t)i * 96;
#pragma unroll 8
        for (int k = 0; k < 96; ++k) s = fmaf(wr[k], sW2[k * 96 + j], s);
        W12[idx] = s;
    }
    if (bid == gbE + 1 && tid < 96) {
        float s = 0.f;
        for (int k = 0; k < 96; ++k) s = fmaf(b1[k], sW2[k * 96 + tid], s);
        betaf1[tid] = s;
    }
}

// ---- multi-block exclusive scan ----
__global__ __launch_bounds__(256) void scan_p1(const int* __restrict__ cnt, int* __restrict__ partial, int n) {
    __shared__ int red[256];
    int base = blockIdx.x * 1024 + threadIdx.x * 4;
    int s = 0;
    if (base + 3 < n) {
        int4 v = *(const int4*)(cnt + base);
        s = v.x + v.y + v.z + v.w;
    } else {
        for (int k = 0; k < 4; k++) { int i = base + k; if (i < n) s += cnt[i]; }
    }
    red[threadIdx.x] = s;
    __syncthreads();
    for (int off = 128; off > 0; off >>= 1) {
        if (threadIdx.x < off) red[threadIdx.x] += red[threadIdx.x + off];
        __syncthreads();
    }
    if (threadIdx.x == 0) partial[blockIdx.x] = red[0];
}

__global__ __launch_bounds__(256) void scan_p2(int* __restrict__ partial, int* __restrict__ rowptr, int nb, int n) {
    __shared__ int sm[256];
    int tid = threadIdx.x;
    int v = (tid < nb) ? partial[tid] : 0;
    sm[tid] = v;
    __syncthreads();
    int acc = v;
    for (int off = 1; off < 256; off <<= 1) {
        int t = (tid >= off) ? sm[tid - off] : 0;
        __syncthreads();
        acc += t;
        sm[tid] = acc;
        __syncthreads();
    }
    if (tid < nb) partial[tid] = acc - v;
    if (tid == 255) rowptr[n] = sm[255];
}

// local scan + write rowptr/cursor + dinv (folded in)
__global__ __launch_bounds__(256) void scan_p3(const int* __restrict__ cnt, const int* __restrict__ partial,
                                               int* __restrict__ rowptr, int* __restrict__ cursor,
                                               float* __restrict__ dinv, int n) {
    __shared__ int tsum[256];
    int tid = threadIdx.x;
    int base = blockIdx.x * 1024 + tid * 4;
    int v0 = 0, v1 = 0, v2 = 0, v3 = 0;
    if (base + 3 < n) {
        int4 t = *(const int4*)(cnt + base);
        v0 = t.x; v1 = t.y; v2 = t.z; v3 = t.w;
    } else {
        if (base + 0 < n) v0 = cnt[base + 0];
        if (base + 1 < n) v1 = cnt[base + 1];
        if (base + 2 < n) v2 = cnt[base + 2];
        if (base + 3 < n) v3 = cnt[base + 3];
    }
    int s = v0 + v1 + v2 + v3;
    tsum[tid] = s;
    __syncthreads();
    int acc = s;
    for (int off = 1; off < 256; off <<= 1) {
        int t = (tid >= off) ? tsum[tid - off] : 0;
        __syncthreads();
        acc += t;
        tsum[tid] = acc;
        __syncthreads();
    }
    int run = partial[blockIdx.x] + acc - s;
    int vv[4] = {v0, v1, v2, v3};
    for (int k = 0; k < 4; k++) {
        int i = base + k;
        if (i < n) {
            rowptr[i] = run; cursor[i] = run; run += vv[k];
            dinv[i] = rsqrtf((float)vv[k] + 1.0f);
        }
    }
}

__global__ void scatter_kernel(const int* __restrict__ src, const int* __restrict__ dst,
                               int* __restrict__ cursor, int* __restrict__ col, int E) {
    int e = blockIdx.x * blockDim.x + threadIdx.x;
    if (e < E) {
        int d = dst[e];
        int p = atomicAdd(&cursor[d], 1);
        col[p] = src[e];
    }
}

// ---------------------------------------------------------------------------
// Register-tiled GEMM: Y = (X @ W) * dinv[i]   (pre-scaled for aggregation)
// ---------------------------------------------------------------------------
template<int FIN, int FOUT, typename TX>
__global__ __launch_bounds__(256) void gemm_kernel(
    const TX* __restrict__ X, const float* __restrict__ W,
    const float* __restrict__ dinv, h16* __restrict__ Y, int n)
{
    constexpr int KC = (FIN % 32 == 0) ? 32 : FIN;
    constexpr int NCHUNK = FIN / KC;
    constexpr int TN = (FOUT + 15) / 16;
    constexpr int FOUTP = TN * 16;
    constexpr int BM = 64;
    constexpr int KP = KC + 4;

    __shared__ __align__(16) float sX[BM * KP];
    __shared__ __align__(16) float sW[FOUTP * KP];

    const int tid = threadIdx.x;
    const int tj = tid & 15;
    const int ti = tid >> 4;
    const int i0 = blockIdx.x * BM;

    float acc[4][TN] = {};

    for (int c = 0; c < NCHUNK; ++c) {
        const int k0 = c * KC;
        __syncthreads();
        if constexpr (sizeof(TX) == 2) {
            constexpr int K8 = KC / 8;
            for (int v = tid; v < BM * K8; v += 256) {
                int r = v / K8, q = v - r * K8;
                int gi = i0 + r;
                float f[8] = {0.f, 0.f, 0.f, 0.f, 0.f, 0.f, 0.f, 0.f};
                if (gi < n) ld8h((const h16*)X + (size_t)gi * FIN + k0 + q * 8, f);
                float* p = &sX[r * KP + q * 8];
#pragma unroll
                for (int j = 0; j < 8; ++j) p[j] = f[j];
            }
        } else {
            constexpr int K4 = KC / 4;
            for (int v = tid; v < BM * K4; v += 256) {
                int r = v / K4, q = v - r * K4;
                int gi = i0 + r;
                float4 val = (gi < n) ? *(const float4*)((const float*)X + (size_t)gi * FIN + k0 + q * 4)
                                      : make_float4(0.f, 0.f, 0.f, 0.f);
                float* p = &sX[r * KP + q * 4];
                p[0] = val.x; p[1] = val.y; p[2] = val.z; p[3] = val.w;
            }
        }
        for (int v = tid; v < KC * FOUT; v += 256) {
            int kk = v / FOUT;
            int j = v - kk * FOUT;
            sW[j * KP + kk] = W[(size_t)(k0 + kk) * FOUT + j];
        }
        __syncthreads();
#pragma unroll
        for (int kk = 0; kk < KC; kk += 4) {
            float4 xv[4];
#pragma unroll
            for (int m = 0; m < 4; ++m)
                xv[m] = *(const float4*)&sX[(ti + 16 * m) * KP + kk];
#pragma unroll
            for (int u = 0; u < TN; ++u) {
                float4 wv = *(const float4*)&sW[(tj + 16 * u) * KP + kk];
#pragma unroll
                for (int m = 0; m < 4; ++m) {
                    acc[m][u] = fmaf(xv[m].x, wv.x, acc[m][u]);
                    acc[m][u] = fmaf(xv[m].y, wv.y, acc[m][u]);
                    acc[m][u] = fmaf(xv[m].z, wv.z, acc[m][u]);
                    acc[m][u] = fmaf(xv[m].w, wv.w, acc[m][u]);
                }
            }
        }
    }

#pragma unroll
    for (int m = 0; m < 4; ++m) {
        int gi = i0 + ti + 16 * m;
        if (gi >= n) continue;
        float dv = dinv[gi];
#pragma unroll
        for (int u = 0; u < TN; ++u) {
            int j = tj + 16 * u;
            if (j < FOUT) Y[(size_t)gi * FOUT + j] = (h16)(acc[m][u] * dv);
        }
    }
}

// out[i,f] = dinv[i]*(hs[i,f] + sum hs[col,f]) + bias[f]; if PRE, out *= dinv[i]
template<int F, int PRE>
__global__ __launch_bounds__(256) void agg_h(
    const h16* __restrict__ hs, const int* __restrict__ rowptr,
    const int* __restrict__ col, const float* __restrict__ dinv,
    const float* __restrict__ bias, h16* __restrict__ out, int n) {
    constexpr int F8 = F / 8;
    int tid = blockIdx.x * blockDim.x + threadIdx.x;
    if (tid >= n * F8) return;
    int i = tid / F8;
    int f = tid - i * F8;
    int s = rowptr[i], e = rowptr[i + 1];
    float acc[8];
    ld8h(hs + (size_t)i * F + f * 8, acc);
    for (int k = s; k < e; k++) {
        int c = col[k];
        float v[8];
        ld8h(hs + (size_t)c * F + f * 8, v);
#pragma unroll
        for (int j = 0; j < 8; ++j) acc[j] += v[j];
    }
    float dv = dinv[i];
    float sc = PRE ? dv : 1.f;
    union { uint4 u; h16 h[8]; } o;
#pragma unroll
    for (int j = 0; j < 8; ++j) o.h[j] = (h16)((acc[j] * dv + bias[f * 8 + j]) * sc);
    *(uint4*)(out + (size_t)i * F + f * 8) = o.u;
}

// ---- fused final layer: out = sigmoid([h2|xl|dw] @ Wf + bf) ----
template<int KC, typename T>
__device__ __forceinline__ void fuse_chunk(
    const T* __restrict__ src, int FIN, int k0, int wrow0,
    const float* __restrict__ Wf, float* sX, float* sW,
    float acc[4][3], int i0, int n, int tid)
{
    constexpr int KP = 44;
    __syncthreads();
    if constexpr (sizeof(T) == 2) {
        constexpr int K8 = KC / 8;
        for (int v = tid; v < 64 * K8; v += 256) {
            int r = v / K8, q = v - r * K8;
            int gi = i0 + r;
            float f[8] = {0.f, 0.f, 0.f, 0.f, 0.f, 0.f, 0.f, 0.f};
            if (gi < n) ld8h((const h16*)src + (size_t)gi * FIN + k0 + q * 8, f);
            float* p = &sX[r * KP + q * 8];
#pragma unroll
            for (int j = 0; j < 8; ++j) p[j] = f[j];
        }
    } else {
        constexpr int K4 = KC / 4;
        for (int v = tid; v < 64 * K4; v += 256) {
            int r = v / K4, q = v - r * K4;
            int gi = i0 + r;
            float4 val = (gi < n) ? *(const float4*)((const float*)src + (size_t)gi * FIN + k0 + q * 4)
                                  : make_float4(0.f, 0.f, 0.f, 0.f);
            float* p = &sX[r * KP + q * 4];
            p[0] = val.x; p[1] = val.y; p[2] = val.z; p[3] = val.w;
        }
    }
    for (int v = tid; v < KC * 40; v += 256) {
        int kk = v / 40, j = v - kk * 40;
        sW[j * KP + kk] = Wf[(size_t)(wrow0 + kk) * 40 + j];
    }
    __syncthreads();
    int tj = tid & 15, ti = tid >> 4;
#pragma unroll
    for (int kk = 0; kk < KC; kk += 4) {
        float4 xv[4];
#pragma unroll
        for (int m = 0; m < 4; ++m)
            xv[m] = *(const float4*)&sX[(ti + 16 * m) * KP + kk];
#pragma unroll
        for (int u = 0; u < 3; ++u) {
            float4 wv = *(const float4*)&sW[(tj + 16 * u) * KP + kk];
#pragma unroll
            for (int m = 0; m < 4; ++m) {
                acc[m][u] = fmaf(xv[m].x, wv.x, acc[m][u]);
                acc[m][u] = fmaf(xv[m].y, wv.y, acc[m][u]);
                acc[m][u] = fmaf(xv[m].z, wv.z, acc[m][u]);
                acc[m][u] = fmaf(xv[m].w, wv.w, acc[m][u]);
            }
        }
    }
}

__global__ __launch_bounds__(256) void fuse_gemm_kernel(
    const h16* __restrict__ h2, const h16* __restrict__ xl,
    const float* __restrict__ dw, const float* __restrict__ Wf,
    const float* __restrict__ bf, float* __restrict__ out, int n)
{
    __shared__ __align__(16) float sX[64 * 44];
    __shared__ __align__(16) float sW[48 * 44];
    float acc[4][3] = {};
    const int tid = threadIdx.x;
    const int i0 = blockIdx.x * 64;
    fuse_chunk<32>(h2, 96, 0,  0,   Wf, sX, sW, acc, i0, n, tid);
    fuse_chunk<32>(h2, 96, 32, 32,  Wf, sX, sW, acc, i0, n, tid);
    fuse_chunk<32>(h2, 96, 64, 64,  Wf, sX, sW, acc, i0, n, tid);
    fuse_chunk<40>(xl, 40, 0,  96,  Wf, sX, sW, acc, i0, n, tid);
    fuse_chunk<32>(dw, 64, 0,  136, Wf, sX, sW, acc, i0, n, tid);
    fuse_chunk<32>(dw, 64, 32, 168, Wf, sX, sW, acc, i0, n, tid);
    const int tj = tid & 15, ti = tid >> 4;
#pragma unroll
    for (int m = 0; m < 4; ++m) {
        int gi = i0 + ti + 16 * m;
        if (gi >= n) continue;
#pragma unroll
        for (int u = 0; u < 3; ++u) {
            int j = tj + 16 * u;
            if (j < 40) {
                float t = acc[m][u] + bf[j];
                out[(size_t)gi * 40 + j] = 1.f / (1.f + expf(-t));
            }
        }
    }
}

extern "C" void kernel_launch(void* const* d_in, const int* in_sizes, int n_in,
                              void* d_out, int out_size, void* d_ws, size_t ws_size,
                              hipStream_t stream) {
    const float* x   = (const float*)d_in[0];
    const float* y   = (const float*)d_in[1];
    const int*   ei  = (const int*)d_in[2];
    const float* dwe = (const float*)d_in[3];
    const float* W1  = (const float*)d_in[4];
    const float* b1  = (const float*)d_in[5];
    const float* W2  = (const float*)d_in[6];
    const float* b2  = (const float*)d_in[7];
    const float* Wl  = (const float*)d_in[8];
    const float* bl  = (const float*)d_in[9];
    const float* Wf  = (const float*)d_in[10];
    const float* bf  = (const float*)d_in[11];
    float* out = (float*)d_out;

    const int n = in_sizes[0] / 128;
    const int E = in_sizes[2] / 2;
    const int* srcp = ei;
    const int* dstp = ei + E;

    char* ws = (char*)d_ws;
    size_t off = 0;
    auto alloc = [&](size_t bytes) -> void* {
        void* p = ws + off;
        off += bytes;
        off = (off + 255) & ~(size_t)255;
        return p;
    };

    int*   cnt     = (int*)alloc((size_t)n * 4);
    float* dinv    = (float*)alloc((size_t)n * 4);
    int*   rowptr  = (int*)alloc((size_t)(n + 1) * 4);
    int*   cursor  = (int*)alloc((size_t)n * 4);
    int*   partial = (int*)alloc(256 * 4);
    int*   col     = (int*)alloc((size_t)E * 4);
    h16*   A96     = (h16*)alloc((size_t)n * 96 * 2);
    h16*   B96     = (h16*)alloc((size_t)n * 96 * 2);
    h16*   Z0      = (h16*)alloc((size_t)n * 40 * 2);
    h16*   LA      = (h16*)alloc((size_t)n * 40 * 2);
    h16*   LB      = (h16*)alloc((size_t)n * 40 * 2);
    float* C0      = (float*)alloc(1600 * 4);
    float* betas   = (float*)alloc(10 * 40 * 4);
    float* W12     = (float*)alloc(128 * 96 * 4);
    float* betaf1  = (float*)alloc(96 * 4);
    (void)ws_size;

    const int gb_e    = (E + THREADS - 1) / THREADS;
    const int NB      = (n + 1023) / 1024;
    const int gb_gm   = (n + 63) / 64;
    const int gb_a96  = (n * 12 + THREADS - 1) / THREADS;
    const int gb_a40  = (n * 5 + THREADS - 1) / THREADS;

    // ---- CSR count + (hidden) weight collapse in one dispatch ----
    hipMemsetAsync(cnt, 0, (size_t)n * 4, stream);
    count_pre_kernel<<<gb_e + 49, THREADS, 0, stream>>>(
        dstp, cnt, E, gb_e, Wl, bl, W1, W2, b1, C0, betas, W12, betaf1);

    // ---- rest of CSR build ----
    scan_p1<<<NB, THREADS, 0, stream>>>(cnt, partial, n);
    scan_p2<<<1, THREADS, 0, stream>>>(partial, rowptr, NB, n);
    scan_p3<<<NB, THREADS, 0, stream>>>(cnt, partial, rowptr, cursor, dinv, n);
    scatter_kernel<<<gb_e, THREADS, 0, stream>>>(srcp, dstp, cursor, col, E);

    // ---- label propagation: z0 = y@C0, then 10 pure aggregations ----
    gemm_kernel<40, 40, float><<<gb_gm, THREADS, 0, stream>>>(y, C0, dinv, Z0, n);
    const h16* cur = Z0;
    const h16* xl = nullptr;
    for (int m = 1; m <= 10; m++) {
        h16* nxt = (m & 1) ? LA : LB;
        if (m < 10)
            agg_h<40, 1><<<gb_a40, THREADS, 0, stream>>>(cur, rowptr, col, dinv, betas + (size_t)(m - 1) * 40, nxt, n);
        else
            agg_h<40, 0><<<gb_a40, THREADS, 0, stream>>>(cur, rowptr, col, dinv, betas + (size_t)(m - 1) * 40, nxt, n);
        cur = nxt;
        xl = nxt;
    }

    // ---- feature propagation: x@W12, then 2 aggregations ----
    gemm_kernel<128, 96, float><<<gb_gm, THREADS, 0, stream>>>(x, W12, dinv, A96, n);
    agg_h<96, 1><<<gb_a96, THREADS, 0, stream>>>(A96, rowptr, col, dinv, betaf1, B96, n);
    agg_h<96, 0><<<gb_a96, THREADS, 0, stream>>>(B96, rowptr, col, dinv, b2, A96, n);

    // ---- fuse + sigmoid ----
    fuse_gemm_kernel<<<gb_gm, THREADS, 0, stream>>>(A96, xl, dwe, Wf, bf, out, n);
}

// Round 8
// 443.353 us; speedup vs baseline: 4.0293x; 1.0880x over previous
//
#include <hip/hip_runtime.h>
#include <hip/hip_bf16.h>
#include <math.h>

#define THREADS 256
typedef _Float16 h16;

__device__ __forceinline__ void ld8h(const h16* p, float* f) {
    union { uint4 u; h16 h[8]; } c;
    c.u = *(const uint4*)p;
#pragma unroll
    for (int j = 0; j < 8; ++j) f[j] = (float)c.h[j];
}

__global__ void count_kernel(const int* __restrict__ dst, int* __restrict__ cnt, int E) {
    int e = blockIdx.x * blockDim.x + threadIdx.x;
    if (e < E) atomicAdd(&cnt[dst[e]], 1);
}

// ---------------------------------------------------------------------------
// scan_p1 (blocks [0,NB)) + weight collapse (block NB: 40x40 chain;
// blocks NB+1..NB+48: W12 = W1@W2, first also betaf1 = b1@W2)
// ---------------------------------------------------------------------------
__global__ __launch_bounds__(256) void scanp1_pre_kernel(
    const int* __restrict__ cnt, int* __restrict__ partial, int n, int NB,
    const float* __restrict__ Wl, const float* __restrict__ bl,
    const float* __restrict__ W1, const float* __restrict__ W2,
    const float* __restrict__ b1,
    float* __restrict__ C0, float* __restrict__ betas,
    float* __restrict__ W12, float* __restrict__ betaf1)
{
    __shared__ __align__(16) float smem[9216];
    const int tid = threadIdx.x;
    const int bid = blockIdx.x;

    if (bid < NB) {
        int* red = (int*)smem;
        int base = bid * 1024 + tid * 4;
        int s = 0;
        if (base + 3 < n) {
            int4 v = *(const int4*)(cnt + base);
            s = v.x + v.y + v.z + v.w;
        } else {
            for (int k = 0; k < 4; k++) { int i = base + k; if (i < n) s += cnt[i]; }
        }
        red[tid] = s;
        __syncthreads();
        for (int off = 128; off > 0; off >>= 1) {
            if (tid < off) red[tid] += red[tid + off];
            __syncthreads();
        }
        if (tid == 0) partial[bid] = red[0];
        return;
    }

    if (bid == NB) {
        // label-prop chain: C_m = W_{m+1} @ C_{m+1}, beta_m = b_m @ C_m
        float* Ca  = smem;            // 1600
        float* Cb  = smem + 1600;     // 1600
        float* sWm = smem + 3200;     // 1600
        float* bls = smem + 4800;     // 400
        for (int idx = tid; idx < 100; idx += 256)
            ((float4*)bls)[idx] = ((const float4*)bl)[idx];
        for (int idx = tid; idx < 1600; idx += 256)
            Ca[idx] = ((idx / 40) == (idx % 40)) ? 1.f : 0.f;
        if (tid < 40) betas[9 * 40 + tid] = bl[9 * 40 + tid];   // beta_10 = b_10
        __syncthreads();
        float* cur = Ca;
        float* nxt = Cb;
        for (int m = 9; m >= 0; --m) {
            for (int idx = tid; idx < 400; idx += 256)
                ((float4*)sWm)[idx] = ((const float4*)(Wl + (size_t)m * 1600))[idx];
            __syncthreads();
            for (int sid = tid; sid < 400; sid += 256) {
                int i = sid / 10, jq = sid - (sid / 10) * 10;
                const float* wr = &sWm[i * 40];
                const float4* c4 = (const float4*)cur;
                float4 a = make_float4(0.f, 0.f, 0.f, 0.f);
#pragma unroll
                for (int k = 0; k < 40; ++k) {
                    float w = wr[k];
                    float4 c = c4[k * 10 + jq];
                    a.x = fmaf(w, c.x, a.x); a.y = fmaf(w, c.y, a.y);
                    a.z = fmaf(w, c.z, a.z); a.w = fmaf(w, c.w, a.w);
                }
                ((float4*)nxt)[sid] = a;
            }
            __syncthreads();
            if (m >= 1 && tid < 40) {
                float s = 0.f;
                const float* br = &bls[(m - 1) * 40];
#pragma unroll
                for (int k = 0; k < 40; ++k) s = fmaf(br[k], nxt[k * 40 + tid], s);
                betas[(size_t)(m - 1) * 40 + tid] = s;
            }
            float* t = cur; cur = nxt; nxt = t;
            __syncthreads();
        }
        for (int idx = tid; idx < 1600; idx += 256) C0[idx] = cur[idx];
        return;
    }

    // W12 = W1 @ W2 (W2 staged in LDS)
    float* sW2 = smem;                // 9216 = 96x96
    for (int idx = tid; idx < 2304; idx += 256)
        ((float4*)sW2)[idx] = ((const float4*)W2)[idx];
    __syncthreads();
    int idx = (bid - NB - 1) * 256 + tid;   // 0..12287 == 128*96
    {
        int i = idx / 96, j = idx - (idx / 96) * 96;
        float s = 0.f;
        const float* wr = W1 + (size_t)i * 96;
#pragma unroll 8
        for (int k = 0; k < 96; ++k) s = fmaf(wr[k], sW2[k * 96 + j], s);
        W12[idx] = s;
    }
    if (bid == NB + 1 && tid < 96) {
        float s = 0.f;
        for (int k = 0; k < 96; ++k) s = fmaf(b1[k], sW2[k * 96 + tid], s);
        betaf1[tid] = s;
    }
}

__global__ __launch_bounds__(256) void scan_p2(int* __restrict__ partial, int* __restrict__ rowptr, int nb, int n) {
    __shared__ int sm[256];
    int tid = threadIdx.x;
    int v = (tid < nb) ? partial[tid] : 0;
    sm[tid] = v;
    __syncthreads();
    int acc = v;
    for (int off = 1; off < 256; off <<= 1) {
        int t = (tid >= off) ? sm[tid - off] : 0;
        __syncthreads();
        acc += t;
        sm[tid] = acc;
        __syncthreads();
    }
    if (tid < nb) partial[tid] = acc - v;
    if (tid == 255) rowptr[n] = sm[255];
}

// local scan + rowptr/cursor + dinv
__global__ __launch_bounds__(256) void scan_p3(const int* __restrict__ cnt, const int* __restrict__ partial,
                                               int* __restrict__ rowptr, int* __restrict__ cursor,
                                               float* __restrict__ dinv, int n) {
    __shared__ int tsum[256];
    int tid = threadIdx.x;
    int base = blockIdx.x * 1024 + tid * 4;
    int v0 = 0, v1 = 0, v2 = 0, v3 = 0;
    if (base + 3 < n) {
        int4 t = *(const int4*)(cnt + base);
        v0 = t.x; v1 = t.y; v2 = t.z; v3 = t.w;
    } else {
        if (base + 0 < n) v0 = cnt[base + 0];
        if (base + 1 < n) v1 = cnt[base + 1];
        if (base + 2 < n) v2 = cnt[base + 2];
        if (base + 3 < n) v3 = cnt[base + 3];
    }
    int s = v0 + v1 + v2 + v3;
    tsum[tid] = s;
    __syncthreads();
    int acc = s;
    for (int off = 1; off < 256; off <<= 1) {
        int t = (tid >= off) ? tsum[tid - off] : 0;
        __syncthreads();
        acc += t;
        tsum[tid] = acc;
        __syncthreads();
    }
    int run = partial[blockIdx.x] + acc - s;
    int vv[4] = {v0, v1, v2, v3};
    for (int k = 0; k < 4; k++) {
        int i = base + k;
        if (i < n) {
            rowptr[i] = run; cursor[i] = run; run += vv[k];
            dinv[i] = rsqrtf((float)vv[k] + 1.0f);
        }
    }
}

__global__ void scatter_kernel(const int* __restrict__ src, const int* __restrict__ dst,
                               int* __restrict__ cursor, int* __restrict__ col, int E) {
    int e = blockIdx.x * blockDim.x + threadIdx.x;
    if (e < E) {
        int d = dst[e];
        int p = atomicAdd(&cursor[d], 1);
        col[p] = src[e];
    }
}

// ---------------------------------------------------------------------------
// GEMM body: Y = (X @ W) * dinv[i], h16 out
// ---------------------------------------------------------------------------
template<int FIN, int FOUT, typename TX>
__device__ __forceinline__ void gemm_body(
    const TX* __restrict__ X, const float* __restrict__ W,
    const float* __restrict__ dinv, h16* __restrict__ Y, int n,
    float* sX, float* sW, int bid, int tid)
{
    constexpr int KC = (FIN % 32 == 0) ? 32 : FIN;
    constexpr int NCHUNK = FIN / KC;
    constexpr int TN = (FOUT + 15) / 16;
    constexpr int BM = 64;
    constexpr int KP = KC + 4;

    const int tj = tid & 15;
    const int ti = tid >> 4;
    const int i0 = bid * BM;

    float acc[4][TN] = {};

    for (int c = 0; c < NCHUNK; ++c) {
        const int k0 = c * KC;
        __syncthreads();
        if constexpr (sizeof(TX) == 2) {
            constexpr int K8 = KC / 8;
            for (int v = tid; v < BM * K8; v += 256) {
                int r = v / K8, q = v - r * K8;
                int gi = i0 + r;
                float f[8] = {0.f, 0.f, 0.f, 0.f, 0.f, 0.f, 0.f, 0.f};
                if (gi < n) ld8h((const h16*)X + (size_t)gi * FIN + k0 + q * 8, f);
                float* p = &sX[r * KP + q * 8];
#pragma unroll
                for (int j = 0; j < 8; ++j) p[j] = f[j];
            }
        } else {
            constexpr int K4 = KC / 4;
            for (int v = tid; v < BM * K4; v += 256) {
                int r = v / K4, q = v - r * K4;
                int gi = i0 + r;
                float4 val = (gi < n) ? *(const float4*)((const float*)X + (size_t)gi * FIN + k0 + q * 4)
                                      : make_float4(0.f, 0.f, 0.f, 0.f);
                float* p = &sX[r * KP + q * 4];
                p[0] = val.x; p[1] = val.y; p[2] = val.z; p[3] = val.w;
            }
        }
        for (int v = tid; v < KC * FOUT; v += 256) {
            int kk = v / FOUT;
            int j = v - kk * FOUT;
            sW[j * KP + kk] = W[(size_t)(k0 + kk) * FOUT + j];
        }
        __syncthreads();
#pragma unroll
        for (int kk = 0; kk < KC; kk += 4) {
            float4 xv[4];
#pragma unroll
            for (int m = 0; m < 4; ++m)
                xv[m] = *(const float4*)&sX[(ti + 16 * m) * KP + kk];
#pragma unroll
            for (int u = 0; u < TN; ++u) {
                float4 wv = *(const float4*)&sW[(tj + 16 * u) * KP + kk];
#pragma unroll
                for (int m = 0; m < 4; ++m) {
                    acc[m][u] = fmaf(xv[m].x, wv.x, acc[m][u]);
                    acc[m][u] = fmaf(xv[m].y, wv.y, acc[m][u]);
                    acc[m][u] = fmaf(xv[m].z, wv.z, acc[m][u]);
                    acc[m][u] = fmaf(xv[m].w, wv.w, acc[m][u]);
                }
            }
        }
    }

#pragma unroll
    for (int m = 0; m < 4; ++m) {
        int gi = i0 + ti + 16 * m;
        if (gi >= n) continue;
        float dv = dinv[gi];
#pragma unroll
        for (int u = 0; u < TN; ++u) {
            int j = tj + 16 * u;
            if (j < FOUT) Y[(size_t)gi * FOUT + j] = (h16)(acc[m][u] * dv);
        }
    }
}

// dual GEMM: blocks [0,nblkA) -> y@C0 -> Z0 (40x40); rest -> x@W12 -> A96 (128x96)
__global__ __launch_bounds__(256) void gemm_dual_kernel(
    const float* __restrict__ y, const float* __restrict__ C0, h16* __restrict__ Z0,
    const float* __restrict__ x, const float* __restrict__ W12, h16* __restrict__ A96,
    const float* __restrict__ dinv, int n, int nblkA)
{
    __shared__ __align__(16) float smem[5760];
    if (blockIdx.x < nblkA)
        gemm_body<40, 40, float>(y, C0, dinv, Z0, n, smem, smem + 64 * 44, blockIdx.x, threadIdx.x);
    else
        gemm_body<128, 96, float>(x, W12, dinv, A96, n, smem, smem + 64 * 36, blockIdx.x - nblkA, threadIdx.x);
}

// ---------------------------------------------------------------------------
// aggregation body: out[i,f8] = dinv*(hs[i]+sum hs[col]) + bias, opt *dinv
// 4x pipelined gathers for memory-level parallelism
// ---------------------------------------------------------------------------
template<int F, int PRE>
__device__ __forceinline__ void agg_body(
    const h16* __restrict__ hs, const int* __restrict__ rowptr,
    const int* __restrict__ col, const float* __restrict__ dinv,
    const float* __restrict__ bias, h16* __restrict__ out, int n,
    int bid, int tid)
{
    constexpr int F8 = F / 8;
    int gt = bid * 256 + tid;
    if (gt >= n * F8) return;
    int i = gt / F8;
    int f = gt - i * F8;
    int s = rowptr[i], e = rowptr[i + 1];
    const h16* base = hs + (size_t)f * 8;
    float acc[8];
    ld8h(hs + (size_t)i * F + f * 8, acc);
    int k = s;
    for (; k + 4 <= e; k += 4) {
        int c0 = col[k], c1 = col[k + 1], c2 = col[k + 2], c3 = col[k + 3];
        union { uint4 u; h16 h[8]; } a0, a1, a2, a3;
        a0.u = *(const uint4*)(base + (size_t)c0 * F);
        a1.u = *(const uint4*)(base + (size_t)c1 * F);
        a2.u = *(const uint4*)(base + (size_t)c2 * F);
        a3.u = *(const uint4*)(base + (size_t)c3 * F);
#pragma unroll
        for (int j = 0; j < 8; ++j)
            acc[j] += ((float)a0.h[j] + (float)a1.h[j]) + ((float)a2.h[j] + (float)a3.h[j]);
    }
    for (; k < e; k++) {
        float v[8];
        ld8h(base + (size_t)col[k] * F, v);
#pragma unroll
        for (int j = 0; j < 8; ++j) acc[j] += v[j];
    }
    float dv = dinv[i];
    float sc = PRE ? dv : 1.f;
    union { uint4 u; h16 h[8]; } o;
#pragma unroll
    for (int j = 0; j < 8; ++j) o.h[j] = (h16)((acc[j] * dv + bias[f * 8 + j]) * sc);
    *(uint4*)(out + (size_t)i * F + f * 8) = o.u;
}

template<int F, int PRE>
__global__ __launch_bounds__(256) void agg_h(
    const h16* __restrict__ hs, const int* __restrict__ rowptr,
    const int* __restrict__ col, const float* __restrict__ dinv,
    const float* __restrict__ bias, h16* __restrict__ out, int n) {
    agg_body<F, PRE>(hs, rowptr, col, dinv, bias, out, n, blockIdx.x, threadIdx.x);
}

// dual agg: label F=40 (PRE=1) + feature F=96 (PRE2)
template<int PRE2>
__global__ __launch_bounds__(256) void agg_dual_kernel(
    const h16* __restrict__ hsA, const float* __restrict__ biasA, h16* __restrict__ outA,
    const h16* __restrict__ hsB, const float* __restrict__ biasB, h16* __restrict__ outB,
    const int* __restrict__ rowptr, const int* __restrict__ col,
    const float* __restrict__ dinv, int n, int nblkA)
{
    if (blockIdx.x < nblkA)
        agg_body<40, 1>(hsA, rowptr, col, dinv, biasA, outA, n, blockIdx.x, threadIdx.x);
    else
        agg_body<96, PRE2>(hsB, rowptr, col, dinv, biasB, outB, n, blockIdx.x - nblkA, threadIdx.x);
}

// ---- fused final layer: out = sigmoid([h2|xl|dw] @ Wf + bf) ----
template<int KC, typename T>
__device__ __forceinline__ void fuse_chunk(
    const T* __restrict__ src, int FIN, int k0, int wrow0,
    const float* __restrict__ Wf, float* sX, float* sW,
    float acc[4][3], int i0, int n, int tid)
{
    constexpr int KP = 44;
    __syncthreads();
    if constexpr (sizeof(T) == 2) {
        constexpr int K8 = KC / 8;
        for (int v = tid; v < 64 * K8; v += 256) {
            int r = v / K8, q = v - r * K8;
            int gi = i0 + r;
            float f[8] = {0.f, 0.f, 0.f, 0.f, 0.f, 0.f, 0.f, 0.f};
            if (gi < n) ld8h((const h16*)src + (size_t)gi * FIN + k0 + q * 8, f);
            float* p = &sX[r * KP + q * 8];
#pragma unroll
            for (int j = 0; j < 8; ++j) p[j] = f[j];
        }
    } else {
        constexpr int K4 = KC / 4;
        for (int v = tid; v < 64 * K4; v += 256) {
            int r = v / K4, q = v - r * K4;
            int gi = i0 + r;
            float4 val = (gi < n) ? *(const float4*)((const float*)src + (size_t)gi * FIN + k0 + q * 4)
                                  : make_float4(0.f, 0.f, 0.f, 0.f);
            float* p = &sX[r * KP + q * 4];
            p[0] = val.x; p[1] = val.y; p[2] = val.z; p[3] = val.w;
        }
    }
    for (int v = tid; v < KC * 40; v += 256) {
        int kk = v / 40, j = v - kk * 40;
        sW[j * KP + kk] = Wf[(size_t)(wrow0 + kk) * 40 + j];
    }
    __syncthreads();
    int tj = tid & 15, ti = tid >> 4;
#pragma unroll
    for (int kk = 0; kk < KC; kk += 4) {
        float4 xv[4];
#pragma unroll
        for (int m = 0; m < 4; ++m)
            xv[m] = *(const float4*)&sX[(ti + 16 * m) * KP + kk];
#pragma unroll
        for (int u = 0; u < 3; ++u) {
            float4 wv = *(const float4*)&sW[(tj + 16 * u) * KP + kk];
#pragma unroll
            for (int m = 0; m < 4; ++m) {
                acc[m][u] = fmaf(xv[m].x, wv.x, acc[m][u]);
                acc[m][u] = fmaf(xv[m].y, wv.y, acc[m][u]);
                acc[m][u] = fmaf(xv[m].z, wv.z, acc[m][u]);
                acc[m][u] = fmaf(xv[m].w, wv.w, acc[m][u]);
            }
        }
    }
}

__global__ __launch_bounds__(256) void fuse_gemm_kernel(
    const h16* __restrict__ h2, const h16* __restrict__ xl,
    const float* __restrict__ dw, const float* __restrict__ Wf,
    const float* __restrict__ bf, float* __restrict__ out, int n)
{
    __shared__ __align__(16) float sX[64 * 44];
    __shared__ __align__(16) float sW[48 * 44];
    float acc[4][3] = {};
    const int tid = threadIdx.x;
    const int i0 = blockIdx.x * 64;
    fuse_chunk<32>(h2, 96, 0,  0,   Wf, sX, sW, acc, i0, n, tid);
    fuse_chunk<32>(h2, 96, 32, 32,  Wf, sX, sW, acc, i0, n, tid);
    fuse_chunk<32>(h2, 96, 64, 64,  Wf, sX, sW, acc, i0, n, tid);
    fuse_chunk<40>(xl, 40, 0,  96,  Wf, sX, sW, acc, i0, n, tid);
    fuse_chunk<32>(dw, 64, 0,  136, Wf, sX, sW, acc, i0, n, tid);
    fuse_chunk<32>(dw, 64, 32, 168, Wf, sX, sW, acc, i0, n, tid);
    const int tj = tid & 15, ti = tid >> 4;
#pragma unroll
    for (int m = 0; m < 4; ++m) {
        int gi = i0 + ti + 16 * m;
        if (gi >= n) continue;
#pragma unroll
        for (int u = 0; u < 3; ++u) {
            int j = tj + 16 * u;
            if (j < 40) {
                float t = acc[m][u] + bf[j];
                out[(size_t)gi * 40 + j] = 1.f / (1.f + expf(-t));
            }
        }
    }
}

extern "C" void kernel_launch(void* const* d_in, const int* in_sizes, int n_in,
                              void* d_out, int out_size, void* d_ws, size_t ws_size,
                              hipStream_t stream) {
    const float* x   = (const float*)d_in[0];
    const float* y   = (const float*)d_in[1];
    const int*   ei  = (const int*)d_in[2];
    const float* dwe = (const float*)d_in[3];
    const float* W1  = (const float*)d_in[4];
    const float* b1  = (const float*)d_in[5];
    const float* W2  = (const float*)d_in[6];
    const float* b2  = (const float*)d_in[7];
    const float* Wl  = (const float*)d_in[8];
    const float* bl  = (const float*)d_in[9];
    const float* Wf  = (const float*)d_in[10];
    const float* bf  = (const float*)d_in[11];
    float* out = (float*)d_out;

    const int n = in_sizes[0] / 128;
    const int E = in_sizes[2] / 2;
    const int* srcp = ei;
    const int* dstp = ei + E;

    char* ws = (char*)d_ws;
    size_t off = 0;
    auto alloc = [&](size_t bytes) -> void* {
        void* p = ws + off;
        off += bytes;
        off = (off + 255) & ~(size_t)255;
        return p;
    };

    int*   cnt     = (int*)alloc((size_t)n * 4);
    float* dinv    = (float*)alloc((size_t)n * 4);
    int*   rowptr  = (int*)alloc((size_t)(n + 1) * 4);
    int*   cursor  = (int*)alloc((size_t)n * 4);
    int*   partial = (int*)alloc(256 * 4);
    int*   col     = (int*)alloc((size_t)E * 4);
    h16*   A96     = (h16*)alloc((size_t)n * 96 * 2);
    h16*   B96     = (h16*)alloc((size_t)n * 96 * 2);
    h16*   Z0      = (h16*)alloc((size_t)n * 40 * 2);
    h16*   LA      = (h16*)alloc((size_t)n * 40 * 2);
    h16*   LB      = (h16*)alloc((size_t)n * 40 * 2);
    float* C0      = (float*)alloc(1600 * 4);
    float* betas   = (float*)alloc(10 * 40 * 4);
    float* W12     = (float*)alloc(128 * 96 * 4);
    float* betaf1  = (float*)alloc(96 * 4);
    (void)ws_size;

    const int gb_e    = (E + THREADS - 1) / THREADS;
    const int NB      = (n + 1023) / 1024;
    const int gb_gm   = (n + 63) / 64;
    const int gb_a96  = (n * 12 + THREADS - 1) / THREADS;
    const int gb_a40  = (n * 5 + THREADS - 1) / THREADS;

    // ---- CSR build + weight collapse (collapse hidden in scan_p1 dispatch) ----
    hipMemsetAsync(cnt, 0, (size_t)n * 4, stream);
    count_kernel<<<gb_e, THREADS, 0, stream>>>(dstp, cnt, E);
    scanp1_pre_kernel<<<NB + 49, THREADS, 0, stream>>>(
        cnt, partial, n, NB, Wl, bl, W1, W2, b1, C0, betas, W12, betaf1);
    scan_p2<<<1, THREADS, 0, stream>>>(partial, rowptr, NB, n);
    scan_p3<<<NB, THREADS, 0, stream>>>(cnt, partial, rowptr, cursor, dinv, n);
    scatter_kernel<<<gb_e, THREADS, 0, stream>>>(srcp, dstp, cursor, col, E);

    // ---- both input GEMMs in one dispatch ----
    gemm_dual_kernel<<<2 * gb_gm, THREADS, 0, stream>>>(y, C0, Z0, x, W12, A96, dinv, n, gb_gm);

    // ---- label layer 1 + feature agg 1 ----
    agg_dual_kernel<1><<<gb_a40 + gb_a96, THREADS, 0, stream>>>(
        Z0, betas + 0, LA, A96, betaf1, B96, rowptr, col, dinv, n, gb_a40);
    // ---- label layer 2 + feature agg 2 ----
    agg_dual_kernel<0><<<gb_a40 + gb_a96, THREADS, 0, stream>>>(
        LA, betas + 40, LB, B96, b2, A96, rowptr, col, dinv, n, gb_a40);

    // ---- label layers 3..10 ----
    const h16* cur = LB;
    const h16* xl = LB;
    for (int m = 3; m <= 10; m++) {
        h16* nxt = (m & 1) ? LA : LB;
        if (m < 10)
            agg_h<40, 1><<<gb_a40, THREADS, 0, stream>>>(cur, rowptr, col, dinv, betas + (size_t)(m - 1) * 40, nxt, n);
        else
            agg_h<40, 0><<<gb_a40, THREADS, 0, stream>>>(cur, rowptr, col, dinv, betas + (size_t)(m - 1) * 40, nxt, n);
        cur = nxt;
        xl = nxt;
    }

    // ---- fuse + sigmoid (h2 = A96 after second feature agg) ----
    fuse_gemm_kernel<<<gb_gm, THREADS, 0, stream>>>(A96, xl, dwe, Wf, bf, out, n);
}

// Round 9
// 405.649 us; speedup vs baseline: 4.4038x; 1.0929x over previous
//
#include <hip/hip_runtime.h>
#include <hip/hip_bf16.h>
#include <math.h>

#define THREADS 256
typedef _Float16 h16;

__device__ __forceinline__ void ld8h(const h16* p, float* f) {
    union { uint4 u; h16 h[8]; } c;
    c.u = *(const uint4*)p;
#pragma unroll
    for (int j = 0; j < 8; ++j) f[j] = (float)c.h[j];
}

__global__ void count_kernel(const int* __restrict__ dst, int* __restrict__ cnt, int E) {
    int e = blockIdx.x * blockDim.x + threadIdx.x;
    if (e < E) atomicAdd(&cnt[dst[e]], 1);
}

// ---------------------------------------------------------------------------
// scan_p1 (blocks [0,NB)) + weight collapse (block NB: 40x40 chain;
// blocks NB+1..NB+48: W12 = W1@W2, first also betaf1 = b1@W2)
// ---------------------------------------------------------------------------
__global__ __launch_bounds__(256) void scanp1_pre_kernel(
    const int* __restrict__ cnt, int* __restrict__ partial, int n, int NB,
    const float* __restrict__ Wl, const float* __restrict__ bl,
    const float* __restrict__ W1, const float* __restrict__ W2,
    const float* __restrict__ b1,
    float* __restrict__ C0, float* __restrict__ betas,
    float* __restrict__ W12, float* __restrict__ betaf1)
{
    __shared__ __align__(16) float smem[9216];
    const int tid = threadIdx.x;
    const int bid = blockIdx.x;

    if (bid < NB) {
        int* red = (int*)smem;
        int base = bid * 1024 + tid * 4;
        int s = 0;
        if (base + 3 < n) {
            int4 v = *(const int4*)(cnt + base);
            s = v.x + v.y + v.z + v.w;
        } else {
            for (int k = 0; k < 4; k++) { int i = base + k; if (i < n) s += cnt[i]; }
        }
        red[tid] = s;
        __syncthreads();
        for (int off = 128; off > 0; off >>= 1) {
            if (tid < off) red[tid] += red[tid + off];
            __syncthreads();
        }
        if (tid == 0) partial[bid] = red[0];
        return;
    }

    if (bid == NB) {
        // label-prop chain: C_m = W_{m+1} @ C_{m+1}, beta_m = b_m @ C_m
        float* Ca  = smem;            // 1600
        float* Cb  = smem + 1600;     // 1600
        float* sWm = smem + 3200;     // 1600
        float* bls = smem + 4800;     // 400
        for (int idx = tid; idx < 100; idx += 256)
            ((float4*)bls)[idx] = ((const float4*)bl)[idx];
        for (int idx = tid; idx < 1600; idx += 256)
            Ca[idx] = ((idx / 40) == (idx % 40)) ? 1.f : 0.f;
        if (tid < 40) betas[9 * 40 + tid] = bl[9 * 40 + tid];   // beta_10 = b_10
        __syncthreads();
        float* cur = Ca;
        float* nxt = Cb;
        for (int m = 9; m >= 0; --m) {
            for (int idx = tid; idx < 400; idx += 256)
                ((float4*)sWm)[idx] = ((const float4*)(Wl + (size_t)m * 1600))[idx];
            __syncthreads();
            for (int sid = tid; sid < 400; sid += 256) {
                int i = sid / 10, jq = sid - (sid / 10) * 10;
                const float* wr = &sWm[i * 40];
                const float4* c4 = (const float4*)cur;
                float4 a = make_float4(0.f, 0.f, 0.f, 0.f);
#pragma unroll
                for (int k = 0; k < 40; ++k) {
                    float w = wr[k];
                    float4 c = c4[k * 10 + jq];
                    a.x = fmaf(w, c.x, a.x); a.y = fmaf(w, c.y, a.y);
                    a.z = fmaf(w, c.z, a.z); a.w = fmaf(w, c.w, a.w);
                }
                ((float4*)nxt)[sid] = a;
            }
            __syncthreads();
            if (m >= 1 && tid < 40) {
                float s = 0.f;
                const float* br = &bls[(m - 1) * 40];
#pragma unroll
                for (int k = 0; k < 40; ++k) s = fmaf(br[k], nxt[k * 40 + tid], s);
                betas[(size_t)(m - 1) * 40 + tid] = s;
            }
            float* t = cur; cur = nxt; nxt = t;
            __syncthreads();
        }
        for (int idx = tid; idx < 1600; idx += 256) C0[idx] = cur[idx];
        return;
    }

    // W12 = W1 @ W2 (W2 staged in LDS)
    float* sW2 = smem;                // 9216 = 96x96
    for (int idx = tid; idx < 2304; idx += 256)
        ((float4*)sW2)[idx] = ((const float4*)W2)[idx];
    __syncthreads();
    int idx = (bid - NB - 1) * 256 + tid;   // 0..12287 == 128*96
    {
        int i = idx / 96, j = idx - (idx / 96) * 96;
        float s = 0.f;
        const float* wr = W1 + (size_t)i * 96;
#pragma unroll 8
        for (int k = 0; k < 96; ++k) s = fmaf(wr[k], sW2[k * 96 + j], s);
        W12[idx] = s;
    }
    if (bid == NB + 1 && tid < 96) {
        float s = 0.f;
        for (int k = 0; k < 96; ++k) s = fmaf(b1[k], sW2[k * 96 + tid], s);
        betaf1[tid] = s;
    }
}

__global__ __launch_bounds__(256) void scan_p2(int* __restrict__ partial, int* __restrict__ rowptr, int nb, int n) {
    __shared__ int sm[256];
    int tid = threadIdx.x;
    int v = (tid < nb) ? partial[tid] : 0;
    sm[tid] = v;
    __syncthreads();
    int acc = v;
    for (int off = 1; off < 256; off <<= 1) {
        int t = (tid >= off) ? sm[tid - off] : 0;
        __syncthreads();
        acc += t;
        sm[tid] = acc;
        __syncthreads();
    }
    if (tid < nb) partial[tid] = acc - v;
    if (tid == 255) rowptr[n] = sm[255];
}

// local scan + rowptr/cursor + dinv
__global__ __launch_bounds__(256) void scan_p3(const int* __restrict__ cnt, const int* __restrict__ partial,
                                               int* __restrict__ rowptr, int* __restrict__ cursor,
                                               float* __restrict__ dinv, int n) {
    __shared__ int tsum[256];
    int tid = threadIdx.x;
    int base = blockIdx.x * 1024 + tid * 4;
    int v0 = 0, v1 = 0, v2 = 0, v3 = 0;
    if (base + 3 < n) {
        int4 t = *(const int4*)(cnt + base);
        v0 = t.x; v1 = t.y; v2 = t.z; v3 = t.w;
    } else {
        if (base + 0 < n) v0 = cnt[base + 0];
        if (base + 1 < n) v1 = cnt[base + 1];
        if (base + 2 < n) v2 = cnt[base + 2];
        if (base + 3 < n) v3 = cnt[base + 3];
    }
    int s = v0 + v1 + v2 + v3;
    tsum[tid] = s;
    __syncthreads();
    int acc = s;
    for (int off = 1; off < 256; off <<= 1) {
        int t = (tid >= off) ? tsum[tid - off] : 0;
        __syncthreads();
        acc += t;
        tsum[tid] = acc;
        __syncthreads();
    }
    int run = partial[blockIdx.x] + acc - s;
    int vv[4] = {v0, v1, v2, v3};
    for (int k = 0; k < 4; k++) {
        int i = base + k;
        if (i < n) {
            rowptr[i] = run; cursor[i] = run; run += vv[k];
            dinv[i] = rsqrtf((float)vv[k] + 1.0f);
        }
    }
}

__global__ void scatter_kernel(const int* __restrict__ src, const int* __restrict__ dst,
                               int* __restrict__ cursor, int* __restrict__ col, int E) {
    int e = blockIdx.x * blockDim.x + threadIdx.x;
    if (e < E) {
        int d = dst[e];
        int p = atomicAdd(&cursor[d], 1);
        col[p] = src[e];
    }
}

// ---------------------------------------------------------------------------
// Register-tiled GEMM: Y = (X @ W) * dinv[i]   (pre-scaled for aggregation)
// ---------------------------------------------------------------------------
template<int FIN, int FOUT, typename TX>
__global__ __launch_bounds__(256) void gemm_kernel(
    const TX* __restrict__ X, const float* __restrict__ W,
    const float* __restrict__ dinv, h16* __restrict__ Y, int n)
{
    constexpr int KC = (FIN % 32 == 0) ? 32 : FIN;
    constexpr int NCHUNK = FIN / KC;
    constexpr int TN = (FOUT + 15) / 16;
    constexpr int FOUTP = TN * 16;
    constexpr int BM = 64;
    constexpr int KP = KC + 4;

    __shared__ __align__(16) float sX[BM * KP];
    __shared__ __align__(16) float sW[FOUTP * KP];

    const int tid = threadIdx.x;
    const int tj = tid & 15;
    const int ti = tid >> 4;
    const int i0 = blockIdx.x * BM;

    float acc[4][TN] = {};

    for (int c = 0; c < NCHUNK; ++c) {
        const int k0 = c * KC;
        __syncthreads();
        if constexpr (sizeof(TX) == 2) {
            constexpr int K8 = KC / 8;
            for (int v = tid; v < BM * K8; v += 256) {
                int r = v / K8, q = v - r * K8;
                int gi = i0 + r;
                float f[8] = {0.f, 0.f, 0.f, 0.f, 0.f, 0.f, 0.f, 0.f};
                if (gi < n) ld8h((const h16*)X + (size_t)gi * FIN + k0 + q * 8, f);
                float* p = &sX[r * KP + q * 8];
#pragma unroll
                for (int j = 0; j < 8; ++j) p[j] = f[j];
            }
        } else {
            constexpr int K4 = KC / 4;
            for (int v = tid; v < BM * K4; v += 256) {
                int r = v / K4, q = v - r * K4;
                int gi = i0 + r;
                float4 val = (gi < n) ? *(const float4*)((const float*)X + (size_t)gi * FIN + k0 + q * 4)
                                      : make_float4(0.f, 0.f, 0.f, 0.f);
                float* p = &sX[r * KP + q * 4];
                p[0] = val.x; p[1] = val.y; p[2] = val.z; p[3] = val.w;
            }
        }
        for (int v = tid; v < KC * FOUT; v += 256) {
            int kk = v / FOUT;
            int j = v - kk * FOUT;
            sW[j * KP + kk] = W[(size_t)(k0 + kk) * FOUT + j];
        }
        __syncthreads();
#pragma unroll
        for (int kk = 0; kk < KC; kk += 4) {
            float4 xv[4];
#pragma unroll
            for (int m = 0; m < 4; ++m)
                xv[m] = *(const float4*)&sX[(ti + 16 * m) * KP + kk];
#pragma unroll
            for (int u = 0; u < TN; ++u) {
                float4 wv = *(const float4*)&sW[(tj + 16 * u) * KP + kk];
#pragma unroll
                for (int m = 0; m < 4; ++m) {
                    acc[m][u] = fmaf(xv[m].x, wv.x, acc[m][u]);
                    acc[m][u] = fmaf(xv[m].y, wv.y, acc[m][u]);
                    acc[m][u] = fmaf(xv[m].z, wv.z, acc[m][u]);
                    acc[m][u] = fmaf(xv[m].w, wv.w, acc[m][u]);
                }
            }
        }
    }

#pragma unroll
    for (int m = 0; m < 4; ++m) {
        int gi = i0 + ti + 16 * m;
        if (gi >= n) continue;
        float dv = dinv[gi];
#pragma unroll
        for (int u = 0; u < TN; ++u) {
            int j = tj + 16 * u;
            if (j < FOUT) Y[(size_t)gi * FOUT + j] = (h16)(acc[m][u] * dv);
        }
    }
}

// ---------------------------------------------------------------------------
// aggregation body: out[i,f8] = dinv*(hs[i]+sum hs[col]) + bias, opt *dinv
// 4x pipelined gathers for memory-level parallelism
// ---------------------------------------------------------------------------
template<int F, int PRE>
__device__ __forceinline__ void agg_body(
    const h16* __restrict__ hs, const int* __restrict__ rowptr,
    const int* __restrict__ col, const float* __restrict__ dinv,
    const float* __restrict__ bias, h16* __restrict__ out, int n,
    int bid, int tid)
{
    constexpr int F8 = F / 8;
    int gt = bid * 256 + tid;
    if (gt >= n * F8) return;
    int i = gt / F8;
    int f = gt - i * F8;
    int s = rowptr[i], e = rowptr[i + 1];
    const h16* base = hs + (size_t)f * 8;
    float acc[8];
    ld8h(hs + (size_t)i * F + f * 8, acc);
    int k = s;
    for (; k + 4 <= e; k += 4) {
        int c0 = col[k], c1 = col[k + 1], c2 = col[k + 2], c3 = col[k + 3];
        union { uint4 u; h16 h[8]; } a0, a1, a2, a3;
        a0.u = *(const uint4*)(base + (size_t)c0 * F);
        a1.u = *(const uint4*)(base + (size_t)c1 * F);
        a2.u = *(const uint4*)(base + (size_t)c2 * F);
        a3.u = *(const uint4*)(base + (size_t)c3 * F);
#pragma unroll
        for (int j = 0; j < 8; ++j)
            acc[j] += ((float)a0.h[j] + (float)a1.h[j]) + ((float)a2.h[j] + (float)a3.h[j]);
    }
    for (; k < e; k++) {
        float v[8];
        ld8h(base + (size_t)col[k] * F, v);
#pragma unroll
        for (int j = 0; j < 8; ++j) acc[j] += v[j];
    }
    float dv = dinv[i];
    float sc = PRE ? dv : 1.f;
    union { uint4 u; h16 h[8]; } o;
#pragma unroll
    for (int j = 0; j < 8; ++j) o.h[j] = (h16)((acc[j] * dv + bias[f * 8 + j]) * sc);
    *(uint4*)(out + (size_t)i * F + f * 8) = o.u;
}

template<int F, int PRE>
__global__ __launch_bounds__(256) void agg_h(
    const h16* __restrict__ hs, const int* __restrict__ rowptr,
    const int* __restrict__ col, const float* __restrict__ dinv,
    const float* __restrict__ bias, h16* __restrict__ out, int n) {
    agg_body<F, PRE>(hs, rowptr, col, dinv, bias, out, n, blockIdx.x, threadIdx.x);
}

// dual agg: label F=40 (PRE=1) + feature F=96 (PRE2)
template<int PRE2>
__global__ __launch_bounds__(256) void agg_dual_kernel(
    const h16* __restrict__ hsA, const float* __restrict__ biasA, h16* __restrict__ outA,
    const h16* __restrict__ hsB, const float* __restrict__ biasB, h16* __restrict__ outB,
    const int* __restrict__ rowptr, const int* __restrict__ col,
    const float* __restrict__ dinv, int n, int nblkA)
{
    if (blockIdx.x < nblkA)
        agg_body<40, 1>(hsA, rowptr, col, dinv, biasA, outA, n, blockIdx.x, threadIdx.x);
    else
        agg_body<96, PRE2>(hsB, rowptr, col, dinv, biasB, outB, n, blockIdx.x - nblkA, threadIdx.x);
}

// ---- fused final layer: out = sigmoid([h2|xl|dw] @ Wf + bf) ----
template<int KC, typename T>
__device__ __forceinline__ void fuse_chunk(
    const T* __restrict__ src, int FIN, int k0, int wrow0,
    const float* __restrict__ Wf, float* sX, float* sW,
    float acc[4][3], int i0, int n, int tid)
{
    constexpr int KP = 44;
    __syncthreads();
    if constexpr (sizeof(T) == 2) {
        constexpr int K8 = KC / 8;
        for (int v = tid; v < 64 * K8; v += 256) {
            int r = v / K8, q = v - r * K8;
            int gi = i0 + r;
            float f[8] = {0.f, 0.f, 0.f, 0.f, 0.f, 0.f, 0.f, 0.f};
            if (gi < n) ld8h((const h16*)src + (size_t)gi * FIN + k0 + q * 8, f);
            float* p = &sX[r * KP + q * 8];
#pragma unroll
            for (int j = 0; j < 8; ++j) p[j] = f[j];
        }
    } else {
        constexpr int K4 = KC / 4;
        for (int v = tid; v < 64 * K4; v += 256) {
            int r = v / K4, q = v - r * K4;
            int gi = i0 + r;
            float4 val = (gi < n) ? *(const float4*)((const float*)src + (size_t)gi * FIN + k0 + q * 4)
                                  : make_float4(0.f, 0.f, 0.f, 0.f);
            float* p = &sX[r * KP + q * 4];
            p[0] = val.x; p[1] = val.y; p[2] = val.z; p[3] = val.w;
        }
    }
    for (int v = tid; v < KC * 40; v += 256) {
        int kk = v / 40, j = v - kk * 40;
        sW[j * KP + kk] = Wf[(size_t)(wrow0 + kk) * 40 + j];
    }
    __syncthreads();
    int tj = tid & 15, ti = tid >> 4;
#pragma unroll
    for (int kk = 0; kk < KC; kk += 4) {
        float4 xv[4];
#pragma unroll
        for (int m = 0; m < 4; ++m)
            xv[m] = *(const float4*)&sX[(ti + 16 * m) * KP + kk];
#pragma unroll
        for (int u = 0; u < 3; ++u) {
            float4 wv = *(const float4*)&sW[(tj + 16 * u) * KP + kk];
#pragma unroll
            for (int m = 0; m < 4; ++m) {
                acc[m][u] = fmaf(xv[m].x, wv.x, acc[m][u]);
                acc[m][u] = fmaf(xv[m].y, wv.y, acc[m][u]);
                acc[m][u] = fmaf(xv[m].z, wv.z, acc[m][u]);
                acc[m][u] = fmaf(xv[m].w, wv.w, acc[m][u]);
            }
        }
    }
}

__global__ __launch_bounds__(256) void fuse_gemm_kernel(
    const h16* __restrict__ h2, const h16* __restrict__ xl,
    const float* __restrict__ dw, const float* __restrict__ Wf,
    const float* __restrict__ bf, float* __restrict__ out, int n)
{
    __shared__ __align__(16) float sX[64 * 44];
    __shared__ __align__(16) float sW[48 * 44];
    float acc[4][3] = {};
    const int tid = threadIdx.x;
    const int i0 = blockIdx.x * 64;
    fuse_chunk<32>(h2, 96, 0,  0,   Wf, sX, sW, acc, i0, n, tid);
    fuse_chunk<32>(h2, 96, 32, 32,  Wf, sX, sW, acc, i0, n, tid);
    fuse_chunk<32>(h2, 96, 64, 64,  Wf, sX, sW, acc, i0, n, tid);
    fuse_chunk<40>(xl, 40, 0,  96,  Wf, sX, sW, acc, i0, n, tid);
    fuse_chunk<32>(dw, 64, 0,  136, Wf, sX, sW, acc, i0, n, tid);
    fuse_chunk<32>(dw, 64, 32, 168, Wf, sX, sW, acc, i0, n, tid);
    const int tj = tid & 15, ti = tid >> 4;
#pragma unroll
    for (int m = 0; m < 4; ++m) {
        int gi = i0 + ti + 16 * m;
        if (gi >= n) continue;
#pragma unroll
        for (int u = 0; u < 3; ++u) {
            int j = tj + 16 * u;
            if (j < 40) {
                float t = acc[m][u] + bf[j];
                out[(size_t)gi * 40 + j] = 1.f / (1.f + expf(-t));
            }
        }
    }
}

extern "C" void kernel_launch(void* const* d_in, const int* in_sizes, int n_in,
                              void* d_out, int out_size, void* d_ws, size_t ws_size,
                              hipStream_t stream) {
    const float* x   = (const float*)d_in[0];
    const float* y   = (const float*)d_in[1];
    const int*   ei  = (const int*)d_in[2];
    const float* dwe = (const float*)d_in[3];
    const float* W1  = (const float*)d_in[4];
    const float* b1  = (const float*)d_in[5];
    const float* W2  = (const float*)d_in[6];
    const float* b2  = (const float*)d_in[7];
    const float* Wl  = (const float*)d_in[8];
    const float* bl  = (const float*)d_in[9];
    const float* Wf  = (const float*)d_in[10];
    const float* bf  = (const float*)d_in[11];
    float* out = (float*)d_out;

    const int n = in_sizes[0] / 128;
    const int E = in_sizes[2] / 2;
    const int* srcp = ei;
    const int* dstp = ei + E;

    char* ws = (char*)d_ws;
    size_t off = 0;
    auto alloc = [&](size_t bytes) -> void* {
        void* p = ws + off;
        off += bytes;
        off = (off + 255) & ~(size_t)255;
        return p;
    };

    int*   cnt     = (int*)alloc((size_t)n * 4);
    float* dinv    = (float*)alloc((size_t)n * 4);
    int*   rowptr  = (int*)alloc((size_t)(n + 1) * 4);
    int*   cursor  = (int*)alloc((size_t)n * 4);
    int*   partial = (int*)alloc(256 * 4);
    int*   col     = (int*)alloc((size_t)E * 4);
    h16*   A96     = (h16*)alloc((size_t)n * 96 * 2);
    h16*   B96     = (h16*)alloc((size_t)n * 96 * 2);
    h16*   Z0      = (h16*)alloc((size_t)n * 40 * 2);
    h16*   LA      = (h16*)alloc((size_t)n * 40 * 2);
    h16*   LB      = (h16*)alloc((size_t)n * 40 * 2);
    float* C0      = (float*)alloc(1600 * 4);
    float* betas   = (float*)alloc(10 * 40 * 4);
    float* W12     = (float*)alloc(128 * 96 * 4);
    float* betaf1  = (float*)alloc(96 * 4);
    (void)ws_size;

    const int gb_e    = (E + THREADS - 1) / THREADS;
    const int NB      = (n + 1023) / 1024;
    const int gb_gm   = (n + 63) / 64;
    const int gb_a96  = (n * 12 + THREADS - 1) / THREADS;
    const int gb_a40  = (n * 5 + THREADS - 1) / THREADS;

    // ---- CSR build + weight collapse (collapse hidden in scan_p1 dispatch) ----
    hipMemsetAsync(cnt, 0, (size_t)n * 4, stream);
    count_kernel<<<gb_e, THREADS, 0, stream>>>(dstp, cnt, E);
    scanp1_pre_kernel<<<NB + 49, THREADS, 0, stream>>>(
        cnt, partial, n, NB, Wl, bl, W1, W2, b1, C0, betas, W12, betaf1);
    scan_p2<<<1, THREADS, 0, stream>>>(partial, rowptr, NB, n);
    scan_p3<<<NB, THREADS, 0, stream>>>(cnt, partial, rowptr, cursor, dinv, n);
    scatter_kernel<<<gb_e, THREADS, 0, stream>>>(srcp, dstp, cursor, col, E);

    // ---- input GEMMs (separate dispatches: merged version halves occupancy) ----
    gemm_kernel<40, 40, float><<<gb_gm, THREADS, 0, stream>>>(y, C0, dinv, Z0, n);
    gemm_kernel<128, 96, float><<<gb_gm, THREADS, 0, stream>>>(x, W12, dinv, A96, n);

    // ---- label layer 1 + feature agg 1 ----
    agg_dual_kernel<1><<<gb_a40 + gb_a96, THREADS, 0, stream>>>(
        Z0, betas + 0, LA, A96, betaf1, B96, rowptr, col, dinv, n, gb_a40);
    // ---- label layer 2 + feature agg 2 ----
    agg_dual_kernel<0><<<gb_a40 + gb_a96, THREADS, 0, stream>>>(
        LA, betas + 40, LB, B96, b2, A96, rowptr, col, dinv, n, gb_a40);

    // ---- label layers 3..10 ----
    const h16* cur = LB;
    const h16* xl = LB;
    for (int m = 3; m <= 10; m++) {
        h16* nxt = (m & 1) ? LA : LB;
        if (m < 10)
            agg_h<40, 1><<<gb_a40, THREADS, 0, stream>>>(cur, rowptr, col, dinv, betas + (size_t)(m - 1) * 40, nxt, n);
        else
            agg_h<40, 0><<<gb_a40, THREADS, 0, stream>>>(cur, rowptr, col, dinv, betas + (size_t)(m - 1) * 40, nxt, n);
        cur = nxt;
        xl = nxt;
    }

    // ---- fuse + sigmoid (h2 = A96 after second feature agg) ----
    fuse_gemm_kernel<<<gb_gm, THREADS, 0, stream>>>(A96, xl, dwe, Wf, bf, out, n);
}

// Round 10
// 397.156 us; speedup vs baseline: 4.4979x; 1.0214x over previous
//
#include <hip/hip_runtime.h>
#include <hip/hip_bf16.h>
#include <math.h>

#define THREADS 256
typedef _Float16 h16;

__device__ __forceinline__ void ld8h(const h16* p, float* f) {
    union { uint4 u; h16 h[8]; } c;
    c.u = *(const uint4*)p;
#pragma unroll
    for (int j = 0; j < 8; ++j) f[j] = (float)c.h[j];
}

__global__ void count_kernel(const int* __restrict__ dst, int* __restrict__ cnt, int E) {
    int e = blockIdx.x * blockDim.x + threadIdx.x;
    if (e < E) atomicAdd(&cnt[dst[e]], 1);
}

// ---------------------------------------------------------------------------
// scan_p1 (blocks [0,NB)) + weight collapse (block NB: 40x40 chain;
// blocks NB+1..NB+48: W12 = W1@W2, first also betaf1 = b1@W2)
// ---------------------------------------------------------------------------
__global__ __launch_bounds__(256) void scanp1_pre_kernel(
    const int* __restrict__ cnt, int* __restrict__ partial, int n, int NB,
    const float* __restrict__ Wl, const float* __restrict__ bl,
    const float* __restrict__ W1, const float* __restrict__ W2,
    const float* __restrict__ b1,
    float* __restrict__ C0, float* __restrict__ betas,
    float* __restrict__ W12, float* __restrict__ betaf1)
{
    __shared__ __align__(16) float smem[9216];
    const int tid = threadIdx.x;
    const int bid = blockIdx.x;

    if (bid < NB) {
        int* red = (int*)smem;
        int base = bid * 1024 + tid * 4;
        int s = 0;
        if (base + 3 < n) {
            int4 v = *(const int4*)(cnt + base);
            s = v.x + v.y + v.z + v.w;
        } else {
            for (int k = 0; k < 4; k++) { int i = base + k; if (i < n) s += cnt[i]; }
        }
        red[tid] = s;
        __syncthreads();
        for (int off = 128; off > 0; off >>= 1) {
            if (tid < off) red[tid] += red[tid + off];
            __syncthreads();
        }
        if (tid == 0) partial[bid] = red[0];
        return;
    }

    if (bid == NB) {
        // label-prop chain: C_m = W_{m+1} @ C_{m+1}, beta_m = b_m @ C_m
        float* Ca  = smem;            // 1600
        float* Cb  = smem + 1600;     // 1600
        float* sWm = smem + 3200;     // 1600
        float* bls = smem + 4800;     // 400
        for (int idx = tid; idx < 100; idx += 256)
            ((float4*)bls)[idx] = ((const float4*)bl)[idx];
        for (int idx = tid; idx < 1600; idx += 256)
            Ca[idx] = ((idx / 40) == (idx % 40)) ? 1.f : 0.f;
        if (tid < 40) betas[9 * 40 + tid] = bl[9 * 40 + tid];   // beta_10 = b_10
        __syncthreads();
        float* cur = Ca;
        float* nxt = Cb;
        for (int m = 9; m >= 0; --m) {
            for (int idx = tid; idx < 400; idx += 256)
                ((float4*)sWm)[idx] = ((const float4*)(Wl + (size_t)m * 1600))[idx];
            __syncthreads();
            for (int sid = tid; sid < 400; sid += 256) {
                int i = sid / 10, jq = sid - (sid / 10) * 10;
                const float* wr = &sWm[i * 40];
                const float4* c4 = (const float4*)cur;
                float4 a = make_float4(0.f, 0.f, 0.f, 0.f);
#pragma unroll
                for (int k = 0; k < 40; ++k) {
                    float w = wr[k];
                    float4 c = c4[k * 10 + jq];
                    a.x = fmaf(w, c.x, a.x); a.y = fmaf(w, c.y, a.y);
                    a.z = fmaf(w, c.z, a.z); a.w = fmaf(w, c.w, a.w);
                }
                ((float4*)nxt)[sid] = a;
            }
            __syncthreads();
            if (m >= 1 && tid < 40) {
                float s = 0.f;
                const float* br = &bls[(m - 1) * 40];
#pragma unroll
                for (int k = 0; k < 40; ++k) s = fmaf(br[k], nxt[k * 40 + tid], s);
                betas[(size_t)(m - 1) * 40 + tid] = s;
            }
            float* t = cur; cur = nxt; nxt = t;
            __syncthreads();
        }
        for (int idx = tid; idx < 1600; idx += 256) C0[idx] = cur[idx];
        return;
    }

    // W12 = W1 @ W2 (W2 staged in LDS)
    float* sW2 = smem;                // 9216 = 96x96
    for (int idx = tid; idx < 2304; idx += 256)
        ((float4*)sW2)[idx] = ((const float4*)W2)[idx];
    __syncthreads();
    int idx = (bid - NB - 1) * 256 + tid;   // 0..12287 == 128*96
    {
        int i = idx / 96, j = idx - (idx / 96) * 96;
        float s = 0.f;
        const float* wr = W1 + (size_t)i * 96;
#pragma unroll 8
        for (int k = 0; k < 96; ++k) s = fmaf(wr[k], sW2[k * 96 + j], s);
        W12[idx] = s;
    }
    if (bid == NB + 1 && tid < 96) {
        float s = 0.f;
        for (int k = 0; k < 96; ++k) s = fmaf(b1[k], sW2[k * 96 + tid], s);
        betaf1[tid] = s;
    }
}

__global__ __launch_bounds__(256) void scan_p2(int* __restrict__ partial, int* __restrict__ rowptr, int nb, int n) {
    __shared__ int sm[256];
    int tid = threadIdx.x;
    int v = (tid < nb) ? partial[tid] : 0;
    sm[tid] = v;
    __syncthreads();
    int acc = v;
    for (int off = 1; off < 256; off <<= 1) {
        int t = (tid >= off) ? sm[tid - off] : 0;
        __syncthreads();
        acc += t;
        sm[tid] = acc;
        __syncthreads();
    }
    if (tid < nb) partial[tid] = acc - v;
    if (tid == 255) rowptr[n] = sm[255];
}

// local scan + rowptr/cursor + dinv
__global__ __launch_bounds__(256) void scan_p3(const int* __restrict__ cnt, const int* __restrict__ partial,
                                               int* __restrict__ rowptr, int* __restrict__ cursor,
                                               float* __restrict__ dinv, int n) {
    __shared__ int tsum[256];
    int tid = threadIdx.x;
    int base = blockIdx.x * 1024 + tid * 4;
    int v0 = 0, v1 = 0, v2 = 0, v3 = 0;
    if (base + 3 < n) {
        int4 t = *(const int4*)(cnt + base);
        v0 = t.x; v1 = t.y; v2 = t.z; v3 = t.w;
    } else {
        if (base + 0 < n) v0 = cnt[base + 0];
        if (base + 1 < n) v1 = cnt[base + 1];
        if (base + 2 < n) v2 = cnt[base + 2];
        if (base + 3 < n) v3 = cnt[base + 3];
    }
    int s = v0 + v1 + v2 + v3;
    tsum[tid] = s;
    __syncthreads();
    int acc = s;
    for (int off = 1; off < 256; off <<= 1) {
        int t = (tid >= off) ? tsum[tid - off] : 0;
        __syncthreads();
        acc += t;
        tsum[tid] = acc;
        __syncthreads();
    }
    int run = partial[blockIdx.x] + acc - s;
    int vv[4] = {v0, v1, v2, v3};
    for (int k = 0; k < 4; k++) {
        int i = base + k;
        if (i < n) {
            rowptr[i] = run; cursor[i] = run; run += vv[k];
            dinv[i] = rsqrtf((float)vv[k] + 1.0f);
        }
    }
}

// ---------------------------------------------------------------------------
// GEMM body: Y = (X @ W) * dinv[i], h16 out
// ---------------------------------------------------------------------------
template<int FIN, int FOUT, typename TX>
__device__ __forceinline__ void gemm_body(
    const TX* __restrict__ X, const float* __restrict__ W,
    const float* __restrict__ dinv, h16* __restrict__ Y, int n,
    float* sX, float* sW, int bid, int tid)
{
    constexpr int KC = (FIN % 32 == 0) ? 32 : FIN;
    constexpr int NCHUNK = FIN / KC;
    constexpr int TN = (FOUT + 15) / 16;
    constexpr int BM = 64;
    constexpr int KP = KC + 4;

    const int tj = tid & 15;
    const int ti = tid >> 4;
    const int i0 = bid * BM;

    float acc[4][TN] = {};

    for (int c = 0; c < NCHUNK; ++c) {
        const int k0 = c * KC;
        __syncthreads();
        if constexpr (sizeof(TX) == 2) {
            constexpr int K8 = KC / 8;
            for (int v = tid; v < BM * K8; v += 256) {
                int r = v / K8, q = v - r * K8;
                int gi = i0 + r;
                float f[8] = {0.f, 0.f, 0.f, 0.f, 0.f, 0.f, 0.f, 0.f};
                if (gi < n) ld8h((const h16*)X + (size_t)gi * FIN + k0 + q * 8, f);
                float* p = &sX[r * KP + q * 8];
#pragma unroll
                for (int j = 0; j < 8; ++j) p[j] = f[j];
            }
        } else {
            constexpr int K4 = KC / 4;
            for (int v = tid; v < BM * K4; v += 256) {
                int r = v / K4, q = v - r * K4;
                int gi = i0 + r;
                float4 val = (gi < n) ? *(const float4*)((const float*)X + (size_t)gi * FIN + k0 + q * 4)
                                      : make_float4(0.f, 0.f, 0.f, 0.f);
                float* p = &sX[r * KP + q * 4];
                p[0] = val.x; p[1] = val.y; p[2] = val.z; p[3] = val.w;
            }
        }
        for (int v = tid; v < KC * FOUT; v += 256) {
            int kk = v / FOUT;
            int j = v - kk * FOUT;
            sW[j * KP + kk] = W[(size_t)(k0 + kk) * FOUT + j];
        }
        __syncthreads();
#pragma unroll
        for (int kk = 0; kk < KC; kk += 4) {
            float4 xv[4];
#pragma unroll
            for (int m = 0; m < 4; ++m)
                xv[m] = *(const float4*)&sX[(ti + 16 * m) * KP + kk];
#pragma unroll
            for (int u = 0; u < TN; ++u) {
                float4 wv = *(const float4*)&sW[(tj + 16 * u) * KP + kk];
#pragma unroll
                for (int m = 0; m < 4; ++m) {
                    acc[m][u] = fmaf(xv[m].x, wv.x, acc[m][u]);
                    acc[m][u] = fmaf(xv[m].y, wv.y, acc[m][u]);
                    acc[m][u] = fmaf(xv[m].z, wv.z, acc[m][u]);
                    acc[m][u] = fmaf(xv[m].w, wv.w, acc[m][u]);
                }
            }
        }
    }

#pragma unroll
    for (int m = 0; m < 4; ++m) {
        int gi = i0 + ti + 16 * m;
        if (gi >= n) continue;
        float dv = dinv[gi];
#pragma unroll
        for (int u = 0; u < TN; ++u) {
            int j = tj + 16 * u;
            if (j < FOUT) Y[(size_t)gi * FOUT + j] = (h16)(acc[m][u] * dv);
        }
    }
}

template<int FIN, int FOUT, typename TX>
__global__ __launch_bounds__(256) void gemm_kernel(
    const TX* __restrict__ X, const float* __restrict__ W,
    const float* __restrict__ dinv, h16* __restrict__ Y, int n)
{
    constexpr int KC = (FIN % 32 == 0) ? 32 : FIN;
    constexpr int KP = KC + 4;
    constexpr int TN = (FOUT + 15) / 16;
    __shared__ __align__(16) float smem[64 * KP + TN * 16 * KP];
    gemm_body<FIN, FOUT, TX>(X, W, dinv, Y, n, smem, smem + 64 * KP, blockIdx.x, threadIdx.x);
}

// ---------------------------------------------------------------------------
// Merged: blocks [0,gbE) scatter col; blocks [gbE, gbE+gbG) gemm 128x96.
// Scatter body is 4-VGPR/0-LDS so the union footprint == gemm96 footprint;
// scatter occupancy (6 blocks/CU) >= its standalone effective occupancy.
// ---------------------------------------------------------------------------
__global__ __launch_bounds__(256) void scatter_gemm96_kernel(
    const int* __restrict__ src, const int* __restrict__ dst,
    int* __restrict__ cursor, int* __restrict__ col, int E, int gbE,
    const float* __restrict__ x, const float* __restrict__ W12,
    const float* __restrict__ dinv, h16* __restrict__ A96, int n)
{
    __shared__ __align__(16) float smem[64 * 36 + 96 * 36];
    if (blockIdx.x < gbE) {
        int e = blockIdx.x * 256 + threadIdx.x;
        if (e < E) {
            int d = dst[e];
            int p = atomicAdd(&cursor[d], 1);
            col[p] = src[e];
        }
        return;
    }
    gemm_body<128, 96, float>(x, W12, dinv, A96, n, smem, smem + 64 * 36,
                              blockIdx.x - gbE, threadIdx.x);
}

// ---------------------------------------------------------------------------
// aggregation body: out[i,f8] = dinv*(hs[i]+sum hs[col]) + bias, opt *dinv
// 8x pipelined gathers for memory-level parallelism
// ---------------------------------------------------------------------------
template<int F, int PRE>
__device__ __forceinline__ void agg_body(
    const h16* __restrict__ hs, const int* __restrict__ rowptr,
    const int* __restrict__ col, const float* __restrict__ dinv,
    const float* __restrict__ bias, h16* __restrict__ out, int n,
    int bid, int tid)
{
    constexpr int F8 = F / 8;
    int gt = bid * 256 + tid;
    if (gt >= n * F8) return;
    int i = gt / F8;
    int f = gt - i * F8;
    int s = rowptr[i], e = rowptr[i + 1];
    const h16* base = hs + (size_t)f * 8;
    float acc[8];
    ld8h(hs + (size_t)i * F + f * 8, acc);
    int k = s;
    for (; k + 8 <= e; k += 8) {
        int c[8];
        union { uint4 u; h16 h[8]; } a[8];
#pragma unroll
        for (int q = 0; q < 8; ++q) c[q] = col[k + q];
#pragma unroll
        for (int q = 0; q < 8; ++q) a[q].u = *(const uint4*)(base + (size_t)c[q] * F);
#pragma unroll
        for (int j = 0; j < 8; ++j) {
            float t0 = ((float)a[0].h[j] + (float)a[1].h[j]) + ((float)a[2].h[j] + (float)a[3].h[j]);
            float t1 = ((float)a[4].h[j] + (float)a[5].h[j]) + ((float)a[6].h[j] + (float)a[7].h[j]);
            acc[j] += t0 + t1;
        }
    }
    for (; k + 4 <= e; k += 4) {
        int c0 = col[k], c1 = col[k + 1], c2 = col[k + 2], c3 = col[k + 3];
        union { uint4 u; h16 h[8]; } a0, a1, a2, a3;
        a0.u = *(const uint4*)(base + (size_t)c0 * F);
        a1.u = *(const uint4*)(base + (size_t)c1 * F);
        a2.u = *(const uint4*)(base + (size_t)c2 * F);
        a3.u = *(const uint4*)(base + (size_t)c3 * F);
#pragma unroll
        for (int j = 0; j < 8; ++j)
            acc[j] += ((float)a0.h[j] + (float)a1.h[j]) + ((float)a2.h[j] + (float)a3.h[j]);
    }
    for (; k < e; k++) {
        float v[8];
        ld8h(base + (size_t)col[k] * F, v);
#pragma unroll
        for (int j = 0; j < 8; ++j) acc[j] += v[j];
    }
    float dv = dinv[i];
    float sc = PRE ? dv : 1.f;
    union { uint4 u; h16 h[8]; } o;
#pragma unroll
    for (int j = 0; j < 8; ++j) o.h[j] = (h16)((acc[j] * dv + bias[f * 8 + j]) * sc);
    *(uint4*)(out + (size_t)i * F + f * 8) = o.u;
}

template<int F, int PRE>
__global__ __launch_bounds__(256) void agg_h(
    const h16* __restrict__ hs, const int* __restrict__ rowptr,
    const int* __restrict__ col, const float* __restrict__ dinv,
    const float* __restrict__ bias, h16* __restrict__ out, int n) {
    agg_body<F, PRE>(hs, rowptr, col, dinv, bias, out, n, blockIdx.x, threadIdx.x);
}

// dual agg: label F=40 (PRE=1) + feature F=96 (PRE2)
template<int PRE2>
__global__ __launch_bounds__(256) void agg_dual_kernel(
    const h16* __restrict__ hsA, const float* __restrict__ biasA, h16* __restrict__ outA,
    const h16* __restrict__ hsB, const float* __restrict__ biasB, h16* __restrict__ outB,
    const int* __restrict__ rowptr, const int* __restrict__ col,
    const float* __restrict__ dinv, int n, int nblkA)
{
    if (blockIdx.x < nblkA)
        agg_body<40, 1>(hsA, rowptr, col, dinv, biasA, outA, n, blockIdx.x, threadIdx.x);
    else
        agg_body<96, PRE2>(hsB, rowptr, col, dinv, biasB, outB, n, blockIdx.x - nblkA, threadIdx.x);
}

// ---- fused final layer: out = sigmoid([h2|xl|dw] @ Wf + bf) ----
template<int KC, typename T>
__device__ __forceinline__ void fuse_chunk(
    const T* __restrict__ src, int FIN, int k0, int wrow0,
    const float* __restrict__ Wf, float* sX, float* sW,
    float acc[4][3], int i0, int n, int tid)
{
    constexpr int KP = 44;
    __syncthreads();
    if constexpr (sizeof(T) == 2) {
        constexpr int K8 = KC / 8;
        for (int v = tid; v < 64 * K8; v += 256) {
            int r = v / K8, q = v - r * K8;
            int gi = i0 + r;
            float f[8] = {0.f, 0.f, 0.f, 0.f, 0.f, 0.f, 0.f, 0.f};
            if (gi < n) ld8h((const h16*)src + (size_t)gi * FIN + k0 + q * 8, f);
            float* p = &sX[r * KP + q * 8];
#pragma unroll
            for (int j = 0; j < 8; ++j) p[j] = f[j];
        }
    } else {
        constexpr int K4 = KC / 4;
        for (int v = tid; v < 64 * K4; v += 256) {
            int r = v / K4, q = v - r * K4;
            int gi = i0 + r;
            float4 val = (gi < n) ? *(const float4*)((const float*)src + (size_t)gi * FIN + k0 + q * 4)
                                  : make_float4(0.f, 0.f, 0.f, 0.f);
            float* p = &sX[r * KP + q * 4];
            p[0] = val.x; p[1] = val.y; p[2] = val.z; p[3] = val.w;
        }
    }
    for (int v = tid; v < KC * 40; v += 256) {
        int kk = v / 40, j = v - kk * 40;
        sW[j * KP + kk] = Wf[(size_t)(wrow0 + kk) * 40 + j];
    }
    __syncthreads();
    int tj = tid & 15, ti = tid >> 4;
#pragma unroll
    for (int kk = 0; kk < KC; kk += 4) {
        float4 xv[4];
#pragma unroll
        for (int m = 0; m < 4; ++m)
            xv[m] = *(const float4*)&sX[(ti + 16 * m) * KP + kk];
#pragma unroll
        for (int u = 0; u < 3; ++u) {
            float4 wv = *(const float4*)&sW[(tj + 16 * u) * KP + kk];
#pragma unroll
            for (int m = 0; m < 4; ++m) {
                acc[m][u] = fmaf(xv[m].x, wv.x, acc[m][u]);
                acc[m][u] = fmaf(xv[m].y, wv.y, acc[m][u]);
                acc[m][u] = fmaf(xv[m].z, wv.z, acc[m][u]);
                acc[m][u] = fmaf(xv[m].w, wv.w, acc[m][u]);
            }
        }
    }
}

__global__ __launch_bounds__(256) void fuse_gemm_kernel(
    const h16* __restrict__ h2, const h16* __restrict__ xl,
    const float* __restrict__ dw, const float* __restrict__ Wf,
    const float* __restrict__ bf, float* __restrict__ out, int n)
{
    __shared__ __align__(16) float sX[64 * 44];
    __shared__ __align__(16) float sW[48 * 44];
    float acc[4][3] = {};
    const int tid = threadIdx.x;
    const int i0 = blockIdx.x * 64;
    fuse_chunk<32>(h2, 96, 0,  0,   Wf, sX, sW, acc, i0, n, tid);
    fuse_chunk<32>(h2, 96, 32, 32,  Wf, sX, sW, acc, i0, n, tid);
    fuse_chunk<32>(h2, 96, 64, 64,  Wf, sX, sW, acc, i0, n, tid);
    fuse_chunk<40>(xl, 40, 0,  96,  Wf, sX, sW, acc, i0, n, tid);
    fuse_chunk<32>(dw, 64, 0,  136, Wf, sX, sW, acc, i0, n, tid);
    fuse_chunk<32>(dw, 64, 32, 168, Wf, sX, sW, acc, i0, n, tid);
    const int tj = tid & 15, ti = tid >> 4;
#pragma unroll
    for (int m = 0; m < 4; ++m) {
        int gi = i0 + ti + 16 * m;
        if (gi >= n) continue;
#pragma unroll
        for (int u = 0; u < 3; ++u) {
            int j = tj + 16 * u;
            if (j < 40) {
                float t = acc[m][u] + bf[j];
                out[(size_t)gi * 40 + j] = 1.f / (1.f + expf(-t));
            }
        }
    }
}

extern "C" void kernel_launch(void* const* d_in, const int* in_sizes, int n_in,
                              void* d_out, int out_size, void* d_ws, size_t ws_size,
                              hipStream_t stream) {
    const float* x   = (const float*)d_in[0];
    const float* y   = (const float*)d_in[1];
    const int*   ei  = (const int*)d_in[2];
    const float* dwe = (const float*)d_in[3];
    const float* W1  = (const float*)d_in[4];
    const float* b1  = (const float*)d_in[5];
    const float* W2  = (const float*)d_in[6];
    const float* b2  = (const float*)d_in[7];
    const float* Wl  = (const float*)d_in[8];
    const float* bl  = (const float*)d_in[9];
    const float* Wf  = (const float*)d_in[10];
    const float* bf  = (const float*)d_in[11];
    float* out = (float*)d_out;

    const int n = in_sizes[0] / 128;
    const int E = in_sizes[2] / 2;
    const int* srcp = ei;
    const int* dstp = ei + E;

    char* ws = (char*)d_ws;
    size_t off = 0;
    auto alloc = [&](size_t bytes) -> void* {
        void* p = ws + off;
        off += bytes;
        off = (off + 255) & ~(size_t)255;
        return p;
    };

    int*   cnt     = (int*)alloc((size_t)n * 4);
    float* dinv    = (float*)alloc((size_t)n * 4);
    int*   rowptr  = (int*)alloc((size_t)(n + 1) * 4);
    int*   cursor  = (int*)alloc((size_t)n * 4);
    int*   partial = (int*)alloc(256 * 4);
    int*   col     = (int*)alloc((size_t)E * 4);
    h16*   A96     = (h16*)alloc((size_t)n * 96 * 2);
    h16*   B96     = (h16*)alloc((size_t)n * 96 * 2);
    h16*   Z0      = (h16*)alloc((size_t)n * 40 * 2);
    h16*   LA      = (h16*)alloc((size_t)n * 40 * 2);
    h16*   LB      = (h16*)alloc((size_t)n * 40 * 2);
    float* C0      = (float*)alloc(1600 * 4);
    float* betas   = (float*)alloc(10 * 40 * 4);
    float* W12     = (float*)alloc(128 * 96 * 4);
    float* betaf1  = (float*)alloc(96 * 4);
    (void)ws_size;

    const int gb_e    = (E + THREADS - 1) / THREADS;
    const int NB      = (n + 1023) / 1024;
    const int gb_gm   = (n + 63) / 64;
    const int gb_a96  = (n * 12 + THREADS - 1) / THREADS;
    const int gb_a40  = (n * 5 + THREADS - 1) / THREADS;

    // ---- CSR build + weight collapse (collapse hidden in scan_p1 dispatch) ----
    hipMemsetAsync(cnt, 0, (size_t)n * 4, stream);
    count_kernel<<<gb_e, THREADS, 0, stream>>>(dstp, cnt, E);
    scanp1_pre_kernel<<<NB + 49, THREADS, 0, stream>>>(
        cnt, partial, n, NB, Wl, bl, W1, W2, b1, C0, betas, W12, betaf1);
    scan_p2<<<1, THREADS, 0, stream>>>(partial, rowptr, NB, n);
    scan_p3<<<NB, THREADS, 0, stream>>>(cnt, partial, rowptr, cursor, dinv, n);

    // ---- small label GEMM (independent of col) ----
    gemm_kernel<40, 40, float><<<gb_gm, THREADS, 0, stream>>>(y, C0, dinv, Z0, n);

    // ---- scatter overlapped with the big feature GEMM ----
    scatter_gemm96_kernel<<<gb_e + gb_gm, THREADS, 0, stream>>>(
        srcp, dstp, cursor, col, E, gb_e, x, W12, dinv, A96, n);

    // ---- label layer 1 + feature agg 1 ----
    agg_dual_kernel<1><<<gb_a40 + gb_a96, THREADS, 0, stream>>>(
        Z0, betas + 0, LA, A96, betaf1, B96, rowptr, col, dinv, n, gb_a40);
    // ---- label layer 2 + feature agg 2 ----
    agg_dual_kernel<0><<<gb_a40 + gb_a96, THREADS, 0, stream>>>(
        LA, betas + 40, LB, B96, b2, A96, rowptr, col, dinv, n, gb_a40);

    // ---- label layers 3..10 ----
    const h16* cur = LB;
    const h16* xl = LB;
    for (int m = 3; m <= 10; m++) {
        h16* nxt = (m & 1) ? LA : LB;
        if (m < 10)
            agg_h<40, 1><<<gb_a40, THREADS, 0, stream>>>(cur, rowptr, col, dinv, betas + (size_t)(m - 1) * 40, nxt, n);
        else
            agg_h<40, 0><<<gb_a40, THREADS, 0, stream>>>(cur, rowptr, col, dinv, betas + (size_t)(m - 1) * 40, nxt, n);
        cur = nxt;
        xl = nxt;
    }

    // ---- fuse + sigmoid (h2 = A96 after second feature agg) ----
    fuse_gemm_kernel<<<gb_gm, THREADS, 0, stream>>>(A96, xl, dwe, Wf, bf, out, n);
}

// Round 11
// 387.560 us; speedup vs baseline: 4.6093x; 1.0248x over previous
//
#include <hip/hip_runtime.h>
#include <hip/hip_bf16.h>
#include <math.h>

#define THREADS 256
typedef _Float16 h16;

__device__ __forceinline__ void ld8h(const h16* p, float* f) {
    union { uint4 u; h16 h[8]; } c;
    c.u = *(const uint4*)p;
#pragma unroll
    for (int j = 0; j < 8; ++j) f[j] = (float)c.h[j];
}

// ---------------------------------------------------------------------------
// XCD-partitioned histogram: class c = blockIdx&7 handles dst in its n/8 range
// so cnt lines are touched by one XCD only (L2-local atomics, no line migration)
// ---------------------------------------------------------------------------
__global__ __launch_bounds__(256) void count_part_kernel(
    const int* __restrict__ dst, int* __restrict__ cnt, int E, int n)
{
    const int cls = blockIdx.x & 7;
    const int nb  = gridDim.x >> 3;
    const int sub = blockIdx.x >> 3;
    const int lo = (int)((long long)n * cls / 8);
    const int hi = (int)((long long)n * (cls + 1) / 8);
    const int stride = nb * 256;
    for (int e = sub * 256 + threadIdx.x; e < E; e += stride) {
        int d = dst[e];
        if (d >= lo && d < hi) atomicAdd(&cnt[d], 1);
    }
}

// XCD-partitioned scatter: col/cursor lines for a dst-range stay on one XCD
__global__ __launch_bounds__(256) void scatter_part_kernel(
    const int* __restrict__ src, const int* __restrict__ dst,
    int* __restrict__ cursor, int* __restrict__ col, int E, int n)
{
    const int cls = blockIdx.x & 7;
    const int nb  = gridDim.x >> 3;
    const int sub = blockIdx.x >> 3;
    const int lo = (int)((long long)n * cls / 8);
    const int hi = (int)((long long)n * (cls + 1) / 8);
    const int stride = nb * 256;
    for (int e = sub * 256 + threadIdx.x; e < E; e += stride) {
        int d = dst[e];
        if (d >= lo && d < hi) {
            int p = atomicAdd(&cursor[d], 1);
            col[p] = src[e];
        }
    }
}

// ---------------------------------------------------------------------------
// scan_p1 (blocks [0,NB)) + weight collapse (block NB: 40x40 chain;
// blocks NB+1..NB+48: W12 = W1@W2, first also betaf1 = b1@W2)
// ---------------------------------------------------------------------------
__global__ __launch_bounds__(256) void scanp1_pre_kernel(
    const int* __restrict__ cnt, int* __restrict__ partial, int n, int NB,
    const float* __restrict__ Wl, const float* __restrict__ bl,
    const float* __restrict__ W1, const float* __restrict__ W2,
    const float* __restrict__ b1,
    float* __restrict__ C0, float* __restrict__ betas,
    float* __restrict__ W12, float* __restrict__ betaf1)
{
    __shared__ __align__(16) float smem[9216];
    const int tid = threadIdx.x;
    const int bid = blockIdx.x;

    if (bid < NB) {
        int* red = (int*)smem;
        int base = bid * 1024 + tid * 4;
        int s = 0;
        if (base + 3 < n) {
            int4 v = *(const int4*)(cnt + base);
            s = v.x + v.y + v.z + v.w;
        } else {
            for (int k = 0; k < 4; k++) { int i = base + k; if (i < n) s += cnt[i]; }
        }
        red[tid] = s;
        __syncthreads();
        for (int off = 128; off > 0; off >>= 1) {
            if (tid < off) red[tid] += red[tid + off];
            __syncthreads();
        }
        if (tid == 0) partial[bid] = red[0];
        return;
    }

    if (bid == NB) {
        // label-prop chain: C_m = W_{m+1} @ C_{m+1}, beta_m = b_m @ C_m
        float* Ca  = smem;            // 1600
        float* Cb  = smem + 1600;     // 1600
        float* sWm = smem + 3200;     // 1600
        float* bls = smem + 4800;     // 400
        for (int idx = tid; idx < 100; idx += 256)
            ((float4*)bls)[idx] = ((const float4*)bl)[idx];
        for (int idx = tid; idx < 1600; idx += 256)
            Ca[idx] = ((idx / 40) == (idx % 40)) ? 1.f : 0.f;
        if (tid < 40) betas[9 * 40 + tid] = bl[9 * 40 + tid];   // beta_10 = b_10
        __syncthreads();
        float* cur = Ca;
        float* nxt = Cb;
        for (int m = 9; m >= 0; --m) {
            for (int idx = tid; idx < 400; idx += 256)
                ((float4*)sWm)[idx] = ((const float4*)(Wl + (size_t)m * 1600))[idx];
            __syncthreads();
            for (int sid = tid; sid < 400; sid += 256) {
                int i = sid / 10, jq = sid - (sid / 10) * 10;
                const float* wr = &sWm[i * 40];
                const float4* c4 = (const float4*)cur;
                float4 a = make_float4(0.f, 0.f, 0.f, 0.f);
#pragma unroll
                for (int k = 0; k < 40; ++k) {
                    float w = wr[k];
                    float4 c = c4[k * 10 + jq];
                    a.x = fmaf(w, c.x, a.x); a.y = fmaf(w, c.y, a.y);
                    a.z = fmaf(w, c.z, a.z); a.w = fmaf(w, c.w, a.w);
                }
                ((float4*)nxt)[sid] = a;
            }
            __syncthreads();
            if (m >= 1 && tid < 40) {
                float s = 0.f;
                const float* br = &bls[(m - 1) * 40];
#pragma unroll
                for (int k = 0; k < 40; ++k) s = fmaf(br[k], nxt[k * 40 + tid], s);
                betas[(size_t)(m - 1) * 40 + tid] = s;
            }
            float* t = cur; cur = nxt; nxt = t;
            __syncthreads();
        }
        for (int idx = tid; idx < 1600; idx += 256) C0[idx] = cur[idx];
        return;
    }

    // W12 = W1 @ W2 (W2 staged in LDS)
    float* sW2 = smem;                // 9216 = 96x96
    for (int idx = tid; idx < 2304; idx += 256)
        ((float4*)sW2)[idx] = ((const float4*)W2)[idx];
    __syncthreads();
    int idx = (bid - NB - 1) * 256 + tid;   // 0..12287 == 128*96
    {
        int i = idx / 96, j = idx - (idx / 96) * 96;
        float s = 0.f;
        const float* wr = W1 + (size_t)i * 96;
#pragma unroll 8
        for (int k = 0; k < 96; ++k) s = fmaf(wr[k], sW2[k * 96 + j], s);
        W12[idx] = s;
    }
    if (bid == NB + 1 && tid < 96) {
        float s = 0.f;
        for (int k = 0; k < 96; ++k) s = fmaf(b1[k], sW2[k * 96 + tid], s);
        betaf1[tid] = s;
    }
}

__global__ __launch_bounds__(256) void scan_p2(int* __restrict__ partial, int* __restrict__ rowptr, int nb, int n) {
    __shared__ int sm[256];
    int tid = threadIdx.x;
    int v = (tid < nb) ? partial[tid] : 0;
    sm[tid] = v;
    __syncthreads();
    int acc = v;
    for (int off = 1; off < 256; off <<= 1) {
        int t = (tid >= off) ? sm[tid - off] : 0;
        __syncthreads();
        acc += t;
        sm[tid] = acc;
        __syncthreads();
    }
    if (tid < nb) partial[tid] = acc - v;
    if (tid == 255) rowptr[n] = sm[255];
}

// local scan + rowptr/cursor + dinv
__global__ __launch_bounds__(256) void scan_p3(const int* __restrict__ cnt, const int* __restrict__ partial,
                                               int* __restrict__ rowptr, int* __restrict__ cursor,
                                               float* __restrict__ dinv, int n) {
    __shared__ int tsum[256];
    int tid = threadIdx.x;
    int base = blockIdx.x * 1024 + tid * 4;
    int v0 = 0, v1 = 0, v2 = 0, v3 = 0;
    if (base + 3 < n) {
        int4 t = *(const int4*)(cnt + base);
        v0 = t.x; v1 = t.y; v2 = t.z; v3 = t.w;
    } else {
        if (base + 0 < n) v0 = cnt[base + 0];
        if (base + 1 < n) v1 = cnt[base + 1];
        if (base + 2 < n) v2 = cnt[base + 2];
        if (base + 3 < n) v3 = cnt[base + 3];
    }
    int s = v0 + v1 + v2 + v3;
    tsum[tid] = s;
    __syncthreads();
    int acc = s;
    for (int off = 1; off < 256; off <<= 1) {
        int t = (tid >= off) ? tsum[tid - off] : 0;
        __syncthreads();
        acc += t;
        tsum[tid] = acc;
        __syncthreads();
    }
    int run = partial[blockIdx.x] + acc - s;
    int vv[4] = {v0, v1, v2, v3};
    for (int k = 0; k < 4; k++) {
        int i = base + k;
        if (i < n) {
            rowptr[i] = run; cursor[i] = run; run += vv[k];
            dinv[i] = rsqrtf((float)vv[k] + 1.0f);
        }
    }
}

// ---------------------------------------------------------------------------
// GEMM body: Y = (X @ W) * dinv[i], h16 out
// ---------------------------------------------------------------------------
template<int FIN, int FOUT, typename TX>
__device__ __forceinline__ void gemm_body(
    const TX* __restrict__ X, const float* __restrict__ W,
    const float* __restrict__ dinv, h16* __restrict__ Y, int n,
    float* sX, float* sW, int bid, int tid)
{
    constexpr int KC = (FIN % 32 == 0) ? 32 : FIN;
    constexpr int NCHUNK = FIN / KC;
    constexpr int TN = (FOUT + 15) / 16;
    constexpr int BM = 64;
    constexpr int KP = KC + 4;

    const int tj = tid & 15;
    const int ti = tid >> 4;
    const int i0 = bid * BM;

    float acc[4][TN] = {};

    for (int c = 0; c < NCHUNK; ++c) {
        const int k0 = c * KC;
        __syncthreads();
        if constexpr (sizeof(TX) == 2) {
            constexpr int K8 = KC / 8;
            for (int v = tid; v < BM * K8; v += 256) {
                int r = v / K8, q = v - r * K8;
                int gi = i0 + r;
                float f[8] = {0.f, 0.f, 0.f, 0.f, 0.f, 0.f, 0.f, 0.f};
                if (gi < n) ld8h((const h16*)X + (size_t)gi * FIN + k0 + q * 8, f);
                float* p = &sX[r * KP + q * 8];
#pragma unroll
                for (int j = 0; j < 8; ++j) p[j] = f[j];
            }
        } else {
            constexpr int K4 = KC / 4;
            for (int v = tid; v < BM * K4; v += 256) {
                int r = v / K4, q = v - r * K4;
                int gi = i0 + r;
                float4 val = (gi < n) ? *(const float4*)((const float*)X + (size_t)gi * FIN + k0 + q * 4)
                                      : make_float4(0.f, 0.f, 0.f, 0.f);
                float* p = &sX[r * KP + q * 4];
                p[0] = val.x; p[1] = val.y; p[2] = val.z; p[3] = val.w;
            }
        }
        for (int v = tid; v < KC * FOUT; v += 256) {
            int kk = v / FOUT;
            int j = v - kk * FOUT;
            sW[j * KP + kk] = W[(size_t)(k0 + kk) * FOUT + j];
        }
        __syncthreads();
#pragma unroll
        for (int kk = 0; kk < KC; kk += 4) {
            float4 xv[4];
#pragma unroll
            for (int m = 0; m < 4; ++m)
                xv[m] = *(const float4*)&sX[(ti + 16 * m) * KP + kk];
#pragma unroll
            for (int u = 0; u < TN; ++u) {
                float4 wv = *(const float4*)&sW[(tj + 16 * u) * KP + kk];
#pragma unroll
                for (int m = 0; m < 4; ++m) {
                    acc[m][u] = fmaf(xv[m].x, wv.x, acc[m][u]);
                    acc[m][u] = fmaf(xv[m].y, wv.y, acc[m][u]);
                    acc[m][u] = fmaf(xv[m].z, wv.z, acc[m][u]);
                    acc[m][u] = fmaf(xv[m].w, wv.w, acc[m][u]);
                }
            }
        }
    }

#pragma unroll
    for (int m = 0; m < 4; ++m) {
        int gi = i0 + ti + 16 * m;
        if (gi >= n) continue;
        float dv = dinv[gi];
#pragma unroll
        for (int u = 0; u < TN; ++u) {
            int j = tj + 16 * u;
            if (j < FOUT) Y[(size_t)gi * FOUT + j] = (h16)(acc[m][u] * dv);
        }
    }
}

template<int FIN, int FOUT, typename TX>
__global__ __launch_bounds__(256) void gemm_kernel(
    const TX* __restrict__ X, const float* __restrict__ W,
    const float* __restrict__ dinv, h16* __restrict__ Y, int n)
{
    constexpr int KC = (FIN % 32 == 0) ? 32 : FIN;
    constexpr int KP = KC + 4;
    constexpr int TN = (FOUT + 15) / 16;
    __shared__ __align__(16) float smem[64 * KP + TN * 16 * KP];
    gemm_body<FIN, FOUT, TX>(X, W, dinv, Y, n, smem, smem + 64 * KP, blockIdx.x, threadIdx.x);
}

// ---------------------------------------------------------------------------
// aggregation body: out[i,f8] = dinv*(hs[i]+sum hs[col]) + bias, opt *dinv
// 8x pipelined gathers for memory-level parallelism
// ---------------------------------------------------------------------------
template<int F, int PRE>
__device__ __forceinline__ void agg_body(
    const h16* __restrict__ hs, const int* __restrict__ rowptr,
    const int* __restrict__ col, const float* __restrict__ dinv,
    const float* __restrict__ bias, h16* __restrict__ out, int n,
    int bid, int tid)
{
    constexpr int F8 = F / 8;
    int gt = bid * 256 + tid;
    if (gt >= n * F8) return;
    int i = gt / F8;
    int f = gt - i * F8;
    int s = rowptr[i], e = rowptr[i + 1];
    const h16* base = hs + (size_t)f * 8;
    float acc[8];
    ld8h(hs + (size_t)i * F + f * 8, acc);
    int k = s;
    for (; k + 8 <= e; k += 8) {
        int c[8];
        union { uint4 u; h16 h[8]; } a[8];
#pragma unroll
        for (int q = 0; q < 8; ++q) c[q] = col[k + q];
#pragma unroll
        for (int q = 0; q < 8; ++q) a[q].u = *(const uint4*)(base + (size_t)c[q] * F);
#pragma unroll
        for (int j = 0; j < 8; ++j) {
            float t0 = ((float)a[0].h[j] + (float)a[1].h[j]) + ((float)a[2].h[j] + (float)a[3].h[j]);
            float t1 = ((float)a[4].h[j] + (float)a[5].h[j]) + ((float)a[6].h[j] + (float)a[7].h[j]);
            acc[j] += t0 + t1;
        }
    }
    for (; k + 4 <= e; k += 4) {
        int c0 = col[k], c1 = col[k + 1], c2 = col[k + 2], c3 = col[k + 3];
        union { uint4 u; h16 h[8]; } a0, a1, a2, a3;
        a0.u = *(const uint4*)(base + (size_t)c0 * F);
        a1.u = *(const uint4*)(base + (size_t)c1 * F);
        a2.u = *(const uint4*)(base + (size_t)c2 * F);
        a3.u = *(const uint4*)(base + (size_t)c3 * F);
#pragma unroll
        for (int j = 0; j < 8; ++j)
            acc[j] += ((float)a0.h[j] + (float)a1.h[j]) + ((float)a2.h[j] + (float)a3.h[j]);
    }
    for (; k < e; k++) {
        float v[8];
        ld8h(base + (size_t)col[k] * F, v);
#pragma unroll
        for (int j = 0; j < 8; ++j) acc[j] += v[j];
    }
    float dv = dinv[i];
    float sc = PRE ? dv : 1.f;
    union { uint4 u; h16 h[8]; } o;
#pragma unroll
    for (int j = 0; j < 8; ++j) o.h[j] = (h16)((acc[j] * dv + bias[f * 8 + j]) * sc);
    *(uint4*)(out + (size_t)i * F + f * 8) = o.u;
}

template<int F, int PRE>
__global__ __launch_bounds__(256) void agg_h(
    const h16* __restrict__ hs, const int* __restrict__ rowptr,
    const int* __restrict__ col, const float* __restrict__ dinv,
    const float* __restrict__ bias, h16* __restrict__ out, int n) {
    agg_body<F, PRE>(hs, rowptr, col, dinv, bias, out, n, blockIdx.x, threadIdx.x);
}

// dual agg: label F=40 (PRE=1) + feature F=96 (PRE2)
template<int PRE2>
__global__ __launch_bounds__(256) void agg_dual_kernel(
    const h16* __restrict__ hsA, const float* __restrict__ biasA, h16* __restrict__ outA,
    const h16* __restrict__ hsB, const float* __restrict__ biasB, h16* __restrict__ outB,
    const int* __restrict__ rowptr, const int* __restrict__ col,
    const float* __restrict__ dinv, int n, int nblkA)
{
    if (blockIdx.x < nblkA)
        agg_body<40, 1>(hsA, rowptr, col, dinv, biasA, outA, n, blockIdx.x, threadIdx.x);
    else
        agg_body<96, PRE2>(hsB, rowptr, col, dinv, biasB, outB, n, blockIdx.x - nblkA, threadIdx.x);
}

// ---- fused final layer: out = sigmoid([h2|xl|dw] @ Wf + bf) ----
template<int KC, typename T>
__device__ __forceinline__ void fuse_chunk(
    const T* __restrict__ src, int FIN, int k0, int wrow0,
    const float* __restrict__ Wf, float* sX, float* sW,
    float acc[4][3], int i0, int n, int tid)
{
    constexpr int KP = 44;
    __syncthreads();
    if constexpr (sizeof(T) == 2) {
        constexpr int K8 = KC / 8;
        for (int v = tid; v < 64 * K8; v += 256) {
            int r = v / K8, q = v - r * K8;
            int gi = i0 + r;
            float f[8] = {0.f, 0.f, 0.f, 0.f, 0.f, 0.f, 0.f, 0.f};
            if (gi < n) ld8h((const h16*)src + (size_t)gi * FIN + k0 + q * 8, f);
            float* p = &sX[r * KP + q * 8];
#pragma unroll
            for (int j = 0; j < 8; ++j) p[j] = f[j];
        }
    } else {
        constexpr int K4 = KC / 4;
        for (int v = tid; v < 64 * K4; v += 256) {
            int r = v / K4, q = v - r * K4;
            int gi = i0 + r;
            float4 val = (gi < n) ? *(const float4*)((const float*)src + (size_t)gi * FIN + k0 + q * 4)
                                  : make_float4(0.f, 0.f, 0.f, 0.f);
            float* p = &sX[r * KP + q * 4];
            p[0] = val.x; p[1] = val.y; p[2] = val.z; p[3] = val.w;
        }
    }
    for (int v = tid; v < KC * 40; v += 256) {
        int kk = v / 40, j = v - kk * 40;
        sW[j * KP + kk] = Wf[(size_t)(wrow0 + kk) * 40 + j];
    }
    __syncthreads();
    int tj = tid & 15, ti = tid >> 4;
#pragma unroll
    for (int kk = 0; kk < KC; kk += 4) {
        float4 xv[4];
#pragma unroll
        for (int m = 0; m < 4; ++m)
            xv[m] = *(const float4*)&sX[(ti + 16 * m) * KP + kk];
#pragma unroll
        for (int u = 0; u < 3; ++u) {
            float4 wv = *(const float4*)&sW[(tj + 16 * u) * KP + kk];
#pragma unroll
            for (int m = 0; m < 4; ++m) {
                acc[m][u] = fmaf(xv[m].x, wv.x, acc[m][u]);
                acc[m][u] = fmaf(xv[m].y, wv.y, acc[m][u]);
                acc[m][u] = fmaf(xv[m].z, wv.z, acc[m][u]);
                acc[m][u] = fmaf(xv[m].w, wv.w, acc[m][u]);
            }
        }
    }
}

__global__ __launch_bounds__(256) void fuse_gemm_kernel(
    const h16* __restrict__ h2, const h16* __restrict__ xl,
    const float* __restrict__ dw, const float* __restrict__ Wf,
    const float* __restrict__ bf, float* __restrict__ out, int n)
{
    __shared__ __align__(16) float sX[64 * 44];
    __shared__ __align__(16) float sW[48 * 44];
    float acc[4][3] = {};
    const int tid = threadIdx.x;
    const int i0 = blockIdx.x * 64;
    fuse_chunk<32>(h2, 96, 0,  0,   Wf, sX, sW, acc, i0, n, tid);
    fuse_chunk<32>(h2, 96, 32, 32,  Wf, sX, sW, acc, i0, n, tid);
    fuse_chunk<32>(h2, 96, 64, 64,  Wf, sX, sW, acc, i0, n, tid);
    fuse_chunk<40>(xl, 40, 0,  96,  Wf, sX, sW, acc, i0, n, tid);
    fuse_chunk<32>(dw, 64, 0,  136, Wf, sX, sW, acc, i0, n, tid);
    fuse_chunk<32>(dw, 64, 32, 168, Wf, sX, sW, acc, i0, n, tid);
    const int tj = tid & 15, ti = tid >> 4;
#pragma unroll
    for (int m = 0; m < 4; ++m) {
        int gi = i0 + ti + 16 * m;
        if (gi >= n) continue;
#pragma unroll
        for (int u = 0; u < 3; ++u) {
            int j = tj + 16 * u;
            if (j < 40) {
                float t = acc[m][u] + bf[j];
                out[(size_t)gi * 40 + j] = 1.f / (1.f + expf(-t));
            }
        }
    }
}

extern "C" void kernel_launch(void* const* d_in, const int* in_sizes, int n_in,
                              void* d_out, int out_size, void* d_ws, size_t ws_size,
                              hipStream_t stream) {
    const float* x   = (const float*)d_in[0];
    const float* y   = (const float*)d_in[1];
    const int*   ei  = (const int*)d_in[2];
    const float* dwe = (const float*)d_in[3];
    const float* W1  = (const float*)d_in[4];
    const float* b1  = (const float*)d_in[5];
    const float* W2  = (const float*)d_in[6];
    const float* b2  = (const float*)d_in[7];
    const float* Wl  = (const float*)d_in[8];
    const float* bl  = (const float*)d_in[9];
    const float* Wf  = (const float*)d_in[10];
    const float* bf  = (const float*)d_in[11];
    float* out = (float*)d_out;

    const int n = in_sizes[0] / 128;
    const int E = in_sizes[2] / 2;
    const int* srcp = ei;
    const int* dstp = ei + E;

    char* ws = (char*)d_ws;
    size_t off = 0;
    auto alloc = [&](size_t bytes) -> void* {
        void* p = ws + off;
        off += bytes;
        off = (off + 255) & ~(size_t)255;
        return p;
    };

    int*   cnt     = (int*)alloc((size_t)n * 4);
    float* dinv    = (float*)alloc((size_t)n * 4);
    int*   rowptr  = (int*)alloc((size_t)(n + 1) * 4);
    int*   cursor  = (int*)alloc((size_t)n * 4);
    int*   partial = (int*)alloc(256 * 4);
    int*   col     = (int*)alloc((size_t)E * 4);
    h16*   A96     = (h16*)alloc((size_t)n * 96 * 2);
    h16*   B96     = (h16*)alloc((size_t)n * 96 * 2);
    h16*   Z0      = (h16*)alloc((size_t)n * 40 * 2);
    h16*   LA      = (h16*)alloc((size_t)n * 40 * 2);
    h16*   LB      = (h16*)alloc((size_t)n * 40 * 2);
    float* C0      = (float*)alloc(1600 * 4);
    float* betas   = (float*)alloc(10 * 40 * 4);
    float* W12     = (float*)alloc(128 * 96 * 4);
    float* betaf1  = (float*)alloc(96 * 4);
    (void)ws_size;

    const int NB      = (n + 1023) / 1024;
    const int gb_gm   = (n + 63) / 64;
    const int gb_a96  = (n * 12 + THREADS - 1) / THREADS;
    const int gb_a40  = (n * 5 + THREADS - 1) / THREADS;
    const int PART_BLOCKS = 2048;   // 256 blocks per XCD class

    // ---- CSR build (XCD-partitioned atomics) + weight collapse ----
    hipMemsetAsync(cnt, 0, (size_t)n * 4, stream);
    count_part_kernel<<<PART_BLOCKS, THREADS, 0, stream>>>(dstp, cnt, E, n);
    scanp1_pre_kernel<<<NB + 49, THREADS, 0, stream>>>(
        cnt, partial, n, NB, Wl, bl, W1, W2, b1, C0, betas, W12, betaf1);
    scan_p2<<<1, THREADS, 0, stream>>>(partial, rowptr, NB, n);
    scan_p3<<<NB, THREADS, 0, stream>>>(cnt, partial, rowptr, cursor, dinv, n);
    scatter_part_kernel<<<PART_BLOCKS, THREADS, 0, stream>>>(srcp, dstp, cursor, col, E, n);

    // ---- input GEMMs ----
    gemm_kernel<40, 40, float><<<gb_gm, THREADS, 0, stream>>>(y, C0, dinv, Z0, n);
    gemm_kernel<128, 96, float><<<gb_gm, THREADS, 0, stream>>>(x, W12, dinv, A96, n);

    // ---- label layer 1 + feature agg 1 ----
    agg_dual_kernel<1><<<gb_a40 + gb_a96, THREADS, 0, stream>>>(
        Z0, betas + 0, LA, A96, betaf1, B96, rowptr, col, dinv, n, gb_a40);
    // ---- label layer 2 + feature agg 2 ----
    agg_dual_kernel<0><<<gb_a40 + gb_a96, THREADS, 0, stream>>>(
        LA, betas + 40, LB, B96, b2, A96, rowptr, col, dinv, n, gb_a40);

    // ---- label layers 3..10 ----
    const h16* cur = LB;
    const h16* xl = LB;
    for (int m = 3; m <= 10; m++) {
        h16* nxt = (m & 1) ? LA : LB;
        if (m < 10)
            agg_h<40, 1><<<gb_a40, THREADS, 0, stream>>>(cur, rowptr, col, dinv, betas + (size_t)(m - 1) * 40, nxt, n);
        else
            agg_h<40, 0><<<gb_a40, THREADS, 0, stream>>>(cur, rowptr, col, dinv, betas + (size_t)(m - 1) * 40, nxt, n);
        cur = nxt;
        xl = nxt;
    }

    // ---- fuse + sigmoid (h2 = A96 after second feature agg) ----
    fuse_gemm_kernel<<<gb_gm, THREADS, 0, stream>>>(A96, xl, dwe, Wf, bf, out, n);
}